// Round 1
// baseline (4035.670 us; speedup 1.0000x reference)
//
#include <hip/hip_runtime.h>
#include <hip/hip_bf16.h>

#define BB 2
#define TT 2048
#define CC 1024
#define NHEAD 16
#define DHEAD 64

// ---------------------------------------------------------------------------
// Generic fp32 GEMM with bias: C[M,N] = A[M,K] @ B[K,N] + bias[N]
// 64x64 output tile per block, 256 threads, each thread computes 4x4.
// K staged in steps of 16 through LDS. Dims must divide 64/16 (they do here).
// ---------------------------------------------------------------------------
__global__ __launch_bounds__(256) void gemm_bias_kernel(
    const float* __restrict__ A, const float* __restrict__ B,
    const float* __restrict__ bias, float* __restrict__ C,
    int M, int N, int K) {
  __shared__ float As[64][17];   // [m][k] padded
  __shared__ float Bs[16][65];   // [k][n] padded

  const int tid = threadIdx.x;
  const int tx = tid & 15;       // 0..15 -> col group
  const int ty = tid >> 4;       // 0..15 -> row group
  const int row0 = blockIdx.y * 64;
  const int col0 = blockIdx.x * 64;

  float acc[4][4];
#pragma unroll
  for (int i = 0; i < 4; ++i)
#pragma unroll
    for (int j = 0; j < 4; ++j) acc[i][j] = 0.0f;

  for (int k0 = 0; k0 < K; k0 += 16) {
    // load A tile: 64 rows x 16 k
#pragma unroll
    for (int i = 0; i < 4; ++i) {
      int e = tid + i * 256;
      int r = e >> 4, c = e & 15;
      As[r][c] = A[(size_t)(row0 + r) * K + (k0 + c)];
    }
    // load B tile: 16 k x 64 cols (coalesced)
#pragma unroll
    for (int i = 0; i < 4; ++i) {
      int e = tid + i * 256;
      int r = e >> 6, c = e & 63;
      Bs[r][c] = B[(size_t)(k0 + r) * N + (col0 + c)];
    }
    __syncthreads();

#pragma unroll
    for (int kk = 0; kk < 16; ++kk) {
      float a[4], b[4];
#pragma unroll
      for (int i = 0; i < 4; ++i) a[i] = As[ty * 4 + i][kk];
#pragma unroll
      for (int j = 0; j < 4; ++j) b[j] = Bs[kk][tx * 4 + j];
#pragma unroll
      for (int i = 0; i < 4; ++i)
#pragma unroll
        for (int j = 0; j < 4; ++j) acc[i][j] += a[i] * b[j];
    }
    __syncthreads();
  }

#pragma unroll
  for (int i = 0; i < 4; ++i) {
    int r = row0 + ty * 4 + i;
#pragma unroll
    for (int j = 0; j < 4; ++j) {
      int c = col0 + tx * 4 + j;
      C[(size_t)r * N + c] = acc[i][j] + bias[c];
    }
  }
}

// ---------------------------------------------------------------------------
// Causal attention: one block (256 threads) per query row (b, h, q).
// qkv layout: [B, T, 3C]; Q at col h*64, K at C + h*64, V at 2C + h*64.
// Writes y in [B, T, C] layout.
// ---------------------------------------------------------------------------
__global__ __launch_bounds__(256) void attn_kernel(
    const float* __restrict__ qkv, float* __restrict__ y) {
  const int gid = blockIdx.x;            // ((b*NHEAD)+h)*TT + q
  const int qidx = gid % TT;
  const int bh = gid / TT;
  const int h = bh % NHEAD;
  const int b = bh / NHEAD;
  const int tid = threadIdx.x;

  __shared__ float qs[DHEAD];
  __shared__ float sc[TT];
  __shared__ float red[256];

  const size_t rowQ = ((size_t)(b * TT + qidx)) * (3 * CC);
  const float* qptr = qkv + rowQ + h * DHEAD;
  if (tid < DHEAD) qs[tid] = qptr[tid];
  __syncthreads();

  // scores for k in [0, qidx]
  for (int k = tid; k <= qidx; k += 256) {
    const float* kptr = qkv + ((size_t)(b * TT + k)) * (3 * CC) + CC + h * DHEAD;
    float s = 0.0f;
#pragma unroll
    for (int d = 0; d < DHEAD; ++d) s += qs[d] * kptr[d];
    sc[k] = s * 0.125f;  // 1/sqrt(64)
  }
  __syncthreads();

  // row max
  float m = -1e30f;
  for (int k = tid; k <= qidx; k += 256) m = fmaxf(m, sc[k]);
  red[tid] = m;
  __syncthreads();
  for (int s = 128; s > 0; s >>= 1) {
    if (tid < s) red[tid] = fmaxf(red[tid], red[tid + s]);
    __syncthreads();
  }
  m = red[0];
  __syncthreads();

  // exp + sum
  float sum = 0.0f;
  for (int k = tid; k <= qidx; k += 256) {
    float e = __expf(sc[k] - m);
    sc[k] = e;
    sum += e;
  }
  red[tid] = sum;
  __syncthreads();
  for (int s = 128; s > 0; s >>= 1) {
    if (tid < s) red[tid] += red[tid + s];
    __syncthreads();
  }
  const float inv = 1.0f / red[0];
  __syncthreads();

  // y[d] = sum_k p[k] * V[k][d]; thread t: d = t&63, group g = t>>6 (4 groups)
  const int d = tid & 63;
  const int g = tid >> 6;
  float acc = 0.0f;
  for (int k = g; k <= qidx; k += 4) {
    const float* vptr = qkv + ((size_t)(b * TT + k)) * (3 * CC) + 2 * CC + h * DHEAD;
    acc += sc[k] * vptr[d];
  }
  red[tid] = acc;
  __syncthreads();
  if (g == 0) {
    float r = red[tid] + red[tid + 64] + red[tid + 128] + red[tid + 192];
    y[((size_t)(b * TT + qidx)) * CC + h * DHEAD + d] = r * inv;
  }
}

extern "C" void kernel_launch(void* const* d_in, const int* in_sizes, int n_in,
                              void* d_out, int out_size, void* d_ws, size_t ws_size,
                              hipStream_t stream) {
  const float* x      = (const float*)d_in[0];  // [B,T,C]
  const float* W_attn = (const float*)d_in[1];  // [C,3C]
  const float* b_attn = (const float*)d_in[2];  // [3C]
  const float* W_proj = (const float*)d_in[3];  // [C,C]
  const float* b_proj = (const float*)d_in[4];  // [C]
  float* out = (float*)d_out;                   // [B,T,C]

  float* qkv = (float*)d_ws;                          // B*T*3C floats
  float* y   = qkv + (size_t)BB * TT * 3 * CC;        // B*T*C floats

  const int M = BB * TT;   // 4096

  // GEMM1: qkv = x @ W_attn + b_attn   (M=4096, N=3072, K=1024)
  {
    dim3 grid((3 * CC) / 64, M / 64);
    gemm_bias_kernel<<<grid, 256, 0, stream>>>(x, W_attn, b_attn, qkv, M, 3 * CC, CC);
  }

  // Attention: one block per (b, h, q)
  attn_kernel<<<BB * NHEAD * TT, 256, 0, stream>>>(qkv, y);

  // GEMM2: out = y @ W_proj + b_proj   (M=4096, N=1024, K=1024)
  {
    dim3 grid(CC / 64, M / 64);
    gemm_bias_kernel<<<grid, 256, 0, stream>>>(y, W_proj, b_proj, out, M, CC, CC);
  }
}

// Round 2
// 1146.503 us; speedup vs baseline: 3.5200x; 3.5200x over previous
//
#include <hip/hip_runtime.h>
#include <hip/hip_bf16.h>

#define BB 2
#define TT 2048
#define CC 1024
#define NHEAD 16
#define DHEAD 64
#define PADW 68   // row stride (floats) in LDS: keeps float4 alignment, spreads banks

// ---------------------------------------------------------------------------
// Generic fp32 GEMM with bias: C[M,N] = A[M,K] @ B[K,N] + bias[N]
// 64x64 output tile per block, 256 threads, each thread computes 4x4.
// ---------------------------------------------------------------------------
__global__ __launch_bounds__(256) void gemm_bias_kernel(
    const float* __restrict__ A, const float* __restrict__ B,
    const float* __restrict__ bias, float* __restrict__ C,
    int M, int N, int K) {
  __shared__ float As[64][17];   // [m][k] padded
  __shared__ float Bs[16][65];   // [k][n] padded

  const int tid = threadIdx.x;
  const int tx = tid & 15;
  const int ty = tid >> 4;
  const int row0 = blockIdx.y * 64;
  const int col0 = blockIdx.x * 64;

  float acc[4][4];
#pragma unroll
  for (int i = 0; i < 4; ++i)
#pragma unroll
    for (int j = 0; j < 4; ++j) acc[i][j] = 0.0f;

  for (int k0 = 0; k0 < K; k0 += 16) {
#pragma unroll
    for (int i = 0; i < 4; ++i) {
      int e = tid + i * 256;
      int r = e >> 4, c = e & 15;
      As[r][c] = A[(size_t)(row0 + r) * K + (k0 + c)];
    }
#pragma unroll
    for (int i = 0; i < 4; ++i) {
      int e = tid + i * 256;
      int r = e >> 6, c = e & 63;
      Bs[r][c] = B[(size_t)(k0 + r) * N + (col0 + c)];
    }
    __syncthreads();

#pragma unroll
    for (int kk = 0; kk < 16; ++kk) {
      float a[4], b[4];
#pragma unroll
      for (int i = 0; i < 4; ++i) a[i] = As[ty * 4 + i][kk];
#pragma unroll
      for (int j = 0; j < 4; ++j) b[j] = Bs[kk][tx * 4 + j];
#pragma unroll
      for (int i = 0; i < 4; ++i)
#pragma unroll
        for (int j = 0; j < 4; ++j) acc[i][j] += a[i] * b[j];
    }
    __syncthreads();
  }

#pragma unroll
  for (int i = 0; i < 4; ++i) {
    int r = row0 + ty * 4 + i;
#pragma unroll
    for (int j = 0; j < 4; ++j) {
      int c = col0 + tx * 4 + j;
      C[(size_t)r * N + c] = acc[i][j] + bias[c];
    }
  }
}

// ---------------------------------------------------------------------------
// Flash-style causal attention, fp32.
// Grid: (T/64 q-tiles, B*NHEAD). Block: 256 threads.
// Each block: Q-tile 64 rows in LDS; loop K/V-tiles of 64 rows; online softmax.
// Thread (tx,ty) owns q-rows ty*4+i and (score-cols / out-dims) tx*4+j.
// LDS: Qs[64][PADW], KT[64][PADW] ([d][krow], aliased with Ps), Vs[64][PADW].
// ---------------------------------------------------------------------------
__global__ __launch_bounds__(256) void flash_attn_kernel(
    const float* __restrict__ qkv, float* __restrict__ y) {
  __shared__ float smem[3 * 64 * PADW];
  float* Qs = smem;                  // [qrow][d]
  float* KT = smem + 64 * PADW;      // [d][krow]
  float* Vs = smem + 2 * 64 * PADW;  // [krow][d]
  float* Ps = KT;                    // [qrow][kcol] (alias, after S done)

  const int qt = blockIdx.x;         // q tile index
  const int bh = blockIdx.y;         // b*NHEAD + h
  const int h = bh & (NHEAD - 1);
  const int b = bh >> 4;
  const int tid = threadIdx.x;
  const int tx = tid & 15;
  const int ty = tid >> 4;

  const size_t baseQ = (size_t)(b * TT) * (3 * CC) + h * DHEAD;
  const size_t baseK = baseQ + CC;
  const size_t baseV = baseQ + 2 * CC;

  // Load Q tile (64 rows x 64 d), coalesced float4.
#pragma unroll
  for (int c = 0; c < 4; ++c) {
    int e = c * 256 + tid;
    int r = e >> 4;
    int d4 = (e & 15) * 4;
    float4 v = *(const float4*)(qkv + baseQ + (size_t)(qt * 64 + r) * (3 * CC) + d4);
    *(float4*)(Qs + r * PADW + d4) = v;
  }

  float m_i[4], l_i[4], acc[4][4];
#pragma unroll
  for (int i = 0; i < 4; ++i) {
    m_i[i] = -1e30f;
    l_i[i] = 0.0f;
#pragma unroll
    for (int j = 0; j < 4; ++j) acc[i][j] = 0.0f;
  }

  for (int kt = 0; kt <= qt; ++kt) {
    __syncthreads();  // prev-iter consumers of KT/Ps/Vs done; Q tile visible (iter 0)

    // K tile, transposed into KT[d][krow]. Global read coalesced.
#pragma unroll
    for (int c = 0; c < 16; ++c) {
      int e = c * 256 + tid;
      int r = e >> 6;
      int d = e & 63;
      KT[d * PADW + r] = qkv[baseK + (size_t)(kt * 64 + r) * (3 * CC) + d];
    }
    // V tile, straight copy, float4.
#pragma unroll
    for (int c = 0; c < 4; ++c) {
      int e = c * 256 + tid;
      int r = e >> 4;
      int d4 = (e & 15) * 4;
      *(float4*)(Vs + r * PADW + d4) =
          *(const float4*)(qkv + baseV + (size_t)(kt * 64 + r) * (3 * CC) + d4);
    }
    __syncthreads();

    // S = (Q K^T) * 1/8 ; s[i][j] for rows ty*4+i, cols tx*4+j
    float s[4][4];
#pragma unroll
    for (int i = 0; i < 4; ++i)
#pragma unroll
      for (int j = 0; j < 4; ++j) s[i][j] = 0.0f;

    for (int d0 = 0; d0 < DHEAD; d0 += 4) {
      float4 qv[4], kv[4];
#pragma unroll
      for (int i = 0; i < 4; ++i)
        qv[i] = *(const float4*)(Qs + (ty * 4 + i) * PADW + d0);
#pragma unroll
      for (int dd = 0; dd < 4; ++dd)
        kv[dd] = *(const float4*)(KT + (d0 + dd) * PADW + tx * 4);
#pragma unroll
      for (int i = 0; i < 4; ++i) {
        const float* qa = (const float*)&qv[i];
#pragma unroll
        for (int dd = 0; dd < 4; ++dd) {
          const float* kb = (const float*)&kv[dd];
#pragma unroll
          for (int j = 0; j < 4; ++j) s[i][j] += qa[dd] * kb[j];
        }
      }
    }

#pragma unroll
    for (int i = 0; i < 4; ++i)
#pragma unroll
      for (int j = 0; j < 4; ++j) s[i][j] *= 0.125f;

    if (kt == qt) {  // causal mask within diagonal tile
#pragma unroll
      for (int i = 0; i < 4; ++i)
#pragma unroll
        for (int j = 0; j < 4; ++j)
          if (tx * 4 + j > ty * 4 + i) s[i][j] = -1e30f;
    }

    // Online softmax per q-row (reduce across the 16 tx lanes).
#pragma unroll
    for (int i = 0; i < 4; ++i) {
      float rm = fmaxf(fmaxf(s[i][0], s[i][1]), fmaxf(s[i][2], s[i][3]));
#pragma unroll
      for (int off = 1; off < 16; off <<= 1)
        rm = fmaxf(rm, __shfl_xor(rm, off, 64));
      float mn = fmaxf(m_i[i], rm);
      float sc = __expf(m_i[i] - mn);
      float rs = 0.0f;
#pragma unroll
      for (int j = 0; j < 4; ++j) {
        float p = __expf(s[i][j] - mn);
        s[i][j] = p;
        rs += p;
      }
#pragma unroll
      for (int off = 1; off < 16; off <<= 1)
        rs += __shfl_xor(rs, off, 64);
      l_i[i] = l_i[i] * sc + rs;
      m_i[i] = mn;
#pragma unroll
      for (int j = 0; j < 4; ++j) acc[i][j] *= sc;
    }

    __syncthreads();  // everyone done reading KT before overwrite with P

#pragma unroll
    for (int i = 0; i < 4; ++i) {
      float4 pv;
      ((float*)&pv)[0] = s[i][0];
      ((float*)&pv)[1] = s[i][1];
      ((float*)&pv)[2] = s[i][2];
      ((float*)&pv)[3] = s[i][3];
      *(float4*)(Ps + (ty * 4 + i) * PADW + tx * 4) = pv;
    }
    __syncthreads();

    // O += P * V : acc[i][j] += sum_k Ps[row_i][k] * Vs[k][tx*4+j]
    for (int k0 = 0; k0 < 64; k0 += 4) {
      float4 pr[4], vv[4];
#pragma unroll
      for (int i = 0; i < 4; ++i)
        pr[i] = *(const float4*)(Ps + (ty * 4 + i) * PADW + k0);
#pragma unroll
      for (int kk = 0; kk < 4; ++kk)
        vv[kk] = *(const float4*)(Vs + (k0 + kk) * PADW + tx * 4);
#pragma unroll
      for (int i = 0; i < 4; ++i) {
        const float* pa = (const float*)&pr[i];
#pragma unroll
        for (int kk = 0; kk < 4; ++kk) {
          const float* vb = (const float*)&vv[kk];
#pragma unroll
          for (int j = 0; j < 4; ++j) acc[i][j] += pa[kk] * vb[j];
        }
      }
    }
  }

  // Final: y[b, qrow, h*64 + d] = acc / l
#pragma unroll
  for (int i = 0; i < 4; ++i) {
    float inv = 1.0f / l_i[i];
    int row = qt * 64 + ty * 4 + i;
    float4 o;
    ((float*)&o)[0] = acc[i][0] * inv;
    ((float*)&o)[1] = acc[i][1] * inv;
    ((float*)&o)[2] = acc[i][2] * inv;
    ((float*)&o)[3] = acc[i][3] * inv;
    *(float4*)(y + (size_t)(b * TT + row) * CC + h * DHEAD + tx * 4) = o;
  }
}

extern "C" void kernel_launch(void* const* d_in, const int* in_sizes, int n_in,
                              void* d_out, int out_size, void* d_ws, size_t ws_size,
                              hipStream_t stream) {
  const float* x      = (const float*)d_in[0];  // [B,T,C]
  const float* W_attn = (const float*)d_in[1];  // [C,3C]
  const float* b_attn = (const float*)d_in[2];  // [3C]
  const float* W_proj = (const float*)d_in[3];  // [C,C]
  const float* b_proj = (const float*)d_in[4];  // [C]
  float* out = (float*)d_out;                   // [B,T,C]

  float* qkv = (float*)d_ws;                    // B*T*3C floats
  float* y   = qkv + (size_t)BB * TT * 3 * CC;  // B*T*C floats

  const int M = BB * TT;  // 4096

  // GEMM1: qkv = x @ W_attn + b_attn   (M=4096, N=3072, K=1024)
  {
    dim3 grid((3 * CC) / 64, M / 64);
    gemm_bias_kernel<<<grid, 256, 0, stream>>>(x, W_attn, b_attn, qkv, M, 3 * CC, CC);
  }

  // Flash attention: grid (q-tiles, B*H)
  {
    dim3 grid(TT / 64, BB * NHEAD);
    flash_attn_kernel<<<grid, 256, 0, stream>>>(qkv, y);
  }

  // GEMM2: out = y @ W_proj + b_proj   (M=4096, N=1024, K=1024)
  {
    dim3 grid(CC / 64, M / 64);
    gemm_bias_kernel<<<grid, 256, 0, stream>>>(y, W_proj, b_proj, out, M, CC, CC);
  }
}

// Round 3
// 578.242 us; speedup vs baseline: 6.9792x; 1.9827x over previous
//
#include <hip/hip_runtime.h>

#define BB 2
#define TT 2048
#define CC 1024
#define NHEAD 16
#define DHEAD 64
#define PADW 68   // LDS row stride (floats) in flash kernel

typedef __attribute__((ext_vector_type(8))) short short8;     // bf16x8 MFMA frag
typedef __attribute__((ext_vector_type(8))) unsigned short ushort8;
typedef __attribute__((ext_vector_type(4))) float floatx4;

__device__ inline unsigned short f32_to_bf16_rne(float f) {
  unsigned u = __builtin_bit_cast(unsigned, f);
  unsigned r = (u + 0x7FFFu + ((u >> 16) & 1u)) >> 16;
  return (unsigned short)r;
}
__device__ inline float bf16_to_f32(unsigned short u) {
  return __builtin_bit_cast(float, (unsigned)u << 16);
}
__device__ inline void gload_lds16(const void* g, void* l) {
  __builtin_amdgcn_global_load_lds(
      (const __attribute__((address_space(1))) void*)g,
      (__attribute__((address_space(3))) void*)l, 16, 0, 0);
}

// ---------------------------------------------------------------------------
// fp32 -> bf16 straight convert (n divisible by 1024)
// ---------------------------------------------------------------------------
__global__ __launch_bounds__(256) void cvt_bf16_kernel(
    const float* __restrict__ in, unsigned short* __restrict__ outp, int n) {
  int i = (blockIdx.x * 256 + threadIdx.x) * 4;
  if (i < n) {
    float4 v = *(const float4*)(in + i);
    ushort4 o;
    o.x = f32_to_bf16_rne(v.x);
    o.y = f32_to_bf16_rne(v.y);
    o.z = f32_to_bf16_rne(v.z);
    o.w = f32_to_bf16_rne(v.w);
    *(ushort4*)(outp + i) = o;
  }
}

// ---------------------------------------------------------------------------
// W[K][N] fp32 -> Wt[N][K] bf16 (32x32 LDS tile transpose)
// ---------------------------------------------------------------------------
__global__ __launch_bounds__(256) void transpose_cvt_kernel(
    const float* __restrict__ W, unsigned short* __restrict__ Wt, int K, int N) {
  __shared__ float T[32][33];
  const int tx = threadIdx.x & 31;
  const int ty = threadIdx.x >> 5;   // 0..7
  const int r0 = blockIdx.y * 32;
  const int c0 = blockIdx.x * 32;
#pragma unroll
  for (int i = 0; i < 4; ++i)
    T[ty + i * 8][tx] = W[(size_t)(r0 + ty + i * 8) * N + c0 + tx];
  __syncthreads();
#pragma unroll
  for (int i = 0; i < 4; ++i)
    Wt[(size_t)(c0 + ty + i * 8) * K + r0 + tx] = f32_to_bf16_rne(T[tx][ty + i * 8]);
}

// ---------------------------------------------------------------------------
// bf16 MFMA GEMM: C[M][N] = A[M][K] @ Bt[N][K]^T + bias[N]
// 128x128 tile, BK=32, 256 threads (4 waves, 2x2 of 64x64), 16 MFMA/wave/step.
// A, Bt bf16; accum fp32; output bf16 or fp32.
// ---------------------------------------------------------------------------
template <bool BF16_OUT>
__global__ __launch_bounds__(256) void gemm_mfma_kernel(
    const unsigned short* __restrict__ A, const unsigned short* __restrict__ Bt,
    const float* __restrict__ bias, void* __restrict__ Cout,
    int M, int N, int K) {
  __shared__ unsigned short As[128 * 32];
  __shared__ unsigned short Bs[128 * 32];

  const int tid = threadIdx.x;
  const int wave = tid >> 6;
  const int lane = tid & 63;
  const int row0 = blockIdx.y * 128;
  const int col0 = blockIdx.x * 128;
  const int wr = (wave >> 1) * 64;
  const int wc = (wave & 1) * 64;

  floatx4 acc[4][4];
#pragma unroll
  for (int m = 0; m < 4; ++m)
#pragma unroll
    for (int n = 0; n < 4; ++n) acc[m][n] = (floatx4){0.f, 0.f, 0.f, 0.f};

  const int sRow = lane >> 2;        // 0..15
  const int sK = (lane & 3) * 8;     // k element offset for staging

  for (int k0 = 0; k0 < K; k0 += 32) {
#pragma unroll
    for (int c = 0; c < 2; ++c) {
      const int g = c * 4 + wave;    // 16-row group 0..7
      gload_lds16(A + (size_t)(row0 + g * 16 + sRow) * K + k0 + sK,
                  (char*)As + g * 1024);
      gload_lds16(Bt + (size_t)(col0 + g * 16 + sRow) * K + k0 + sK,
                  (char*)Bs + g * 1024);
    }
    __syncthreads();

    short8 af[4], bf[4];
#pragma unroll
    for (int m = 0; m < 4; ++m)
      af[m] = *(const short8*)(As + (wr + m * 16 + (lane & 15)) * 32 + (lane >> 4) * 8);
#pragma unroll
    for (int n = 0; n < 4; ++n)
      bf[n] = *(const short8*)(Bs + (wc + n * 16 + (lane & 15)) * 32 + (lane >> 4) * 8);
#pragma unroll
    for (int m = 0; m < 4; ++m)
#pragma unroll
      for (int n = 0; n < 4; ++n)
        acc[m][n] = __builtin_amdgcn_mfma_f32_16x16x32_bf16(af[m], bf[n], acc[m][n], 0, 0, 0);
    __syncthreads();
  }

  const int cl = lane & 15;
  const int rg = (lane >> 4) * 4;
#pragma unroll
  for (int m = 0; m < 4; ++m) {
#pragma unroll
    for (int n = 0; n < 4; ++n) {
      const int col = col0 + wc + n * 16 + cl;
      const float b = bias[col];
#pragma unroll
      for (int r = 0; r < 4; ++r) {
        const int row = row0 + wr + m * 16 + rg + r;
        const float v = acc[m][n][r] + b;
        if (BF16_OUT)
          ((unsigned short*)Cout)[(size_t)row * N + col] = f32_to_bf16_rne(v);
        else
          ((float*)Cout)[(size_t)row * N + col] = v;
      }
    }
  }
}

// ---------------------------------------------------------------------------
// Flash-style causal attention, fp32 compute, bf16 qkv in / bf16 y out.
// Grid: (T/64, B*NHEAD). Block 256. Thread (tx,ty): q-rows ty*4+i, cols tx*4+j.
// ---------------------------------------------------------------------------
__global__ __launch_bounds__(256) void flash_attn_kernel(
    const unsigned short* __restrict__ qkv, unsigned short* __restrict__ y) {
  __shared__ float smem[3 * 64 * PADW];
  float* Qs = smem;
  float* KT = smem + 64 * PADW;      // [d][krow]
  float* Vs = smem + 2 * 64 * PADW;  // [krow][d]
  float* Ps = KT;                    // alias

  const int qt = blockIdx.x;
  const int bh = blockIdx.y;
  const int h = bh & (NHEAD - 1);
  const int b = bh >> 4;
  const int tid = threadIdx.x;
  const int tx = tid & 15;
  const int ty = tid >> 4;

  const size_t baseQ = (size_t)(b * TT) * (3 * CC) + h * DHEAD;
  const size_t baseK = baseQ + CC;
  const size_t baseV = baseQ + 2 * CC;

  // Q tile: 64 rows x 64 d, 8 bf16 per thread x2
#pragma unroll
  for (int c = 0; c < 2; ++c) {
    int e = c * 256 + tid;
    int r = e >> 3;
    int d8 = (e & 7) * 8;
    ushort8 v = *(const ushort8*)(qkv + baseQ + (size_t)(qt * 64 + r) * (3 * CC) + d8);
#pragma unroll
    for (int i = 0; i < 8; ++i) Qs[r * PADW + d8 + i] = bf16_to_f32(v[i]);
  }

  float m_i[4], l_i[4], acc[4][4];
#pragma unroll
  for (int i = 0; i < 4; ++i) {
    m_i[i] = -1e30f;
    l_i[i] = 0.0f;
#pragma unroll
    for (int j = 0; j < 4; ++j) acc[i][j] = 0.0f;
  }

  for (int kt = 0; kt <= qt; ++kt) {
    __syncthreads();

    // K tile transposed into KT[d][krow]
#pragma unroll
    for (int c = 0; c < 16; ++c) {
      int e = c * 256 + tid;
      int r = e >> 6;
      int d = e & 63;
      KT[d * PADW + r] = bf16_to_f32(qkv[baseK + (size_t)(kt * 64 + r) * (3 * CC) + d]);
    }
    // V tile straight
#pragma unroll
    for (int c = 0; c < 2; ++c) {
      int e = c * 256 + tid;
      int r = e >> 3;
      int d8 = (e & 7) * 8;
      ushort8 v = *(const ushort8*)(qkv + baseV + (size_t)(kt * 64 + r) * (3 * CC) + d8);
#pragma unroll
      for (int i = 0; i < 8; ++i) Vs[r * PADW + d8 + i] = bf16_to_f32(v[i]);
    }
    __syncthreads();

    float s[4][4];
#pragma unroll
    for (int i = 0; i < 4; ++i)
#pragma unroll
      for (int j = 0; j < 4; ++j) s[i][j] = 0.0f;

    for (int d0 = 0; d0 < DHEAD; d0 += 4) {
      float4 qv[4], kv[4];
#pragma unroll
      for (int i = 0; i < 4; ++i)
        qv[i] = *(const float4*)(Qs + (ty * 4 + i) * PADW + d0);
#pragma unroll
      for (int dd = 0; dd < 4; ++dd)
        kv[dd] = *(const float4*)(KT + (d0 + dd) * PADW + tx * 4);
#pragma unroll
      for (int i = 0; i < 4; ++i) {
        const float* qa = (const float*)&qv[i];
#pragma unroll
        for (int dd = 0; dd < 4; ++dd) {
          const float* kb = (const float*)&kv[dd];
#pragma unroll
          for (int j = 0; j < 4; ++j) s[i][j] += qa[dd] * kb[j];
        }
      }
    }

#pragma unroll
    for (int i = 0; i < 4; ++i)
#pragma unroll
      for (int j = 0; j < 4; ++j) s[i][j] *= 0.125f;

    if (kt == qt) {
#pragma unroll
      for (int i = 0; i < 4; ++i)
#pragma unroll
        for (int j = 0; j < 4; ++j)
          if (tx * 4 + j > ty * 4 + i) s[i][j] = -1e30f;
    }

#pragma unroll
    for (int i = 0; i < 4; ++i) {
      float rm = fmaxf(fmaxf(s[i][0], s[i][1]), fmaxf(s[i][2], s[i][3]));
#pragma unroll
      for (int off = 1; off < 16; off <<= 1)
        rm = fmaxf(rm, __shfl_xor(rm, off, 64));
      float mn = fmaxf(m_i[i], rm);
      float sc = __expf(m_i[i] - mn);
      float rs = 0.0f;
#pragma unroll
      for (int j = 0; j < 4; ++j) {
        float p = __expf(s[i][j] - mn);
        s[i][j] = p;
        rs += p;
      }
#pragma unroll
      for (int off = 1; off < 16; off <<= 1)
        rs += __shfl_xor(rs, off, 64);
      l_i[i] = l_i[i] * sc + rs;
      m_i[i] = mn;
#pragma unroll
      for (int j = 0; j < 4; ++j) acc[i][j] *= sc;
    }

    __syncthreads();  // done reading KT

#pragma unroll
    for (int i = 0; i < 4; ++i) {
      float4 pv;
      ((float*)&pv)[0] = s[i][0];
      ((float*)&pv)[1] = s[i][1];
      ((float*)&pv)[2] = s[i][2];
      ((float*)&pv)[3] = s[i][3];
      *(float4*)(Ps + (ty * 4 + i) * PADW + tx * 4) = pv;
    }
    __syncthreads();

    for (int k0 = 0; k0 < 64; k0 += 4) {
      float4 pr[4], vv[4];
#pragma unroll
      for (int i = 0; i < 4; ++i)
        pr[i] = *(const float4*)(Ps + (ty * 4 + i) * PADW + k0);
#pragma unroll
      for (int kk = 0; kk < 4; ++kk)
        vv[kk] = *(const float4*)(Vs + (k0 + kk) * PADW + tx * 4);
#pragma unroll
      for (int i = 0; i < 4; ++i) {
        const float* pa = (const float*)&pr[i];
#pragma unroll
        for (int kk = 0; kk < 4; ++kk) {
          const float* vb = (const float*)&vv[kk];
#pragma unroll
          for (int j = 0; j < 4; ++j) acc[i][j] += pa[kk] * vb[j];
        }
      }
    }
  }

#pragma unroll
  for (int i = 0; i < 4; ++i) {
    float inv = 1.0f / l_i[i];
    int row = qt * 64 + ty * 4 + i;
    ushort4 o;
    o.x = f32_to_bf16_rne(acc[i][0] * inv);
    o.y = f32_to_bf16_rne(acc[i][1] * inv);
    o.z = f32_to_bf16_rne(acc[i][2] * inv);
    o.w = f32_to_bf16_rne(acc[i][3] * inv);
    *(ushort4*)(y + (size_t)(b * TT + row) * CC + h * DHEAD + tx * 4) = o;
  }
}

extern "C" void kernel_launch(void* const* d_in, const int* in_sizes, int n_in,
                              void* d_out, int out_size, void* d_ws, size_t ws_size,
                              hipStream_t stream) {
  const float* x      = (const float*)d_in[0];  // [B,T,C]
  const float* W_attn = (const float*)d_in[1];  // [C,3C]
  const float* b_attn = (const float*)d_in[2];  // [3C]
  const float* W_proj = (const float*)d_in[3];  // [C,C]
  const float* b_proj = (const float*)d_in[4];  // [C]
  float* out = (float*)d_out;                   // [B,T,C] fp32

  const int M = BB * TT;  // 4096

  // workspace layout (ushort units)
  unsigned short* qkvb = (unsigned short*)d_ws;              // M * 3C
  unsigned short* xb   = qkvb + (size_t)M * 3 * CC;          // M * C
  unsigned short* Wat  = xb + (size_t)M * CC;                // 3C * C (transposed)
  unsigned short* Wpt  = Wat + (size_t)3 * CC * CC;          // C * C (transposed)
  unsigned short* yb   = Wpt + (size_t)CC * CC;              // M * C

  // converts
  cvt_bf16_kernel<<<(M * CC) / 1024, 256, 0, stream>>>(x, xb, M * CC);
  {
    dim3 g((3 * CC) / 32, CC / 32);
    transpose_cvt_kernel<<<g, 256, 0, stream>>>(W_attn, Wat, CC, 3 * CC);
  }
  {
    dim3 g(CC / 32, CC / 32);
    transpose_cvt_kernel<<<g, 256, 0, stream>>>(W_proj, Wpt, CC, CC);
  }

  // GEMM1: qkvb = xb @ Wat^T + b_attn  (M=4096, N=3072, K=1024), bf16 out
  {
    dim3 grid((3 * CC) / 128, M / 128);
    gemm_mfma_kernel<true><<<grid, 256, 0, stream>>>(xb, Wat, b_attn, qkvb, M, 3 * CC, CC);
  }

  // flash attention
  {
    dim3 grid(TT / 64, BB * NHEAD);
    flash_attn_kernel<<<grid, 256, 0, stream>>>(qkvb, yb);
  }

  // GEMM2: out = yb @ Wpt^T + b_proj  (M=4096, N=1024, K=1024), fp32 out
  {
    dim3 grid(CC / 128, M / 128);
    gemm_mfma_kernel<false><<<grid, 256, 0, stream>>>(yb, Wpt, b_proj, out, M, CC, CC);
  }
}

// Round 4
// 225.452 us; speedup vs baseline: 17.9003x; 2.5648x over previous
//
#include <hip/hip_runtime.h>

#define BB 2
#define TT 2048
#define CC 1024
#define NHEAD 16
#define DHEAD 64

typedef __attribute__((ext_vector_type(8))) short short8;     // bf16x8 MFMA frag
typedef __attribute__((ext_vector_type(8))) unsigned short ushort8;
typedef __attribute__((ext_vector_type(4))) float floatx4;

__device__ inline unsigned short f32_to_bf16_rne(float f) {
  unsigned u = __builtin_bit_cast(unsigned, f);
  unsigned r = (u + 0x7FFFu + ((u >> 16) & 1u)) >> 16;
  return (unsigned short)r;
}
__device__ inline float bf16_to_f32(unsigned short u) {
  return __builtin_bit_cast(float, (unsigned)u << 16);
}
__device__ inline void gload_lds16(const void* g, void* l) {
  __builtin_amdgcn_global_load_lds(
      (const __attribute__((address_space(1))) void*)g,
      (__attribute__((address_space(3))) void*)l, 16, 0, 0);
}

// ---------------------------------------------------------------------------
// fp32 -> bf16 straight convert
// ---------------------------------------------------------------------------
__global__ __launch_bounds__(256) void cvt_bf16_kernel(
    const float* __restrict__ in, unsigned short* __restrict__ outp, int n) {
  int i = (blockIdx.x * 256 + threadIdx.x) * 4;
  if (i < n) {
    float4 v = *(const float4*)(in + i);
    ushort4 o;
    o.x = f32_to_bf16_rne(v.x);
    o.y = f32_to_bf16_rne(v.y);
    o.z = f32_to_bf16_rne(v.z);
    o.w = f32_to_bf16_rne(v.w);
    *(ushort4*)(outp + i) = o;
  }
}

// ---------------------------------------------------------------------------
// W[K][N] fp32 -> Wt[N][K] bf16 (32x32 LDS tile transpose)
// ---------------------------------------------------------------------------
__global__ __launch_bounds__(256) void transpose_cvt_kernel(
    const float* __restrict__ W, unsigned short* __restrict__ Wt, int K, int N) {
  __shared__ float T[32][33];
  const int tx = threadIdx.x & 31;
  const int ty = threadIdx.x >> 5;
  const int r0 = blockIdx.y * 32;
  const int c0 = blockIdx.x * 32;
#pragma unroll
  for (int i = 0; i < 4; ++i)
    T[ty + i * 8][tx] = W[(size_t)(r0 + ty + i * 8) * N + c0 + tx];
  __syncthreads();
#pragma unroll
  for (int i = 0; i < 4; ++i)
    Wt[(size_t)(c0 + ty + i * 8) * K + r0 + tx] = f32_to_bf16_rne(T[tx][ty + i * 8]);
}

// ---------------------------------------------------------------------------
// bf16 MFMA GEMM: C[M][N] = A[M][K] @ Bt[N][K]^T + bias[N]
// 128x128 tile, BK=32, 256 threads (4 waves, 2x2 of 64x64).
// VSPLIT: for N-cols >= 2C (the V part of qkv), write transposed bf16 into
// vTp[b][h][d][T] instead of Cout.
// ---------------------------------------------------------------------------
template <bool BF16_OUT, bool VSPLIT>
__global__ __launch_bounds__(256) void gemm_mfma_kernel(
    const unsigned short* __restrict__ A, const unsigned short* __restrict__ Bt,
    const float* __restrict__ bias, void* __restrict__ Cout,
    unsigned short* __restrict__ vTp, int M, int N, int K) {
  __shared__ unsigned short As[128 * 32];
  __shared__ unsigned short Bs[128 * 32];

  const int tid = threadIdx.x;
  const int wave = tid >> 6;
  const int lane = tid & 63;
  const int row0 = blockIdx.y * 128;
  const int col0 = blockIdx.x * 128;
  const int wr = (wave >> 1) * 64;
  const int wc = (wave & 1) * 64;

  floatx4 acc[4][4];
#pragma unroll
  for (int m = 0; m < 4; ++m)
#pragma unroll
    for (int n = 0; n < 4; ++n) acc[m][n] = (floatx4){0.f, 0.f, 0.f, 0.f};

  const int sRow = lane >> 2;
  const int sK = (lane & 3) * 8;

  for (int k0 = 0; k0 < K; k0 += 32) {
#pragma unroll
    for (int c = 0; c < 2; ++c) {
      const int g = c * 4 + wave;
      gload_lds16(A + (size_t)(row0 + g * 16 + sRow) * K + k0 + sK,
                  (char*)As + g * 1024);
      gload_lds16(Bt + (size_t)(col0 + g * 16 + sRow) * K + k0 + sK,
                  (char*)Bs + g * 1024);
    }
    __syncthreads();

    short8 af[4], bf[4];
#pragma unroll
    for (int m = 0; m < 4; ++m)
      af[m] = *(const short8*)(As + (wr + m * 16 + (lane & 15)) * 32 + (lane >> 4) * 8);
#pragma unroll
    for (int n = 0; n < 4; ++n)
      bf[n] = *(const short8*)(Bs + (wc + n * 16 + (lane & 15)) * 32 + (lane >> 4) * 8);
#pragma unroll
    for (int m = 0; m < 4; ++m)
#pragma unroll
      for (int n = 0; n < 4; ++n)
        acc[m][n] = __builtin_amdgcn_mfma_f32_16x16x32_bf16(af[m], bf[n], acc[m][n], 0, 0, 0);
    __syncthreads();
  }

  const int cl = lane & 15;
  const int rg = (lane >> 4) * 4;

  if (VSPLIT && col0 >= 2 * CC) {
    // V part: write transposed into vT[b][h][d][T], packed 4 tokens (bf16x4)
#pragma unroll
    for (int m = 0; m < 4; ++m) {
#pragma unroll
      for (int n = 0; n < 4; ++n) {
        const int col = col0 + wc + n * 16 + cl;
        const float bsv = bias[col];
        const int hh = (col - 2 * CC) >> 6;
        const int dd = col & (DHEAD - 1);
        const int t0r = row0 + wr + m * 16 + rg;  // 4-aligned global row
        const int bb = t0r >> 11;
        const int tt = t0r & (TT - 1);
        ushort4 o;
        o.x = f32_to_bf16_rne(acc[m][n][0] + bsv);
        o.y = f32_to_bf16_rne(acc[m][n][1] + bsv);
        o.z = f32_to_bf16_rne(acc[m][n][2] + bsv);
        o.w = f32_to_bf16_rne(acc[m][n][3] + bsv);
        *(ushort4*)(vTp + ((size_t)((bb * NHEAD + hh) * DHEAD + dd)) * TT + tt) = o;
      }
    }
  } else {
#pragma unroll
    for (int m = 0; m < 4; ++m) {
#pragma unroll
      for (int n = 0; n < 4; ++n) {
        const int col = col0 + wc + n * 16 + cl;
        const float bv = bias[col];
#pragma unroll
        for (int r = 0; r < 4; ++r) {
          const int row = row0 + wr + m * 16 + rg + r;
          const float v = acc[m][n][r] + bv;
          if (BF16_OUT)
            ((unsigned short*)Cout)[(size_t)row * N + col] = f32_to_bf16_rne(v);
          else
            ((float*)Cout)[(size_t)row * N + col] = v;
        }
      }
    }
  }
}

// ---------------------------------------------------------------------------
// MFMA flash attention (bf16 inputs, fp32 softmax/accum, bf16 out).
// Grid: (T/64 q-tiles reversed, B*H). Block 256 = 4 waves; each wave owns
// 16 q-rows. K staged from qkv, V^T staged from vT, both via global_load_lds
// with XOR-swizzled source (chunk ^= row&7) for conflict-free b128 reads.
// ---------------------------------------------------------------------------
__global__ __launch_bounds__(256) void flash_mfma_kernel(
    const unsigned short* __restrict__ qkv,
    const unsigned short* __restrict__ vT,
    unsigned short* __restrict__ y) {
  __shared__ unsigned short Ks[64 * 64];     // [token][d-chunk swz]
  __shared__ unsigned short Vs[64 * 64];     // [d][k-chunk swz]
  __shared__ unsigned short Ps[4][16 * 64];  // per-wave P tile [q][k swz]

  const int qt = (TT / 64 - 1) - blockIdx.x;  // longest blocks first
  const int bh = blockIdx.y;
  const int h = bh & (NHEAD - 1);
  const int b = bh >> 4;
  const int tid = threadIdx.x;
  const int wq = tid >> 6;
  const int lane = tid & 63;
  const int l15 = lane & 15;
  const int l4 = lane >> 4;
  const int srow = lane >> 3;   // 0..7
  const int schunk = lane & 7;  // 0..7

  const size_t baseQ = (size_t)(b * TT) * (3 * CC) + h * DHEAD;
  const size_t baseK = baseQ + CC;
  const size_t vbase = (size_t)((b * NHEAD + h) * DHEAD) * TT;

  // Q A-frags, register-resident (wave's 16 q-rows x 64 d)
  short8 aq[2];
  {
    const unsigned short* qp =
        qkv + baseQ + (size_t)(qt * 64 + wq * 16 + l15) * (3 * CC) + l4 * 8;
    aq[0] = *(const short8*)(qp);
    aq[1] = *(const short8*)(qp + 32);
  }

  floatx4 accO[4];
  float m_i[4], l_i[4];
#pragma unroll
  for (int i = 0; i < 4; ++i) {
    accO[i] = (floatx4){0.f, 0.f, 0.f, 0.f};
    m_i[i] = -1e30f;
    l_i[i] = 0.f;
  }

  for (int kt = 0; kt <= qt; ++kt) {
    __syncthreads();  // previous iteration's LDS reads complete
#pragma unroll
    for (int it = 0; it < 2; ++it) {
      const int blk = it * 4 + wq;      // 8-row group, wave-uniform
      const int grow = blk * 8 + srow;  // row within tile
      gload_lds16(
          qkv + baseK + (size_t)(kt * 64 + grow) * (3 * CC) + (schunk ^ srow) * 8,
          (char*)Ks + blk * 1024);
      gload_lds16(
          vT + vbase + (size_t)grow * TT + kt * 64 + (schunk ^ srow) * 8,
          (char*)Vs + blk * 1024);
    }
    __syncthreads();  // staging complete

    // S = Q K^T (wave's 16 q x 64 k), 8 MFMA
    floatx4 sa[4];
#pragma unroll
    for (int n = 0; n < 4; ++n) sa[n] = (floatx4){0.f, 0.f, 0.f, 0.f};
#pragma unroll
    for (int kc = 0; kc < 2; ++kc) {
#pragma unroll
      for (int n = 0; n < 4; ++n) {
        const int row = 16 * n + l15;
        short8 bk = *(const short8*)(Ks + row * 64 + ((kc * 4 + l4) ^ (row & 7)) * 8);
        sa[n] = __builtin_amdgcn_mfma_f32_16x16x32_bf16(aq[kc], bk, sa[n], 0, 0, 0);
      }
    }

    // online softmax; lane holds rows l4*4+r (r=0..3), cols 16n+l15
    float pv[4][4];
    const bool diag = (kt == qt);
#pragma unroll
    for (int r = 0; r < 4; ++r) {
      const int qg = qt * 64 + wq * 16 + l4 * 4 + r;
      float rm = -1e30f;
#pragma unroll
      for (int n = 0; n < 4; ++n) {
        float s = sa[n][r] * 0.125f;
        if (diag) {
          const int kg = kt * 64 + 16 * n + l15;
          if (kg > qg) s = -1e30f;
        }
        pv[n][r] = s;
        rm = fmaxf(rm, s);
      }
#pragma unroll
      for (int off = 1; off < 16; off <<= 1)
        rm = fmaxf(rm, __shfl_xor(rm, off, 64));
      const float mn = fmaxf(m_i[r], rm);
      const float scale = __expf(m_i[r] - mn);
      float rs = 0.f;
#pragma unroll
      for (int n = 0; n < 4; ++n) {
        const float p = __expf(pv[n][r] - mn);
        pv[n][r] = p;
        rs += p;
      }
#pragma unroll
      for (int off = 1; off < 16; off <<= 1)
        rs += __shfl_xor(rs, off, 64);
      l_i[r] = l_i[r] * scale + rs;
      m_i[r] = mn;
#pragma unroll
      for (int nd = 0; nd < 4; ++nd) accO[nd][r] *= scale;
    }

    // P -> per-wave LDS (bf16, same chunk-XOR swizzle)
    unsigned short* Pw = Ps[wq];
#pragma unroll
    for (int n = 0; n < 4; ++n) {
#pragma unroll
      for (int r = 0; r < 4; ++r) {
        const int row = l4 * 4 + r;
        const int col = 16 * n + l15;
        Pw[row * 64 + ((col >> 3) ^ (row & 7)) * 8 + (col & 7)] =
            f32_to_bf16_rne(pv[n][r]);
      }
    }
    asm volatile("s_waitcnt lgkmcnt(0)" ::: "memory");  // same-wave RAW safety

    // O += P V, 8 MFMA
    short8 pa[2];
#pragma unroll
    for (int kc = 0; kc < 2; ++kc)
      pa[kc] = *(const short8*)(Pw + l15 * 64 + ((kc * 4 + l4) ^ (l15 & 7)) * 8);
#pragma unroll
    for (int kc = 0; kc < 2; ++kc) {
#pragma unroll
      for (int nd = 0; nd < 4; ++nd) {
        const int row = 16 * nd + l15;
        short8 vb = *(const short8*)(Vs + row * 64 + ((kc * 4 + l4) ^ (row & 7)) * 8);
        accO[nd] = __builtin_amdgcn_mfma_f32_16x16x32_bf16(pa[kc], vb, accO[nd], 0, 0, 0);
      }
    }
  }

  // epilogue: y[b, q, h*64+d] = O / l
#pragma unroll
  for (int r = 0; r < 4; ++r) {
    const float inv = 1.0f / l_i[r];
    const int qg = qt * 64 + wq * 16 + l4 * 4 + r;
#pragma unroll
    for (int nd = 0; nd < 4; ++nd) {
      y[(size_t)(b * TT + qg) * CC + h * DHEAD + 16 * nd + l15] =
          f32_to_bf16_rne(accO[nd][r] * inv);
    }
  }
}

extern "C" void kernel_launch(void* const* d_in, const int* in_sizes, int n_in,
                              void* d_out, int out_size, void* d_ws, size_t ws_size,
                              hipStream_t stream) {
  const float* x      = (const float*)d_in[0];
  const float* W_attn = (const float*)d_in[1];
  const float* b_attn = (const float*)d_in[2];
  const float* W_proj = (const float*)d_in[3];
  const float* b_proj = (const float*)d_in[4];
  float* out = (float*)d_out;

  const int M = BB * TT;  // 4096

  // workspace layout (ushort units)
  unsigned short* qkvb = (unsigned short*)d_ws;          // M * 3C (V part unused)
  unsigned short* xb   = qkvb + (size_t)M * 3 * CC;      // M * C
  unsigned short* Wat  = xb + (size_t)M * CC;            // 3C * C
  unsigned short* Wpt  = Wat + (size_t)3 * CC * CC;      // C * C
  unsigned short* yb   = Wpt + (size_t)CC * CC;          // M * C
  unsigned short* vTb  = yb + (size_t)M * CC;            // B*H*D*T

  cvt_bf16_kernel<<<(M * CC) / 1024, 256, 0, stream>>>(x, xb, M * CC);
  {
    dim3 g((3 * CC) / 32, CC / 32);
    transpose_cvt_kernel<<<g, 256, 0, stream>>>(W_attn, Wat, CC, 3 * CC);
  }
  {
    dim3 g(CC / 32, CC / 32);
    transpose_cvt_kernel<<<g, 256, 0, stream>>>(W_proj, Wpt, CC, CC);
  }

  // GEMM1: qkv = x @ W_attn + b_attn; V third goes transposed to vTb
  {
    dim3 grid((3 * CC) / 128, M / 128);
    gemm_mfma_kernel<true, true><<<grid, 256, 0, stream>>>(
        xb, Wat, b_attn, qkvb, vTb, M, 3 * CC, CC);
  }

  // MFMA flash attention
  {
    dim3 grid(TT / 64, BB * NHEAD);
    flash_mfma_kernel<<<grid, 256, 0, stream>>>(qkvb, vTb, yb);
  }

  // GEMM2: out = y @ W_proj + b_proj (fp32 out)
  {
    dim3 grid(CC / 128, M / 128);
    gemm_mfma_kernel<false, false><<<grid, 256, 0, stream>>>(
        yb, Wpt, b_proj, out, nullptr, M, CC, CC);
  }
}

// Round 5
// 215.470 us; speedup vs baseline: 18.7296x; 1.0463x over previous
//
#include <hip/hip_runtime.h>

#define BB 2
#define TT 2048
#define CC 1024
#define NHEAD 16
#define DHEAD 64

typedef __attribute__((ext_vector_type(8))) short short8;     // bf16x8 MFMA frag
typedef __attribute__((ext_vector_type(8))) unsigned short ushort8;
typedef __attribute__((ext_vector_type(4))) float floatx4;

__device__ inline unsigned short f32_to_bf16_rne(float f) {
  unsigned u = __builtin_bit_cast(unsigned, f);
  unsigned r = (u + 0x7FFFu + ((u >> 16) & 1u)) >> 16;
  return (unsigned short)r;
}
__device__ inline float bf16_to_f32(unsigned short u) {
  return __builtin_bit_cast(float, (unsigned)u << 16);
}
__device__ inline void gload_lds16(const void* g, void* l) {
  __builtin_amdgcn_global_load_lds(
      (const __attribute__((address_space(1))) void*)g,
      (__attribute__((address_space(3))) void*)l, 16, 0, 0);
}

// ---------------------------------------------------------------------------
// fp32 -> bf16 straight convert
// ---------------------------------------------------------------------------
__global__ __launch_bounds__(256) void cvt_bf16_kernel(
    const float* __restrict__ in, unsigned short* __restrict__ outp, int n) {
  int i = (blockIdx.x * 256 + threadIdx.x) * 4;
  if (i < n) {
    float4 v = *(const float4*)(in + i);
    ushort4 o;
    o.x = f32_to_bf16_rne(v.x);
    o.y = f32_to_bf16_rne(v.y);
    o.z = f32_to_bf16_rne(v.z);
    o.w = f32_to_bf16_rne(v.w);
    *(ushort4*)(outp + i) = o;
  }
}

// ---------------------------------------------------------------------------
// W[K][N] fp32 -> Wt[N][K] bf16 (32x32 LDS tile transpose)
// ---------------------------------------------------------------------------
__global__ __launch_bounds__(256) void transpose_cvt_kernel(
    const float* __restrict__ W, unsigned short* __restrict__ Wt, int K, int N) {
  __shared__ float T[32][33];
  const int tx = threadIdx.x & 31;
  const int ty = threadIdx.x >> 5;
  const int r0 = blockIdx.y * 32;
  const int c0 = blockIdx.x * 32;
#pragma unroll
  for (int i = 0; i < 4; ++i)
    T[ty + i * 8][tx] = W[(size_t)(r0 + ty + i * 8) * N + c0 + tx];
  __syncthreads();
#pragma unroll
  for (int i = 0; i < 4; ++i)
    Wt[(size_t)(c0 + ty + i * 8) * K + r0 + tx] = f32_to_bf16_rne(T[tx][ty + i * 8]);
}

// ---------------------------------------------------------------------------
// bf16 MFMA GEMM: C[M][N] = A[M][K] @ Bt[N][K]^T + bias[N]
// 128x128 tile, BK=32, 256 threads (4 waves, 2x2 of 64x64).
// VSPLIT: for N-cols >= 2C (the V part of qkv), write transposed bf16 into
// vTp[b][h][d][T] instead of Cout.
// ---------------------------------------------------------------------------
template <bool BF16_OUT, bool VSPLIT>
__global__ __launch_bounds__(256) void gemm_mfma_kernel(
    const unsigned short* __restrict__ A, const unsigned short* __restrict__ Bt,
    const float* __restrict__ bias, void* __restrict__ Cout,
    unsigned short* __restrict__ vTp, int M, int N, int K) {
  __shared__ unsigned short As[128 * 32];
  __shared__ unsigned short Bs[128 * 32];

  const int tid = threadIdx.x;
  const int wave = tid >> 6;
  const int lane = tid & 63;
  const int row0 = blockIdx.y * 128;
  const int col0 = blockIdx.x * 128;
  const int wr = (wave >> 1) * 64;
  const int wc = (wave & 1) * 64;

  floatx4 acc[4][4];
#pragma unroll
  for (int m = 0; m < 4; ++m)
#pragma unroll
    for (int n = 0; n < 4; ++n) acc[m][n] = (floatx4){0.f, 0.f, 0.f, 0.f};

  const int sRow = lane >> 2;
  const int sK = (lane & 3) * 8;

  for (int k0 = 0; k0 < K; k0 += 32) {
#pragma unroll
    for (int c = 0; c < 2; ++c) {
      const int g = c * 4 + wave;
      gload_lds16(A + (size_t)(row0 + g * 16 + sRow) * K + k0 + sK,
                  (char*)As + g * 1024);
      gload_lds16(Bt + (size_t)(col0 + g * 16 + sRow) * K + k0 + sK,
                  (char*)Bs + g * 1024);
    }
    __syncthreads();

    short8 af[4], bf[4];
#pragma unroll
    for (int m = 0; m < 4; ++m)
      af[m] = *(const short8*)(As + (wr + m * 16 + (lane & 15)) * 32 + (lane >> 4) * 8);
#pragma unroll
    for (int n = 0; n < 4; ++n)
      bf[n] = *(const short8*)(Bs + (wc + n * 16 + (lane & 15)) * 32 + (lane >> 4) * 8);
#pragma unroll
    for (int m = 0; m < 4; ++m)
#pragma unroll
      for (int n = 0; n < 4; ++n)
        acc[m][n] = __builtin_amdgcn_mfma_f32_16x16x32_bf16(af[m], bf[n], acc[m][n], 0, 0, 0);
    __syncthreads();
  }

  const int cl = lane & 15;
  const int rg = (lane >> 4) * 4;

  if (VSPLIT && col0 >= 2 * CC) {
#pragma unroll
    for (int m = 0; m < 4; ++m) {
#pragma unroll
      for (int n = 0; n < 4; ++n) {
        const int col = col0 + wc + n * 16 + cl;
        const float bsv = bias[col];
        const int hh = (col - 2 * CC) >> 6;
        const int dd = col & (DHEAD - 1);
        const int t0r = row0 + wr + m * 16 + rg;
        const int bb = t0r >> 11;
        const int tt = t0r & (TT - 1);
        ushort4 o;
        o.x = f32_to_bf16_rne(acc[m][n][0] + bsv);
        o.y = f32_to_bf16_rne(acc[m][n][1] + bsv);
        o.z = f32_to_bf16_rne(acc[m][n][2] + bsv);
        o.w = f32_to_bf16_rne(acc[m][n][3] + bsv);
        *(ushort4*)(vTp + ((size_t)((bb * NHEAD + hh) * DHEAD + dd)) * TT + tt) = o;
      }
    }
  } else {
#pragma unroll
    for (int m = 0; m < 4; ++m) {
#pragma unroll
      for (int n = 0; n < 4; ++n) {
        const int col = col0 + wc + n * 16 + cl;
        const float bv = bias[col];
#pragma unroll
        for (int r = 0; r < 4; ++r) {
          const int row = row0 + wr + m * 16 + rg + r;
          const float v = acc[m][n][r] + bv;
          if (BF16_OUT)
            ((unsigned short*)Cout)[(size_t)row * N + col] = f32_to_bf16_rne(v);
          else
            ((float*)Cout)[(size_t)row * N + col] = v;
        }
      }
    }
  }
}

// ---------------------------------------------------------------------------
// MFMA flash attention, 2-phase pipelined (double-buffered K/V, single raw
// barrier per KV-tile, counted-stage overlap). bf16 in, fp32 softmax, bf16 out.
// Grid: (T/128 q-tiles reversed, B*H). Block 256 = 4 waves; each wave owns
// 32 q-rows (2 m-frags). KV tiles of 64. XOR-swizzled staging (chunk ^= row&7).
// ---------------------------------------------------------------------------
__global__ __launch_bounds__(256) void flash_mfma_kernel(
    const unsigned short* __restrict__ qkv,
    const unsigned short* __restrict__ vT,
    unsigned short* __restrict__ y) {
  __shared__ unsigned short Ks[2][64 * 64];   // [token][d-chunk swz]
  __shared__ unsigned short Vs[2][64 * 64];   // [d][k-chunk swz]
  __shared__ unsigned short Ps[4][32 * 64];   // per-wave P [q][k swz]

  const int qt = (TT / 128 - 1) - blockIdx.x;  // longest first
  const int bh = blockIdx.y;
  const int h = bh & (NHEAD - 1);
  const int b = bh >> 4;
  const int tid = threadIdx.x;
  const int wq = tid >> 6;
  const int lane = tid & 63;
  const int l15 = lane & 15;
  const int l4 = lane >> 4;
  const int srow = lane >> 3;   // 0..7
  const int schunk = lane & 7;  // 0..7

  const int q0 = qt * 128;
  const int qminw = q0 + wq * 32;

  const size_t baseQ = (size_t)(b * TT) * (3 * CC) + h * DHEAD;
  const size_t baseK = baseQ + CC;
  const size_t vbase = (size_t)((b * NHEAD + h) * DHEAD) * TT;

  // Q A-frags: rows qminw + m*16 + l15
  short8 aq[2][2];
#pragma unroll
  for (int m = 0; m < 2; ++m) {
    const unsigned short* qp =
        qkv + baseQ + (size_t)(qminw + m * 16 + l15) * (3 * CC) + l4 * 8;
    aq[m][0] = *(const short8*)(qp);
    aq[m][1] = *(const short8*)(qp + 32);
  }

  floatx4 accO[2][4];
  float m_i[8], l_i[8];
#pragma unroll
  for (int i = 0; i < 8; ++i) { m_i[i] = -1e30f; l_i[i] = 0.f; }
#pragma unroll
  for (int m = 0; m < 2; ++m)
#pragma unroll
    for (int n = 0; n < 4; ++n) accO[m][n] = (floatx4){0.f, 0.f, 0.f, 0.f};

  const int nt = 2 * qt + 2;

  auto stage = [&](int KT, int BUF) {
#pragma unroll
    for (int it = 0; it < 2; ++it) {
      const int blk = it * 4 + wq;
      const int grow = blk * 8 + srow;
      gload_lds16(qkv + baseK + (size_t)(KT * 64 + grow) * (3 * CC) +
                      (schunk ^ srow) * 8,
                  (char*)Ks[BUF] + blk * 1024);
      gload_lds16(vT + vbase + (size_t)grow * TT + KT * 64 + (schunk ^ srow) * 8,
                  (char*)Vs[BUF] + blk * 1024);
    }
  };

  // prologue
  stage(0, 0);
  asm volatile("s_waitcnt vmcnt(0)" ::: "memory");
  __builtin_amdgcn_s_barrier();

  for (int kt = 0; kt < nt; ++kt) {
    const int cur = kt & 1;
    if (kt + 1 < nt) stage(kt + 1, cur ^ 1);  // overlaps with compute below

    if (kt * 64 <= qminw + 31) {  // wave has unmasked rows in this tile
      // ---- S = Q K^T : 16 MFMA, 8 b128 reads ----
      floatx4 sa[2][4];
#pragma unroll
      for (int m = 0; m < 2; ++m)
#pragma unroll
        for (int n = 0; n < 4; ++n) sa[m][n] = (floatx4){0.f, 0.f, 0.f, 0.f};

      __builtin_amdgcn_s_setprio(1);
#pragma unroll
      for (int kc = 0; kc < 2; ++kc) {
#pragma unroll
        for (int n = 0; n < 4; ++n) {
          const int row = 16 * n + l15;
          short8 bk = *(const short8*)(Ks[cur] + row * 64 +
                                       ((kc * 4 + l4) ^ (row & 7)) * 8);
#pragma unroll
          for (int m = 0; m < 2; ++m)
            sa[m][n] = __builtin_amdgcn_mfma_f32_16x16x32_bf16(aq[m][kc], bk,
                                                               sa[m][n], 0, 0, 0);
        }
      }
      __builtin_amdgcn_s_setprio(0);

      // ---- online softmax (rows m*16 + l4*4 + r, cols 16n + l15) ----
      const bool needmask = (kt * 64 + 63 > qminw);
#pragma unroll
      for (int m = 0; m < 2; ++m) {
#pragma unroll
        for (int r = 0; r < 4; ++r) {
          const int ri = m * 4 + r;
          const int qg = qminw + m * 16 + l4 * 4 + r;
          float rm = -1e30f;
#pragma unroll
          for (int n = 0; n < 4; ++n) {
            float s = sa[m][n][r] * 0.125f;
            if (needmask) {
              const int kg = kt * 64 + 16 * n + l15;
              if (kg > qg) s = -1e30f;
            }
            sa[m][n][r] = s;
            rm = fmaxf(rm, s);
          }
#pragma unroll
          for (int off = 1; off < 16; off <<= 1)
            rm = fmaxf(rm, __shfl_xor(rm, off, 64));
          const float mn = fmaxf(m_i[ri], rm);
          const float scale = __expf(m_i[ri] - mn);
          float rs = 0.f;
#pragma unroll
          for (int n = 0; n < 4; ++n) {
            const float p = __expf(sa[m][n][r] - mn);
            sa[m][n][r] = p;
            rs += p;
          }
#pragma unroll
          for (int off = 1; off < 16; off <<= 1)
            rs += __shfl_xor(rs, off, 64);
          l_i[ri] = l_i[ri] * scale + rs;
          m_i[ri] = mn;
#pragma unroll
          for (int nd = 0; nd < 4; ++nd) accO[m][nd][r] *= scale;
        }
      }

      // ---- P -> per-wave LDS (bf16, chunk-XOR swizzle) ----
      unsigned short* Pw = Ps[wq];
#pragma unroll
      for (int m = 0; m < 2; ++m)
#pragma unroll
        for (int n = 0; n < 4; ++n)
#pragma unroll
          for (int r = 0; r < 4; ++r) {
            const int row = m * 16 + l4 * 4 + r;
            const int col = 16 * n + l15;
            Pw[row * 64 + ((col >> 3) ^ (row & 7)) * 8 + (col & 7)] =
                f32_to_bf16_rne(sa[m][n][r]);
          }
      asm volatile("s_waitcnt lgkmcnt(0)" ::: "memory");  // same-wave RAW

      // ---- O += P V : 16 MFMA ----
      short8 pa[2][2];
#pragma unroll
      for (int m2 = 0; m2 < 2; ++m2)
#pragma unroll
        for (int kc = 0; kc < 2; ++kc) {
          const int prow = m2 * 16 + l15;
          pa[m2][kc] = *(const short8*)(Pw + prow * 64 +
                                        ((kc * 4 + l4) ^ (prow & 7)) * 8);
        }
      __builtin_amdgcn_s_setprio(1);
#pragma unroll
      for (int kc = 0; kc < 2; ++kc) {
#pragma unroll
        for (int nd = 0; nd < 4; ++nd) {
          const int row = 16 * nd + l15;
          short8 vb = *(const short8*)(Vs[cur] + row * 64 +
                                       ((kc * 4 + l4) ^ (row & 7)) * 8);
#pragma unroll
          for (int m2 = 0; m2 < 2; ++m2)
            accO[m2][nd] = __builtin_amdgcn_mfma_f32_16x16x32_bf16(
                pa[m2][kc], vb, accO[m2][nd], 0, 0, 0);
        }
      }
      __builtin_amdgcn_s_setprio(0);
    }

    // staged tile kt+1 fully landed; all waves done reading buf[cur]
    asm volatile("s_waitcnt vmcnt(0)" ::: "memory");
    __builtin_amdgcn_s_barrier();
  }

  // epilogue: y[b, q, h*64+d] = O / l
#pragma unroll
  for (int m = 0; m < 2; ++m)
#pragma unroll
    for (int r = 0; r < 4; ++r) {
      const float inv = 1.0f / l_i[m * 4 + r];
      const int qg = qminw + m * 16 + l4 * 4 + r;
#pragma unroll
      for (int nd = 0; nd < 4; ++nd)
        y[(size_t)(b * TT + qg) * CC + h * DHEAD + 16 * nd + l15] =
            f32_to_bf16_rne(accO[m][nd][r] * inv);
    }
}

extern "C" void kernel_launch(void* const* d_in, const int* in_sizes, int n_in,
                              void* d_out, int out_size, void* d_ws, size_t ws_size,
                              hipStream_t stream) {
  const float* x      = (const float*)d_in[0];
  const float* W_attn = (const float*)d_in[1];
  const float* b_attn = (const float*)d_in[2];
  const float* W_proj = (const float*)d_in[3];
  const float* b_proj = (const float*)d_in[4];
  float* out = (float*)d_out;

  const int M = BB * TT;  // 4096

  // workspace layout (ushort units)
  unsigned short* qkvb = (unsigned short*)d_ws;          // M * 3C (V part unused)
  unsigned short* xb   = qkvb + (size_t)M * 3 * CC;      // M * C
  unsigned short* Wat  = xb + (size_t)M * CC;            // 3C * C
  unsigned short* Wpt  = Wat + (size_t)3 * CC * CC;      // C * C
  unsigned short* yb   = Wpt + (size_t)CC * CC;          // M * C
  unsigned short* vTb  = yb + (size_t)M * CC;            // B*H*D*T

  cvt_bf16_kernel<<<(M * CC) / 1024, 256, 0, stream>>>(x, xb, M * CC);
  {
    dim3 g((3 * CC) / 32, CC / 32);
    transpose_cvt_kernel<<<g, 256, 0, stream>>>(W_attn, Wat, CC, 3 * CC);
  }
  {
    dim3 g(CC / 32, CC / 32);
    transpose_cvt_kernel<<<g, 256, 0, stream>>>(W_proj, Wpt, CC, CC);
  }

  // GEMM1: qkv = x @ W_attn + b_attn; V third goes transposed to vTb
  {
    dim3 grid((3 * CC) / 128, M / 128);
    gemm_mfma_kernel<true, true><<<grid, 256, 0, stream>>>(
        xb, Wat, b_attn, qkvb, vTb, M, 3 * CC, CC);
  }

  // MFMA flash attention (128-row q tiles)
  {
    dim3 grid(TT / 128, BB * NHEAD);
    flash_mfma_kernel<<<grid, 256, 0, stream>>>(qkvb, vTb, yb);
  }

  // GEMM2: out = y @ W_proj + b_proj (fp32 out)
  {
    dim3 grid(CC / 128, M / 128);
    gemm_mfma_kernel<false, false><<<grid, 256, 0, stream>>>(
        yb, Wpt, b_proj, out, nullptr, M, CC, CC);
  }
}

// Round 6
// 176.748 us; speedup vs baseline: 22.8330x; 1.2191x over previous
//
#include <hip/hip_runtime.h>

#define BB 2
#define TT 2048
#define CC 1024
#define NHEAD 16
#define DHEAD 64

typedef __attribute__((ext_vector_type(8))) short short8;     // bf16x8 MFMA frag
typedef __attribute__((ext_vector_type(8))) unsigned short ushort8;
typedef __attribute__((ext_vector_type(4))) float floatx4;
typedef __attribute__((ext_vector_type(2))) unsigned int uintx2;

__device__ inline unsigned short f32_to_bf16_rne(float f) {
  unsigned u = __builtin_bit_cast(unsigned, f);
  unsigned r = (u + 0x7FFFu + ((u >> 16) & 1u)) >> 16;
  return (unsigned short)r;
}
__device__ inline unsigned pack_bf16x2(float lo, float hi) {
  return (unsigned)f32_to_bf16_rne(lo) | ((unsigned)f32_to_bf16_rne(hi) << 16);
}
__device__ inline void gload_lds16(const void* g, void* l) {
  __builtin_amdgcn_global_load_lds(
      (const __attribute__((address_space(1))) void*)g,
      (__attribute__((address_space(3))) void*)l, 16, 0, 0);
}

// ---------------------------------------------------------------------------
// fp32 -> bf16 straight convert
// ---------------------------------------------------------------------------
__global__ __launch_bounds__(256) void cvt_bf16_kernel(
    const float* __restrict__ in, unsigned short* __restrict__ outp, int n) {
  int i = (blockIdx.x * 256 + threadIdx.x) * 4;
  if (i < n) {
    float4 v = *(const float4*)(in + i);
    ushort4 o;
    o.x = f32_to_bf16_rne(v.x);
    o.y = f32_to_bf16_rne(v.y);
    o.z = f32_to_bf16_rne(v.z);
    o.w = f32_to_bf16_rne(v.w);
    *(ushort4*)(outp + i) = o;
  }
}

// ---------------------------------------------------------------------------
// W[K][N] fp32 -> Wt[N][K] bf16 (32x32 LDS tile transpose)
// ---------------------------------------------------------------------------
__global__ __launch_bounds__(256) void transpose_cvt_kernel(
    const float* __restrict__ W, unsigned short* __restrict__ Wt, int K, int N) {
  __shared__ float T[32][33];
  const int tx = threadIdx.x & 31;
  const int ty = threadIdx.x >> 5;
  const int r0 = blockIdx.y * 32;
  const int c0 = blockIdx.x * 32;
#pragma unroll
  for (int i = 0; i < 4; ++i)
    T[ty + i * 8][tx] = W[(size_t)(r0 + ty + i * 8) * N + c0 + tx];
  __syncthreads();
#pragma unroll
  for (int i = 0; i < 4; ++i)
    Wt[(size_t)(c0 + ty + i * 8) * K + r0 + tx] = f32_to_bf16_rne(T[tx][ty + i * 8]);
}

// ---------------------------------------------------------------------------
// V part of qkv (bf16, [B,T,3C] at col 2C+h*64) -> vT[b][h][d][T]
// 64x64 tiles through LDS; coalesced on both sides.
// ---------------------------------------------------------------------------
__global__ __launch_bounds__(256) void transpose_v_kernel(
    const unsigned short* __restrict__ qkv, unsigned short* __restrict__ vT) {
  __shared__ unsigned short Ts[64][72];
  const int tt0 = blockIdx.x * 64;
  const int bh = blockIdx.y;
  const int h = bh & (NHEAD - 1);
  const int b = bh >> 4;
  const int tid = threadIdx.x;
  const unsigned short* src = qkv + (size_t)(b * TT) * (3 * CC) + 2 * CC + h * DHEAD;
#pragma unroll
  for (int it = 0; it < 2; ++it) {
    const int t = it * 32 + (tid >> 3);
    const int d8 = (tid & 7) * 8;
    ushort8 v = *(const ushort8*)(src + (size_t)(tt0 + t) * (3 * CC) + d8);
#pragma unroll
    for (int j = 0; j < 8; ++j) Ts[t][d8 + j] = v[j];
  }
  __syncthreads();
  unsigned short* dst = vT + ((size_t)((b * NHEAD + h) * DHEAD)) * TT;
#pragma unroll
  for (int it = 0; it < 2; ++it) {
    const int d = it * 32 + (tid >> 3);
    const int t8 = (tid & 7) * 8;
    ushort8 o;
#pragma unroll
    for (int j = 0; j < 8; ++j) o[j] = Ts[t8 + j][d];
    *(ushort8*)(dst + (size_t)d * TT + tt0 + t8) = o;
  }
}

// ---------------------------------------------------------------------------
// bf16 MFMA GEMM: C[M][N] = A[M][K] @ Bt[N][K]^T + bias[N]
// 128x128 tile, BK=32, 256 threads (4 waves, 2x2 of 64x64).
// ---------------------------------------------------------------------------
template <bool BF16_OUT>
__global__ __launch_bounds__(256) void gemm_mfma_kernel(
    const unsigned short* __restrict__ A, const unsigned short* __restrict__ Bt,
    const float* __restrict__ bias, void* __restrict__ Cout,
    int M, int N, int K) {
  __shared__ unsigned short As[128 * 32];
  __shared__ unsigned short Bs[128 * 32];

  const int tid = threadIdx.x;
  const int wave = tid >> 6;
  const int lane = tid & 63;
  const int row0 = blockIdx.y * 128;
  const int col0 = blockIdx.x * 128;
  const int wr = (wave >> 1) * 64;
  const int wc = (wave & 1) * 64;

  floatx4 acc[4][4];
#pragma unroll
  for (int m = 0; m < 4; ++m)
#pragma unroll
    for (int n = 0; n < 4; ++n) acc[m][n] = (floatx4){0.f, 0.f, 0.f, 0.f};

  const int sRow = lane >> 2;
  const int sK = (lane & 3) * 8;

  for (int k0 = 0; k0 < K; k0 += 32) {
#pragma unroll
    for (int c = 0; c < 2; ++c) {
      const int g = c * 4 + wave;
      gload_lds16(A + (size_t)(row0 + g * 16 + sRow) * K + k0 + sK,
                  (char*)As + g * 1024);
      gload_lds16(Bt + (size_t)(col0 + g * 16 + sRow) * K + k0 + sK,
                  (char*)Bs + g * 1024);
    }
    __syncthreads();

    short8 af[4], bf[4];
#pragma unroll
    for (int m = 0; m < 4; ++m)
      af[m] = *(const short8*)(As + (wr + m * 16 + (lane & 15)) * 32 + (lane >> 4) * 8);
#pragma unroll
    for (int n = 0; n < 4; ++n)
      bf[n] = *(const short8*)(Bs + (wc + n * 16 + (lane & 15)) * 32 + (lane >> 4) * 8);
#pragma unroll
    for (int m = 0; m < 4; ++m)
#pragma unroll
      for (int n = 0; n < 4; ++n)
        acc[m][n] = __builtin_amdgcn_mfma_f32_16x16x32_bf16(af[m], bf[n], acc[m][n], 0, 0, 0);
    __syncthreads();
  }

  const int cl = lane & 15;
  const int rg = (lane >> 4) * 4;
#pragma unroll
  for (int m = 0; m < 4; ++m) {
#pragma unroll
    for (int n = 0; n < 4; ++n) {
      const int col = col0 + wc + n * 16 + cl;
      const float bv = bias[col];
#pragma unroll
      for (int r = 0; r < 4; ++r) {
        const int row = row0 + wr + m * 16 + rg + r;
        const float v = acc[m][n][r] + bv;
        if (BF16_OUT)
          ((unsigned short*)Cout)[(size_t)row * N + col] = f32_to_bf16_rne(v);
        else
          ((float*)Cout)[(size_t)row * N + col] = v;
      }
    }
  }
}

// ---------------------------------------------------------------------------
// MFMA flash attention, swapped-operand form.
// S^T = mfma(K_frag, Q_frag): lane owns q-row (col=l15), 16 k-scores in regs
//   -> in-register softmax (2 shuffles per reduce, no per-row lane reduces).
// O^T = mfma(V^T_frag, P_frag): scale/l lane-local; O transposed via LDS at end.
// Grid (T/128 reversed, B*H), 256 thr = 4 waves x 32 q-rows. KV tiles of 64,
// double-buffered, raw-barrier 2-phase pipeline.
// ---------------------------------------------------------------------------
__global__ __launch_bounds__(256) void flash_mfma_kernel(
    const unsigned short* __restrict__ qkv,
    const unsigned short* __restrict__ vT,
    unsigned short* __restrict__ y) {
  __shared__ unsigned short Ks[2][64 * 64];   // [token][d-chunk swz]
  __shared__ unsigned short Vs[2][64 * 64];   // [d][k-chunk swz]
  __shared__ unsigned short Ps[4][32 * 64];   // per-wave P / O^T staging

  const int qt = (TT / 128 - 1) - blockIdx.x;
  const int bh = blockIdx.y;
  const int h = bh & (NHEAD - 1);
  const int b = bh >> 4;
  const int tid = threadIdx.x;
  const int wq = tid >> 6;
  const int lane = tid & 63;
  const int l15 = lane & 15;
  const int l4 = lane >> 4;
  const int srow = lane >> 3;
  const int schunk = lane & 7;

  const int qminw = qt * 128 + wq * 32;

  const size_t baseQ = (size_t)(b * TT) * (3 * CC) + h * DHEAD;
  const size_t baseK = baseQ + CC;
  const size_t vbase = (size_t)((b * NHEAD + h) * DHEAD) * TT;

  // Q B-frags: lane l15 = q-row (within group), d = kc*32 + l4*8
  short8 aq[2][2];
#pragma unroll
  for (int m = 0; m < 2; ++m) {
    const unsigned short* qp =
        qkv + baseQ + (size_t)(qminw + m * 16 + l15) * (3 * CC) + l4 * 8;
    aq[m][0] = *(const short8*)(qp);
    aq[m][1] = *(const short8*)(qp + 32);
  }

  floatx4 accT[2][4];  // [group][nd]: O^T[d=nd*16+l4*4+r][q=l15]
  float m_i[2], l_i[2];
#pragma unroll
  for (int m = 0; m < 2; ++m) {
    m_i[m] = -1e30f;
    l_i[m] = 0.f;
#pragma unroll
    for (int n = 0; n < 4; ++n) accT[m][n] = (floatx4){0.f, 0.f, 0.f, 0.f};
  }

  const int nt = 2 * qt + 2;

  auto stage = [&](int KT, int BUF) {
#pragma unroll
    for (int it = 0; it < 2; ++it) {
      const int blk = it * 4 + wq;
      const int grow = blk * 8 + srow;
      gload_lds16(qkv + baseK + (size_t)(KT * 64 + grow) * (3 * CC) +
                      (schunk ^ srow) * 8,
                  (char*)Ks[BUF] + blk * 1024);
      gload_lds16(vT + vbase + (size_t)grow * TT + KT * 64 + (schunk ^ srow) * 8,
                  (char*)Vs[BUF] + blk * 1024);
    }
  };

  stage(0, 0);
  asm volatile("s_waitcnt vmcnt(0)" ::: "memory");
  __builtin_amdgcn_s_barrier();

  for (int kt = 0; kt < nt; ++kt) {
    const int cur = kt & 1;
    if (kt + 1 < nt) stage(kt + 1, cur ^ 1);

    if (kt * 64 <= qminw + 31) {
      // ---- S^T = K Q^T : sa[group][f] rows k=f*16+l4*4+r, col q=l15 ----
      floatx4 sa[2][4];
#pragma unroll
      for (int m = 0; m < 2; ++m)
#pragma unroll
        for (int f = 0; f < 4; ++f) sa[m][f] = (floatx4){0.f, 0.f, 0.f, 0.f};

      __builtin_amdgcn_s_setprio(1);
#pragma unroll
      for (int kc = 0; kc < 2; ++kc) {
#pragma unroll
        for (int f = 0; f < 4; ++f) {
          const int row = 16 * f + l15;
          short8 bk = *(const short8*)(Ks[cur] + row * 64 +
                                       ((kc * 4 + l4) ^ (row & 7)) * 8);
#pragma unroll
          for (int m = 0; m < 2; ++m)
            sa[m][f] = __builtin_amdgcn_mfma_f32_16x16x32_bf16(bk, aq[m][kc],
                                                               sa[m][f], 0, 0, 0);
        }
      }
      __builtin_amdgcn_s_setprio(0);

      // ---- in-register online softmax per group; pack P to LDS ----
      unsigned short* Pw0 = Ps[wq];
#pragma unroll
      for (int m = 0; m < 2; ++m) {
        const int qg = qminw + m * 16 + l15;
        const bool needmask = (kt * 64 + 63 > qminw + m * 16);
        float rm = -1e30f;
#pragma unroll
        for (int f = 0; f < 4; ++f)
#pragma unroll
          for (int r = 0; r < 4; ++r) {
            float s = sa[m][f][r] * 0.125f;
            if (needmask) {
              const int kg = kt * 64 + f * 16 + l4 * 4 + r;
              if (kg > qg) s = -1e30f;
            }
            sa[m][f][r] = s;
            rm = fmaxf(rm, s);
          }
        rm = fmaxf(rm, __shfl_xor(rm, 16, 64));
        rm = fmaxf(rm, __shfl_xor(rm, 32, 64));
        const float mn = fmaxf(m_i[m], rm);
        const float scale = __expf(m_i[m] - mn);
        float rs = 0.f;
#pragma unroll
        for (int f = 0; f < 4; ++f)
#pragma unroll
          for (int r = 0; r < 4; ++r) {
            const float p = __expf(sa[m][f][r] - mn);
            sa[m][f][r] = p;
            rs += p;
          }
        rs += __shfl_xor(rs, 16, 64);
        rs += __shfl_xor(rs, 32, 64);
        l_i[m] = l_i[m] * scale + rs;
        m_i[m] = mn;
#pragma unroll
        for (int nd = 0; nd < 4; ++nd) accT[m][nd] *= scale;

        // P^T pack: lane (q=l15) holds k=f*16+l4*4+0..3 -> b64 per f
        char* Pg = (char*)Pw0 + m * 2048;
#pragma unroll
        for (int f = 0; f < 4; ++f) {
          uintx2 dw;
          dw[0] = pack_bf16x2(sa[m][f][0], sa[m][f][1]);
          dw[1] = pack_bf16x2(sa[m][f][2], sa[m][f][3]);
          const int c = f * 2 + (l4 >> 1);
          *(uintx2*)(Pg + l15 * 128 + ((c ^ (l15 & 7)) * 16) + (l4 & 1) * 8) = dw;
        }
      }
      asm volatile("s_waitcnt lgkmcnt(0)" ::: "memory");  // same-wave RAW

      // ---- B-frags of P: lane l15 = q, k = kc*32 + l4*8 ----
      short8 pb[2][2];
#pragma unroll
      for (int m = 0; m < 2; ++m)
#pragma unroll
        for (int kc = 0; kc < 2; ++kc) {
          const int c = kc * 4 + l4;
          pb[m][kc] = *(const short8*)((char*)Pw0 + m * 2048 + l15 * 128 +
                                       ((c ^ (l15 & 7)) * 16));
        }

      // ---- O^T += V^T P : A = V^T rows d, B = P rows q ----
      __builtin_amdgcn_s_setprio(1);
#pragma unroll
      for (int kc = 0; kc < 2; ++kc) {
#pragma unroll
        for (int nd = 0; nd < 4; ++nd) {
          const int row = 16 * nd + l15;
          short8 vb = *(const short8*)(Vs[cur] + row * 64 +
                                       ((kc * 4 + l4) ^ (row & 7)) * 8);
#pragma unroll
          for (int m = 0; m < 2; ++m)
            accT[m][nd] = __builtin_amdgcn_mfma_f32_16x16x32_bf16(
                vb, pb[m][kc], accT[m][nd], 0, 0, 0);
        }
      }
      __builtin_amdgcn_s_setprio(0);
    }

    asm volatile("s_waitcnt vmcnt(0)" ::: "memory");
    __builtin_amdgcn_s_barrier();
  }

  // ---- epilogue: O = O^T^T via per-wave LDS, then coalesced store ----
  char* Pw = (char*)Ps[wq];
#pragma unroll
  for (int m = 0; m < 2; ++m) {
    const float inv = 1.0f / l_i[m];
    const int q32 = m * 16 + l15;
#pragma unroll
    for (int nd = 0; nd < 4; ++nd) {
      uintx2 dw;
      dw[0] = pack_bf16x2(accT[m][nd][0] * inv, accT[m][nd][1] * inv);
      dw[1] = pack_bf16x2(accT[m][nd][2] * inv, accT[m][nd][3] * inv);
      const int c = nd * 2 + (l4 >> 1);
      *(uintx2*)(Pw + q32 * 128 + ((c ^ (q32 & 7)) * 16) + (l4 & 1) * 8) = dw;
    }
  }
  asm volatile("s_waitcnt lgkmcnt(0)" ::: "memory");
#pragma unroll
  for (int it = 0; it < 2; ++it) {
#pragma unroll
    for (int ch = 0; ch < 2; ++ch) {
      const int q32 = it * 16 + (lane >> 2);
      const int c = ch * 4 + (lane & 3);
      ushort8 o = *(const ushort8*)(Pw + q32 * 128 + ((c ^ (q32 & 7)) * 16));
      const int qg = qminw + q32;
      *(ushort8*)(y + (size_t)(b * TT + qg) * CC + h * DHEAD + c * 8) = o;
    }
  }
}

extern "C" void kernel_launch(void* const* d_in, const int* in_sizes, int n_in,
                              void* d_out, int out_size, void* d_ws, size_t ws_size,
                              hipStream_t stream) {
  const float* x      = (const float*)d_in[0];
  const float* W_attn = (const float*)d_in[1];
  const float* b_attn = (const float*)d_in[2];
  const float* W_proj = (const float*)d_in[3];
  const float* b_proj = (const float*)d_in[4];
  float* out = (float*)d_out;

  const int M = BB * TT;  // 4096

  // workspace layout (ushort units)
  unsigned short* qkvb = (unsigned short*)d_ws;          // M * 3C
  unsigned short* xb   = qkvb + (size_t)M * 3 * CC;      // M * C
  unsigned short* Wat  = xb + (size_t)M * CC;            // 3C * C
  unsigned short* Wpt  = Wat + (size_t)3 * CC * CC;      // C * C
  unsigned short* yb   = Wpt + (size_t)CC * CC;          // M * C
  unsigned short* vTb  = yb + (size_t)M * CC;            // B*H*D*T

  cvt_bf16_kernel<<<(M * CC) / 1024, 256, 0, stream>>>(x, xb, M * CC);
  {
    dim3 g((3 * CC) / 32, CC / 32);
    transpose_cvt_kernel<<<g, 256, 0, stream>>>(W_attn, Wat, CC, 3 * CC);
  }
  {
    dim3 g(CC / 32, CC / 32);
    transpose_cvt_kernel<<<g, 256, 0, stream>>>(W_proj, Wpt, CC, CC);
  }

  // GEMM1: qkv = x @ W_attn + b_attn (plain layout, coalesced stores)
  {
    dim3 grid((3 * CC) / 128, M / 128);
    gemm_mfma_kernel<true><<<grid, 256, 0, stream>>>(xb, Wat, b_attn, qkvb, M, 3 * CC, CC);
  }

  // V -> vT[b][h][d][T]
  {
    dim3 grid(TT / 64, BB * NHEAD);
    transpose_v_kernel<<<grid, 256, 0, stream>>>(qkvb, vTb);
  }

  // MFMA flash attention (128-row q tiles)
  {
    dim3 grid(TT / 128, BB * NHEAD);
    flash_mfma_kernel<<<grid, 256, 0, stream>>>(qkvb, vTb, yb);
  }

  // GEMM2: out = y @ W_proj + b_proj (fp32 out)
  {
    dim3 grid(CC / 128, M / 128);
    gemm_mfma_kernel<false><<<grid, 256, 0, stream>>>(yb, Wpt, b_proj, out, M, CC, CC);
  }
}

// Round 7
// 160.005 us; speedup vs baseline: 25.2221x; 1.1046x over previous
//
#include <hip/hip_runtime.h>

#define BB 2
#define TT 2048
#define CC 1024
#define NHEAD 16
#define DHEAD 64

typedef __attribute__((ext_vector_type(8))) short short8;     // bf16x8 MFMA frag
typedef __attribute__((ext_vector_type(8))) unsigned short ushort8;
typedef __attribute__((ext_vector_type(4))) float floatx4;
typedef __attribute__((ext_vector_type(2))) unsigned int uintx2;

__device__ inline unsigned short f32_to_bf16_rne(float f) {
  unsigned u = __builtin_bit_cast(unsigned, f);
  unsigned r = (u + 0x7FFFu + ((u >> 16) & 1u)) >> 16;
  return (unsigned short)r;
}
__device__ inline unsigned pack_bf16x2(float lo, float hi) {
  return (unsigned)f32_to_bf16_rne(lo) | ((unsigned)f32_to_bf16_rne(hi) << 16);
}
__device__ inline void gload_lds16(const void* g, void* l) {
  __builtin_amdgcn_global_load_lds(
      (const __attribute__((address_space(1))) void*)g,
      (__attribute__((address_space(3))) void*)l, 16, 0, 0);
}

// ---------------------------------------------------------------------------
// fp32 -> bf16 straight convert
// ---------------------------------------------------------------------------
__global__ __launch_bounds__(256) void cvt_bf16_kernel(
    const float* __restrict__ in, unsigned short* __restrict__ outp, int n) {
  int i = (blockIdx.x * 256 + threadIdx.x) * 4;
  if (i < n) {
    float4 v = *(const float4*)(in + i);
    ushort4 o;
    o.x = f32_to_bf16_rne(v.x);
    o.y = f32_to_bf16_rne(v.y);
    o.z = f32_to_bf16_rne(v.z);
    o.w = f32_to_bf16_rne(v.w);
    *(ushort4*)(outp + i) = o;
  }
}

// ---------------------------------------------------------------------------
// W[K][N] fp32 -> Wt[N][K] bf16 (32x32 LDS tile transpose)
// ---------------------------------------------------------------------------
__global__ __launch_bounds__(256) void transpose_cvt_kernel(
    const float* __restrict__ W, unsigned short* __restrict__ Wt, int K, int N) {
  __shared__ float T[32][33];
  const int tx = threadIdx.x & 31;
  const int ty = threadIdx.x >> 5;
  const int r0 = blockIdx.y * 32;
  const int c0 = blockIdx.x * 32;
#pragma unroll
  for (int i = 0; i < 4; ++i)
    T[ty + i * 8][tx] = W[(size_t)(r0 + ty + i * 8) * N + c0 + tx];
  __syncthreads();
#pragma unroll
  for (int i = 0; i < 4; ++i)
    Wt[(size_t)(c0 + ty + i * 8) * K + r0 + tx] = f32_to_bf16_rne(T[tx][ty + i * 8]);
}

// ---------------------------------------------------------------------------
// V part of qkv (bf16, [B,T,3C] at col 2C+h*64) -> vT[b][h][d][T]
// 64x64 tiles through LDS; coalesced on both sides.
// ---------------------------------------------------------------------------
__global__ __launch_bounds__(256) void transpose_v_kernel(
    const unsigned short* __restrict__ qkv, unsigned short* __restrict__ vT) {
  __shared__ unsigned short Ts[64][72];
  const int tt0 = blockIdx.x * 64;
  const int bh = blockIdx.y;
  const int h = bh & (NHEAD - 1);
  const int b = bh >> 4;
  const int tid = threadIdx.x;
  const unsigned short* src = qkv + (size_t)(b * TT) * (3 * CC) + 2 * CC + h * DHEAD;
#pragma unroll
  for (int it = 0; it < 2; ++it) {
    const int t = it * 32 + (tid >> 3);
    const int d8 = (tid & 7) * 8;
    ushort8 v = *(const ushort8*)(src + (size_t)(tt0 + t) * (3 * CC) + d8);
#pragma unroll
    for (int j = 0; j < 8; ++j) Ts[t][d8 + j] = v[j];
  }
  __syncthreads();
  unsigned short* dst = vT + ((size_t)((b * NHEAD + h) * DHEAD)) * TT;
#pragma unroll
  for (int it = 0; it < 2; ++it) {
    const int d = it * 32 + (tid >> 3);
    const int t8 = (tid & 7) * 8;
    ushort8 o;
#pragma unroll
    for (int j = 0; j < 8; ++j) o[j] = Ts[t8 + j][d];
    *(ushort8*)(dst + (size_t)d * TT + tt0 + t8) = o;
  }
}

// ---------------------------------------------------------------------------
// bf16 MFMA GEMM: C[M][N] = A[M][K] @ Bt[N][K]^T + bias[N]
// 128x128 tile, BK=32, 256 threads (4 waves, 2x2 of 64x64).
// ---------------------------------------------------------------------------
template <bool BF16_OUT>
__global__ __launch_bounds__(256) void gemm_mfma_kernel(
    const unsigned short* __restrict__ A, const unsigned short* __restrict__ Bt,
    const float* __restrict__ bias, void* __restrict__ Cout,
    int M, int N, int K) {
  __shared__ unsigned short As[128 * 32];
  __shared__ unsigned short Bs[128 * 32];

  const int tid = threadIdx.x;
  const int wave = tid >> 6;
  const int lane = tid & 63;
  const int row0 = blockIdx.y * 128;
  const int col0 = blockIdx.x * 128;
  const int wr = (wave >> 1) * 64;
  const int wc = (wave & 1) * 64;

  floatx4 acc[4][4];
#pragma unroll
  for (int m = 0; m < 4; ++m)
#pragma unroll
    for (int n = 0; n < 4; ++n) acc[m][n] = (floatx4){0.f, 0.f, 0.f, 0.f};

  const int sRow = lane >> 2;
  const int sK = (lane & 3) * 8;

  for (int k0 = 0; k0 < K; k0 += 32) {
#pragma unroll
    for (int c = 0; c < 2; ++c) {
      const int g = c * 4 + wave;
      gload_lds16(A + (size_t)(row0 + g * 16 + sRow) * K + k0 + sK,
                  (char*)As + g * 1024);
      gload_lds16(Bt + (size_t)(col0 + g * 16 + sRow) * K + k0 + sK,
                  (char*)Bs + g * 1024);
    }
    __syncthreads();

    short8 af[4], bf[4];
#pragma unroll
    for (int m = 0; m < 4; ++m)
      af[m] = *(const short8*)(As + (wr + m * 16 + (lane & 15)) * 32 + (lane >> 4) * 8);
#pragma unroll
    for (int n = 0; n < 4; ++n)
      bf[n] = *(const short8*)(Bs + (wc + n * 16 + (lane & 15)) * 32 + (lane >> 4) * 8);
#pragma unroll
    for (int m = 0; m < 4; ++m)
#pragma unroll
      for (int n = 0; n < 4; ++n)
        acc[m][n] = __builtin_amdgcn_mfma_f32_16x16x32_bf16(af[m], bf[n], acc[m][n], 0, 0, 0);
    __syncthreads();
  }

  const int cl = lane & 15;
  const int rg = (lane >> 4) * 4;
#pragma unroll
  for (int m = 0; m < 4; ++m) {
#pragma unroll
    for (int n = 0; n < 4; ++n) {
      const int col = col0 + wc + n * 16 + cl;
      const float bv = bias[col];
#pragma unroll
      for (int r = 0; r < 4; ++r) {
        const int row = row0 + wr + m * 16 + rg + r;
        const float v = acc[m][n][r] + bv;
        if (BF16_OUT)
          ((unsigned short*)Cout)[(size_t)row * N + col] = f32_to_bf16_rne(v);
        else
          ((float*)Cout)[(size_t)row * N + col] = v;
      }
    }
  }
}

// ---------------------------------------------------------------------------
// MFMA flash attention, swapped-operand form, 8 waves x 16 q-rows.
// S^T = mfma(K_frag, Q_frag): lane owns q-row (col=l15), 16 k-scores in regs
//   -> in-register softmax (2 shuffles per reduce).
// O^T = mfma(V^T_frag, P_frag): scale/l lane-local; O transposed via LDS at end.
// Grid (T/128 reversed, B*H), 512 thr = 8 waves. KV tiles of 64, double-
// buffered, raw-barrier 2-phase pipeline. 16 waves/CU resident (vs 8 before).
// ---------------------------------------------------------------------------
__global__ __launch_bounds__(512) void flash_mfma_kernel(
    const unsigned short* __restrict__ qkv,
    const unsigned short* __restrict__ vT,
    unsigned short* __restrict__ y) {
  __shared__ unsigned short Ks[2][64 * 64];   // [token][d-chunk swz]
  __shared__ unsigned short Vs[2][64 * 64];   // [d][k-chunk swz]
  __shared__ unsigned short Ps[8][16 * 64];   // per-wave P / O^T staging

  const int qt = (TT / 128 - 1) - blockIdx.x;  // longest first
  const int bh = blockIdx.y;
  const int h = bh & (NHEAD - 1);
  const int b = bh >> 4;
  const int tid = threadIdx.x;
  const int wq = tid >> 6;      // 0..7
  const int lane = tid & 63;
  const int l15 = lane & 15;
  const int l4 = lane >> 4;
  const int srow = lane >> 3;   // 0..7
  const int schunk = lane & 7;  // 0..7

  const int qminw = qt * 128 + wq * 16;

  const size_t baseQ = (size_t)(b * TT) * (3 * CC) + h * DHEAD;
  const size_t baseK = baseQ + CC;
  const size_t vbase = (size_t)((b * NHEAD + h) * DHEAD) * TT;

  // Q B-frags: lane l15 = q-row, d = kc*32 + l4*8
  short8 aq[2];
  {
    const unsigned short* qp =
        qkv + baseQ + (size_t)(qminw + l15) * (3 * CC) + l4 * 8;
    aq[0] = *(const short8*)(qp);
    aq[1] = *(const short8*)(qp + 32);
  }

  floatx4 accT[4];  // [nd]: O^T[d=nd*16+l4*4+r][q=l15]
  float m_i = -1e30f, l_i = 0.f;
#pragma unroll
  for (int n = 0; n < 4; ++n) accT[n] = (floatx4){0.f, 0.f, 0.f, 0.f};

  const int nt = 2 * qt + 2;

  auto stage = [&](int KT, int BUF) {
    // 16 gload_lds total; wave wq stages K block wq and V block wq
    const int grow = wq * 8 + srow;
    gload_lds16(qkv + baseK + (size_t)(KT * 64 + grow) * (3 * CC) +
                    (schunk ^ srow) * 8,
                (char*)Ks[BUF] + wq * 1024);
    gload_lds16(vT + vbase + (size_t)grow * TT + KT * 64 + (schunk ^ srow) * 8,
                (char*)Vs[BUF] + wq * 1024);
  };

  stage(0, 0);
  asm volatile("s_waitcnt vmcnt(0)" ::: "memory");
  __builtin_amdgcn_s_barrier();

  for (int kt = 0; kt < nt; ++kt) {
    const int cur = kt & 1;
    if (kt + 1 < nt) stage(kt + 1, cur ^ 1);  // overlaps with compute below

    if (kt * 64 <= qminw + 15) {  // wave has unmasked rows in this tile
      // ---- S^T = K Q^T : sa[f] rows k=f*16+l4*4+r, col q=l15 ----
      floatx4 sa[4];
#pragma unroll
      for (int f = 0; f < 4; ++f) sa[f] = (floatx4){0.f, 0.f, 0.f, 0.f};

      __builtin_amdgcn_s_setprio(1);
#pragma unroll
      for (int kc = 0; kc < 2; ++kc) {
#pragma unroll
        for (int f = 0; f < 4; ++f) {
          const int row = 16 * f + l15;
          short8 bk = *(const short8*)(Ks[cur] + row * 64 +
                                       ((kc * 4 + l4) ^ (row & 7)) * 8);
          sa[f] = __builtin_amdgcn_mfma_f32_16x16x32_bf16(bk, aq[kc], sa[f], 0, 0, 0);
        }
      }
      __builtin_amdgcn_s_setprio(0);

      // ---- in-register online softmax; pack P to LDS ----
      const int qg = qminw + l15;
      const bool needmask = (kt * 64 + 63 > qminw);
      float rm = -1e30f;
#pragma unroll
      for (int f = 0; f < 4; ++f)
#pragma unroll
        for (int r = 0; r < 4; ++r) {
          float s = sa[f][r] * 0.125f;
          if (needmask) {
            const int kg = kt * 64 + f * 16 + l4 * 4 + r;
            if (kg > qg) s = -1e30f;
          }
          sa[f][r] = s;
          rm = fmaxf(rm, s);
        }
      rm = fmaxf(rm, __shfl_xor(rm, 16, 64));
      rm = fmaxf(rm, __shfl_xor(rm, 32, 64));
      const float mn = fmaxf(m_i, rm);
      const float scale = __expf(m_i - mn);
      float rs = 0.f;
#pragma unroll
      for (int f = 0; f < 4; ++f)
#pragma unroll
        for (int r = 0; r < 4; ++r) {
          const float p = __expf(sa[f][r] - mn);
          sa[f][r] = p;
          rs += p;
        }
      rs += __shfl_xor(rs, 16, 64);
      rs += __shfl_xor(rs, 32, 64);
      l_i = l_i * scale + rs;
      m_i = mn;
#pragma unroll
      for (int nd = 0; nd < 4; ++nd) accT[nd] *= scale;

      // P^T pack: lane (q=l15) holds k=f*16+l4*4+0..3 -> b64 per f
      char* Pg = (char*)Ps[wq];
#pragma unroll
      for (int f = 0; f < 4; ++f) {
        uintx2 dw;
        dw[0] = pack_bf16x2(sa[f][0], sa[f][1]);
        dw[1] = pack_bf16x2(sa[f][2], sa[f][3]);
        const int c = f * 2 + (l4 >> 1);
        *(uintx2*)(Pg + l15 * 128 + ((c ^ (l15 & 7)) * 16) + (l4 & 1) * 8) = dw;
      }
      asm volatile("s_waitcnt lgkmcnt(0)" ::: "memory");  // same-wave RAW

      // ---- B-frags of P: lane l15 = q, k = kc*32 + l4*8 ----
      short8 pb[2];
#pragma unroll
      for (int kc = 0; kc < 2; ++kc) {
        const int c = kc * 4 + l4;
        pb[kc] = *(const short8*)(Pg + l15 * 128 + ((c ^ (l15 & 7)) * 16));
      }

      // ---- O^T += V^T P ----
      __builtin_amdgcn_s_setprio(1);
#pragma unroll
      for (int kc = 0; kc < 2; ++kc) {
#pragma unroll
        for (int nd = 0; nd < 4; ++nd) {
          const int row = 16 * nd + l15;
          short8 vb = *(const short8*)(Vs[cur] + row * 64 +
                                       ((kc * 4 + l4) ^ (row & 7)) * 8);
          accT[nd] = __builtin_amdgcn_mfma_f32_16x16x32_bf16(vb, pb[kc], accT[nd], 0, 0, 0);
        }
      }
      __builtin_amdgcn_s_setprio(0);
    }

    asm volatile("s_waitcnt vmcnt(0)" ::: "memory");
    __builtin_amdgcn_s_barrier();
  }

  // ---- epilogue: O = (O^T)^T via per-wave LDS, then coalesced store ----
  char* Pw = (char*)Ps[wq];
  {
    const float inv = 1.0f / l_i;
#pragma unroll
    for (int nd = 0; nd < 4; ++nd) {
      uintx2 dw;
      dw[0] = pack_bf16x2(accT[nd][0] * inv, accT[nd][1] * inv);
      dw[1] = pack_bf16x2(accT[nd][2] * inv, accT[nd][3] * inv);
      const int c = nd * 2 + (l4 >> 1);
      *(uintx2*)(Pw + l15 * 128 + ((c ^ (l15 & 7)) * 16) + (l4 & 1) * 8) = dw;
    }
  }
  asm volatile("s_waitcnt lgkmcnt(0)" ::: "memory");
#pragma unroll
  for (int ch = 0; ch < 2; ++ch) {
    const int q16 = lane >> 2;
    const int c = ch * 4 + (lane & 3);
    ushort8 o = *(const ushort8*)(Pw + q16 * 128 + ((c ^ (q16 & 7)) * 16));
    const int qg = qminw + q16;
    *(ushort8*)(y + (size_t)(b * TT + qg) * CC + h * DHEAD + c * 8) = o;
  }
}

extern "C" void kernel_launch(void* const* d_in, const int* in_sizes, int n_in,
                              void* d_out, int out_size, void* d_ws, size_t ws_size,
                              hipStream_t stream) {
  const float* x      = (const float*)d_in[0];
  const float* W_attn = (const float*)d_in[1];
  const float* b_attn = (const float*)d_in[2];
  const float* W_proj = (const float*)d_in[3];
  const float* b_proj = (const float*)d_in[4];
  float* out = (float*)d_out;

  const int M = BB * TT;  // 4096

  // workspace layout (ushort units)
  unsigned short* qkvb = (unsigned short*)d_ws;          // M * 3C
  unsigned short* xb   = qkvb + (size_t)M * 3 * CC;      // M * C
  unsigned short* Wat  = xb + (size_t)M * CC;            // 3C * C
  unsigned short* Wpt  = Wat + (size_t)3 * CC * CC;      // C * C
  unsigned short* yb   = Wpt + (size_t)CC * CC;          // M * C
  unsigned short* vTb  = yb + (size_t)M * CC;            // B*H*D*T

  cvt_bf16_kernel<<<(M * CC) / 1024, 256, 0, stream>>>(x, xb, M * CC);
  {
    dim3 g((3 * CC) / 32, CC / 32);
    transpose_cvt_kernel<<<g, 256, 0, stream>>>(W_attn, Wat, CC, 3 * CC);
  }
  {
    dim3 g(CC / 32, CC / 32);
    transpose_cvt_kernel<<<g, 256, 0, stream>>>(W_proj, Wpt, CC, CC);
  }

  // GEMM1: qkv = x @ W_attn + b_attn (plain layout, coalesced stores)
  {
    dim3 grid((3 * CC) / 128, M / 128);
    gemm_mfma_kernel<true><<<grid, 256, 0, stream>>>(xb, Wat, b_attn, qkvb, M, 3 * CC, CC);
  }

  // V -> vT[b][h][d][T]
  {
    dim3 grid(TT / 64, BB * NHEAD);
    transpose_v_kernel<<<grid, 256, 0, stream>>>(qkvb, vTb);
  }

  // MFMA flash attention (128-row q tiles, 8 waves)
  {
    dim3 grid(TT / 128, BB * NHEAD);
    flash_mfma_kernel<<<grid, 512, 0, stream>>>(qkvb, vTb, yb);
  }

  // GEMM2: out = y @ W_proj + b_proj (fp32 out)
  {
    dim3 grid(CC / 128, M / 128);
    gemm_mfma_kernel<false><<<grid, 256, 0, stream>>>(yb, Wpt, b_proj, out, M, CC, CC);
  }
}

// Round 8
// 148.456 us; speedup vs baseline: 27.1843x; 1.0778x over previous
//
#include <hip/hip_runtime.h>

#define BB 2
#define TT 2048
#define CC 1024
#define NHEAD 16
#define DHEAD 64

typedef __attribute__((ext_vector_type(8))) short short8;     // bf16x8 MFMA frag
typedef __attribute__((ext_vector_type(8))) unsigned short ushort8;
typedef __attribute__((ext_vector_type(4))) float floatx4;
typedef __attribute__((ext_vector_type(2))) unsigned int uintx2;

__device__ inline unsigned short f32_to_bf16_rne(float f) {
  unsigned u = __builtin_bit_cast(unsigned, f);
  unsigned r = (u + 0x7FFFu + ((u >> 16) & 1u)) >> 16;
  return (unsigned short)r;
}
__device__ inline unsigned pack_bf16x2(float lo, float hi) {
  return (unsigned)f32_to_bf16_rne(lo) | ((unsigned)f32_to_bf16_rne(hi) << 16);
}
__device__ inline void gload_lds16(const void* g, void* l) {
  __builtin_amdgcn_global_load_lds(
      (const __attribute__((address_space(1))) void*)g,
      (__attribute__((address_space(3))) void*)l, 16, 0, 0);
}

// ---------------------------------------------------------------------------
// fp32 -> bf16 straight convert
// ---------------------------------------------------------------------------
__global__ __launch_bounds__(256) void cvt_bf16_kernel(
    const float* __restrict__ in, unsigned short* __restrict__ outp, int n) {
  int i = (blockIdx.x * 256 + threadIdx.x) * 4;
  if (i < n) {
    float4 v = *(const float4*)(in + i);
    ushort4 o;
    o.x = f32_to_bf16_rne(v.x);
    o.y = f32_to_bf16_rne(v.y);
    o.z = f32_to_bf16_rne(v.z);
    o.w = f32_to_bf16_rne(v.w);
    *(ushort4*)(outp + i) = o;
  }
}

// ---------------------------------------------------------------------------
// W[K][N] fp32 -> Wt[N][K] bf16 (32x32 LDS tile transpose)
// ---------------------------------------------------------------------------
__global__ __launch_bounds__(256) void transpose_cvt_kernel(
    const float* __restrict__ W, unsigned short* __restrict__ Wt, int K, int N) {
  __shared__ float T[32][33];
  const int tx = threadIdx.x & 31;
  const int ty = threadIdx.x >> 5;
  const int r0 = blockIdx.y * 32;
  const int c0 = blockIdx.x * 32;
#pragma unroll
  for (int i = 0; i < 4; ++i)
    T[ty + i * 8][tx] = W[(size_t)(r0 + ty + i * 8) * N + c0 + tx];
  __syncthreads();
#pragma unroll
  for (int i = 0; i < 4; ++i)
    Wt[(size_t)(c0 + ty + i * 8) * K + r0 + tx] = f32_to_bf16_rne(T[tx][ty + i * 8]);
}

// ---------------------------------------------------------------------------
// V part of qkv (bf16, [B,T,3C] at col 2C+h*64) -> vT[b][h][d][T]
// 64x64 tiles through LDS; coalesced on both sides.
// ---------------------------------------------------------------------------
__global__ __launch_bounds__(256) void transpose_v_kernel(
    const unsigned short* __restrict__ qkv, unsigned short* __restrict__ vT) {
  __shared__ unsigned short Ts[64][72];
  const int tt0 = blockIdx.x * 64;
  const int bh = blockIdx.y;
  const int h = bh & (NHEAD - 1);
  const int b = bh >> 4;
  const int tid = threadIdx.x;
  const unsigned short* src = qkv + (size_t)(b * TT) * (3 * CC) + 2 * CC + h * DHEAD;
#pragma unroll
  for (int it = 0; it < 2; ++it) {
    const int t = it * 32 + (tid >> 3);
    const int d8 = (tid & 7) * 8;
    ushort8 v = *(const ushort8*)(src + (size_t)(tt0 + t) * (3 * CC) + d8);
#pragma unroll
    for (int j = 0; j < 8; ++j) Ts[t][d8 + j] = v[j];
  }
  __syncthreads();
  unsigned short* dst = vT + ((size_t)((b * NHEAD + h) * DHEAD)) * TT;
#pragma unroll
  for (int it = 0; it < 2; ++it) {
    const int d = it * 32 + (tid >> 3);
    const int t8 = (tid & 7) * 8;
    ushort8 o;
#pragma unroll
    for (int j = 0; j < 8; ++j) o[j] = Ts[t8 + j][d];
    *(ushort8*)(dst + (size_t)d * TT + tt0 + t8) = o;
  }
}

// ---------------------------------------------------------------------------
// bf16 MFMA GEMM: C[M][N] = A[M][K] @ Bt[N][K]^T + bias[N]
// 128x128 tile, BK=32, 256 threads (4 waves, 2x2 of 64x64).
// ---------------------------------------------------------------------------
template <bool BF16_OUT>
__global__ __launch_bounds__(256) void gemm_mfma_kernel(
    const unsigned short* __restrict__ A, const unsigned short* __restrict__ Bt,
    const float* __restrict__ bias, void* __restrict__ Cout,
    int M, int N, int K) {
  __shared__ unsigned short As[128 * 32];
  __shared__ unsigned short Bs[128 * 32];

  const int tid = threadIdx.x;
  const int wave = tid >> 6;
  const int lane = tid & 63;
  const int row0 = blockIdx.y * 128;
  const int col0 = blockIdx.x * 128;
  const int wr = (wave >> 1) * 64;
  const int wc = (wave & 1) * 64;

  floatx4 acc[4][4];
#pragma unroll
  for (int m = 0; m < 4; ++m)
#pragma unroll
    for (int n = 0; n < 4; ++n) acc[m][n] = (floatx4){0.f, 0.f, 0.f, 0.f};

  const int sRow = lane >> 2;
  const int sK = (lane & 3) * 8;

  for (int k0 = 0; k0 < K; k0 += 32) {
#pragma unroll
    for (int c = 0; c < 2; ++c) {
      const int g = c * 4 + wave;
      gload_lds16(A + (size_t)(row0 + g * 16 + sRow) * K + k0 + sK,
                  (char*)As + g * 1024);
      gload_lds16(Bt + (size_t)(col0 + g * 16 + sRow) * K + k0 + sK,
                  (char*)Bs + g * 1024);
    }
    __syncthreads();

    short8 af[4], bf[4];
#pragma unroll
    for (int m = 0; m < 4; ++m)
      af[m] = *(const short8*)(As + (wr + m * 16 + (lane & 15)) * 32 + (lane >> 4) * 8);
#pragma unroll
    for (int n = 0; n < 4; ++n)
      bf[n] = *(const short8*)(Bs + (wc + n * 16 + (lane & 15)) * 32 + (lane >> 4) * 8);
#pragma unroll
    for (int m = 0; m < 4; ++m)
#pragma unroll
      for (int n = 0; n < 4; ++n)
        acc[m][n] = __builtin_amdgcn_mfma_f32_16x16x32_bf16(af[m], bf[n], acc[m][n], 0, 0, 0);
    __syncthreads();
  }

  const int cl = lane & 15;
  const int rg = (lane >> 4) * 4;
#pragma unroll
  for (int m = 0; m < 4; ++m) {
#pragma unroll
    for (int n = 0; n < 4; ++n) {
      const int col = col0 + wc + n * 16 + cl;
      const float bv = bias[col];
#pragma unroll
      for (int r = 0; r < 4; ++r) {
        const int row = row0 + wr + m * 16 + rg + r;
        const float v = acc[m][n][r] + bv;
        if (BF16_OUT)
          ((unsigned short*)Cout)[(size_t)row * N + col] = f32_to_bf16_rne(v);
        else
          ((float*)Cout)[(size_t)row * N + col] = v;
      }
    }
  }
}

// ---------------------------------------------------------------------------
// MFMA flash attention, swapped-operand form, 8 waves x 16 q-rows.
// 1-D grid of 512 with COMPLEMENTARY-qt pairing: blocks id and id+256 get
// qt = 15-k and k, so any CU's two resident blocks total ~34 tile-iters
// (balanced) instead of up to 64 (same-qt pairing of the 2-D grid).
// Softmax in log2 domain (exp2), scale folded: S*1/8*log2e.
// ---------------------------------------------------------------------------
__global__ __launch_bounds__(512) void flash_mfma_kernel(
    const unsigned short* __restrict__ qkv,
    const unsigned short* __restrict__ vT,
    unsigned short* __restrict__ y) {
  __shared__ unsigned short Ks[2][64 * 64];   // [token][d-chunk swz]
  __shared__ unsigned short Vs[2][64 * 64];   // [d][k-chunk swz]
  __shared__ unsigned short Ps[8][16 * 64];   // per-wave P / O^T staging

  // complementary-qt mapping (bijective over 512)
  const int id = blockIdx.x;
  const int half = id >> 8;          // 0 | 1
  const int id2 = id & 255;
  const int bh = half * 16 + (id2 >> 4);
  const int qtx = id2 & 15;
  const int qt = half ? qtx : 15 - qtx;

  const int h = bh & (NHEAD - 1);
  const int b = bh >> 4;
  const int tid = threadIdx.x;
  const int wq = tid >> 6;      // 0..7
  const int lane = tid & 63;
  const int l15 = lane & 15;
  const int l4 = lane >> 4;
  const int srow = lane >> 3;   // 0..7
  const int schunk = lane & 7;  // 0..7

  const int qminw = qt * 128 + wq * 16;

  const size_t baseQ = (size_t)(b * TT) * (3 * CC) + h * DHEAD;
  const size_t baseK = baseQ + CC;
  const size_t vbase = (size_t)((b * NHEAD + h) * DHEAD) * TT;

  // Q B-frags: lane l15 = q-row, d = kc*32 + l4*8
  short8 aq[2];
  {
    const unsigned short* qp =
        qkv + baseQ + (size_t)(qminw + l15) * (3 * CC) + l4 * 8;
    aq[0] = *(const short8*)(qp);
    aq[1] = *(const short8*)(qp + 32);
  }

  floatx4 accT[4];  // [nd]: O^T[d=nd*16+l4*4+r][q=l15]
  float m_i = -1e30f, l_i = 0.f;   // log2-domain running max
#pragma unroll
  for (int n = 0; n < 4; ++n) accT[n] = (floatx4){0.f, 0.f, 0.f, 0.f};

  const int nt = 2 * qt + 2;
  const float SCL = 0.125f * 1.44269504089f;  // 1/sqrt(64) * log2(e)

  auto stage = [&](int KT, int BUF) {
    const int grow = wq * 8 + srow;
    gload_lds16(qkv + baseK + (size_t)(KT * 64 + grow) * (3 * CC) +
                    (schunk ^ srow) * 8,
                (char*)Ks[BUF] + wq * 1024);
    gload_lds16(vT + vbase + (size_t)grow * TT + KT * 64 + (schunk ^ srow) * 8,
                (char*)Vs[BUF] + wq * 1024);
  };

  stage(0, 0);
  asm volatile("s_waitcnt vmcnt(0)" ::: "memory");
  __builtin_amdgcn_s_barrier();

  for (int kt = 0; kt < nt; ++kt) {
    const int cur = kt & 1;
    if (kt + 1 < nt) stage(kt + 1, cur ^ 1);  // overlaps with compute below

    if (kt * 64 <= qminw + 15) {  // wave has unmasked rows in this tile
      // ---- S^T = K Q^T : sa[f] rows k=f*16+l4*4+r, col q=l15 ----
      floatx4 sa[4];
#pragma unroll
      for (int f = 0; f < 4; ++f) sa[f] = (floatx4){0.f, 0.f, 0.f, 0.f};

      __builtin_amdgcn_s_setprio(1);
#pragma unroll
      for (int kc = 0; kc < 2; ++kc) {
#pragma unroll
        for (int f = 0; f < 4; ++f) {
          const int row = 16 * f + l15;
          short8 bk = *(const short8*)(Ks[cur] + row * 64 +
                                       ((kc * 4 + l4) ^ (row & 7)) * 8);
          sa[f] = __builtin_amdgcn_mfma_f32_16x16x32_bf16(bk, aq[kc], sa[f], 0, 0, 0);
        }
      }
      __builtin_amdgcn_s_setprio(0);

      // ---- in-register online softmax (log2 domain) ----
      const int qg = qminw + l15;
      const bool needmask = (kt * 64 + 63 > qminw);
      float rm = -1e30f;
#pragma unroll
      for (int f = 0; f < 4; ++f)
#pragma unroll
        for (int r = 0; r < 4; ++r) {
          float s = sa[f][r] * SCL;
          if (needmask) {
            const int kg = kt * 64 + f * 16 + l4 * 4 + r;
            if (kg > qg) s = -1e30f;
          }
          sa[f][r] = s;
          rm = fmaxf(rm, s);
        }
      rm = fmaxf(rm, __shfl_xor(rm, 16, 64));
      rm = fmaxf(rm, __shfl_xor(rm, 32, 64));
      const float mn = fmaxf(m_i, rm);
      const float scale = exp2f(m_i - mn);
      float rs = 0.f;
#pragma unroll
      for (int f = 0; f < 4; ++f)
#pragma unroll
        for (int r = 0; r < 4; ++r) {
          const float p = exp2f(sa[f][r] - mn);
          sa[f][r] = p;
          rs += p;
        }
      rs += __shfl_xor(rs, 16, 64);
      rs += __shfl_xor(rs, 32, 64);
      l_i = l_i * scale + rs;
      m_i = mn;
#pragma unroll
      for (int nd = 0; nd < 4; ++nd) accT[nd] *= scale;

      // P^T pack: lane (q=l15) holds k=f*16+l4*4+0..3 -> b64 per f
      char* Pg = (char*)Ps[wq];
#pragma unroll
      for (int f = 0; f < 4; ++f) {
        uintx2 dw;
        dw[0] = pack_bf16x2(sa[f][0], sa[f][1]);
        dw[1] = pack_bf16x2(sa[f][2], sa[f][3]);
        const int c = f * 2 + (l4 >> 1);
        *(uintx2*)(Pg + l15 * 128 + ((c ^ (l15 & 7)) * 16) + (l4 & 1) * 8) = dw;
      }
      asm volatile("s_waitcnt lgkmcnt(0)" ::: "memory");  // same-wave RAW

      // ---- B-frags of P: lane l15 = q, k = kc*32 + l4*8 ----
      short8 pb[2];
#pragma unroll
      for (int kc = 0; kc < 2; ++kc) {
        const int c = kc * 4 + l4;
        pb[kc] = *(const short8*)(Pg + l15 * 128 + ((c ^ (l15 & 7)) * 16));
      }

      // ---- O^T += V^T P ----
      __builtin_amdgcn_s_setprio(1);
#pragma unroll
      for (int kc = 0; kc < 2; ++kc) {
#pragma unroll
        for (int nd = 0; nd < 4; ++nd) {
          const int row = 16 * nd + l15;
          short8 vb = *(const short8*)(Vs[cur] + row * 64 +
                                       ((kc * 4 + l4) ^ (row & 7)) * 8);
          accT[nd] = __builtin_amdgcn_mfma_f32_16x16x32_bf16(vb, pb[kc], accT[nd], 0, 0, 0);
        }
      }
      __builtin_amdgcn_s_setprio(0);
    }

    asm volatile("s_waitcnt vmcnt(0)" ::: "memory");
    __builtin_amdgcn_s_barrier();
  }

  // ---- epilogue: O = (O^T)^T via per-wave LDS, then coalesced store ----
  char* Pw = (char*)Ps[wq];
  {
    const float inv = 1.0f / l_i;
#pragma unroll
    for (int nd = 0; nd < 4; ++nd) {
      uintx2 dw;
      dw[0] = pack_bf16x2(accT[nd][0] * inv, accT[nd][1] * inv);
      dw[1] = pack_bf16x2(accT[nd][2] * inv, accT[nd][3] * inv);
      const int c = nd * 2 + (l4 >> 1);
      *(uintx2*)(Pw + l15 * 128 + ((c ^ (l15 & 7)) * 16) + (l4 & 1) * 8) = dw;
    }
  }
  asm volatile("s_waitcnt lgkmcnt(0)" ::: "memory");
#pragma unroll
  for (int ch = 0; ch < 2; ++ch) {
    const int q16 = lane >> 2;
    const int c = ch * 4 + (lane & 3);
    ushort8 o = *(const ushort8*)(Pw + q16 * 128 + ((c ^ (q16 & 7)) * 16));
    const int qg = qminw + q16;
    *(ushort8*)(y + (size_t)(b * TT + qg) * CC + h * DHEAD + c * 8) = o;
  }
}

extern "C" void kernel_launch(void* const* d_in, const int* in_sizes, int n_in,
                              void* d_out, int out_size, void* d_ws, size_t ws_size,
                              hipStream_t stream) {
  const float* x      = (const float*)d_in[0];
  const float* W_attn = (const float*)d_in[1];
  const float* b_attn = (const float*)d_in[2];
  const float* W_proj = (const float*)d_in[3];
  const float* b_proj = (const float*)d_in[4];
  float* out = (float*)d_out;

  const int M = BB * TT;  // 4096

  // workspace layout (ushort units)
  unsigned short* qkvb = (unsigned short*)d_ws;          // M * 3C
  unsigned short* xb   = qkvb + (size_t)M * 3 * CC;      // M * C
  unsigned short* Wat  = xb + (size_t)M * CC;            // 3C * C
  unsigned short* Wpt  = Wat + (size_t)3 * CC * CC;      // C * C
  unsigned short* yb   = Wpt + (size_t)CC * CC;          // M * C
  unsigned short* vTb  = yb + (size_t)M * CC;            // B*H*D*T

  cvt_bf16_kernel<<<(M * CC) / 1024, 256, 0, stream>>>(x, xb, M * CC);
  {
    dim3 g((3 * CC) / 32, CC / 32);
    transpose_cvt_kernel<<<g, 256, 0, stream>>>(W_attn, Wat, CC, 3 * CC);
  }
  {
    dim3 g(CC / 32, CC / 32);
    transpose_cvt_kernel<<<g, 256, 0, stream>>>(W_proj, Wpt, CC, CC);
  }

  // GEMM1: qkv = x @ W_attn + b_attn (plain layout, coalesced stores)
  {
    dim3 grid((3 * CC) / 128, M / 128);
    gemm_mfma_kernel<true><<<grid, 256, 0, stream>>>(xb, Wat, b_attn, qkvb, M, 3 * CC, CC);
  }

  // V -> vT[b][h][d][T]
  {
    dim3 grid(TT / 64, BB * NHEAD);
    transpose_v_kernel<<<grid, 256, 0, stream>>>(qkvb, vTb);
  }

  // MFMA flash attention (128-row q tiles, 8 waves, balanced 1-D grid)
  flash_mfma_kernel<<<512, 512, 0, stream>>>(qkvb, vTb, yb);

  // GEMM2: out = y @ W_proj + b_proj (fp32 out)
  {
    dim3 grid(CC / 128, M / 128);
    gemm_mfma_kernel<false><<<grid, 256, 0, stream>>>(yb, Wpt, b_proj, out, M, CC, CC);
  }
}

// Round 9
// 135.655 us; speedup vs baseline: 29.7496x; 1.0944x over previous
//
#include <hip/hip_runtime.h>

#define BB 2
#define TT 2048
#define CC 1024
#define NHEAD 16
#define DHEAD 64

typedef __attribute__((ext_vector_type(8))) short short8;     // bf16x8 MFMA frag
typedef __attribute__((ext_vector_type(8))) unsigned short ushort8;
typedef __attribute__((ext_vector_type(4))) float floatx4;
typedef __attribute__((ext_vector_type(2))) unsigned int uintx2;

__device__ inline unsigned short f32_to_bf16_rne(float f) {
  unsigned u = __builtin_bit_cast(unsigned, f);
  unsigned r = (u + 0x7FFFu + ((u >> 16) & 1u)) >> 16;
  return (unsigned short)r;
}
__device__ inline unsigned cvt_pk_bf16(float lo, float hi) {
  unsigned r;
  asm("v_cvt_pk_bf16_f32 %0, %1, %2" : "=v"(r) : "v"(lo), "v"(hi));
  return r;
}
__device__ inline void gload_lds16(const void* g, void* l) {
  __builtin_amdgcn_global_load_lds(
      (const __attribute__((address_space(1))) void*)g,
      (__attribute__((address_space(3))) void*)l, 16, 0, 0);
}

// ---------------------------------------------------------------------------
// fp32 -> bf16 straight convert
// ---------------------------------------------------------------------------
__global__ __launch_bounds__(256) void cvt_bf16_kernel(
    const float* __restrict__ in, unsigned short* __restrict__ outp, int n) {
  int i = (blockIdx.x * 256 + threadIdx.x) * 4;
  if (i < n) {
    float4 v = *(const float4*)(in + i);
    ushort4 o;
    o.x = f32_to_bf16_rne(v.x);
    o.y = f32_to_bf16_rne(v.y);
    o.z = f32_to_bf16_rne(v.z);
    o.w = f32_to_bf16_rne(v.w);
    *(ushort4*)(outp + i) = o;
  }
}

// ---------------------------------------------------------------------------
// scaled bias copy: out[i] = b[i] * (i < cut ? scl : 1)
// ---------------------------------------------------------------------------
__global__ __launch_bounds__(256) void bias_scale_kernel(
    const float* __restrict__ b, float* __restrict__ outp, int cut, float scl, int n) {
  int i = blockIdx.x * 256 + threadIdx.x;
  if (i < n) outp[i] = b[i] * (i < cut ? scl : 1.0f);
}

// ---------------------------------------------------------------------------
// W[K][N] fp32 -> Wt[N][K] bf16 (32x32 LDS tile transpose).
// Output rows (= W cols) < scale_cut are multiplied by scl (Q pre-scaling).
// ---------------------------------------------------------------------------
__global__ __launch_bounds__(256) void transpose_cvt_kernel(
    const float* __restrict__ W, unsigned short* __restrict__ Wt, int K, int N,
    int scale_cut, float scl) {
  __shared__ float T[32][33];
  const int tx = threadIdx.x & 31;
  const int ty = threadIdx.x >> 5;
  const int r0 = blockIdx.y * 32;
  const int c0 = blockIdx.x * 32;
#pragma unroll
  for (int i = 0; i < 4; ++i)
    T[ty + i * 8][tx] = W[(size_t)(r0 + ty + i * 8) * N + c0 + tx];
  __syncthreads();
#pragma unroll
  for (int i = 0; i < 4; ++i) {
    const int nrow = c0 + ty + i * 8;
    const float s = (nrow < scale_cut) ? scl : 1.0f;
    Wt[(size_t)nrow * K + r0 + tx] = f32_to_bf16_rne(T[tx][ty + i * 8] * s);
  }
}

// ---------------------------------------------------------------------------
// V part of qkv (bf16, [B,T,3C] at col 2C+h*64) -> vT[b][h][d][T]
// ---------------------------------------------------------------------------
__global__ __launch_bounds__(256) void transpose_v_kernel(
    const unsigned short* __restrict__ qkv, unsigned short* __restrict__ vT) {
  __shared__ unsigned short Ts[64][72];
  const int tt0 = blockIdx.x * 64;
  const int bh = blockIdx.y;
  const int h = bh & (NHEAD - 1);
  const int b = bh >> 4;
  const int tid = threadIdx.x;
  const unsigned short* src = qkv + (size_t)(b * TT) * (3 * CC) + 2 * CC + h * DHEAD;
#pragma unroll
  for (int it = 0; it < 2; ++it) {
    const int t = it * 32 + (tid >> 3);
    const int d8 = (tid & 7) * 8;
    ushort8 v = *(const ushort8*)(src + (size_t)(tt0 + t) * (3 * CC) + d8);
#pragma unroll
    for (int j = 0; j < 8; ++j) Ts[t][d8 + j] = v[j];
  }
  __syncthreads();
  unsigned short* dst = vT + ((size_t)((b * NHEAD + h) * DHEAD)) * TT;
#pragma unroll
  for (int it = 0; it < 2; ++it) {
    const int d = it * 32 + (tid >> 3);
    const int t8 = (tid & 7) * 8;
    ushort8 o;
#pragma unroll
    for (int j = 0; j < 8; ++j) o[j] = Ts[t8 + j][d];
    *(ushort8*)(dst + (size_t)d * TT + tt0 + t8) = o;
  }
}

// ---------------------------------------------------------------------------
// bf16 MFMA GEMM: C[M][N] = A[M][K] @ Bt[N][K]^T + bias[N]
// 128xBN tile (BN=128 or 64), BK=32, 256 threads (4 waves, 2x2).
// BN=64 doubles the grid for small-N outputs (2 blocks/CU instead of 1).
// ---------------------------------------------------------------------------
template <bool BF16_OUT, int BN>
__global__ __launch_bounds__(256) void gemm_mfma_kernel(
    const unsigned short* __restrict__ A, const unsigned short* __restrict__ Bt,
    const float* __restrict__ bias, void* __restrict__ Cout,
    int M, int N, int K) {
  constexpr int NR = BN / 32;  // col frags per wave
  __shared__ unsigned short As[128 * 32];
  __shared__ unsigned short Bs[BN * 32];

  const int tid = threadIdx.x;
  const int wave = tid >> 6;
  const int lane = tid & 63;
  const int row0 = blockIdx.y * 128;
  const int col0 = blockIdx.x * BN;
  const int wr = (wave >> 1) * 64;
  const int wc = (wave & 1) * (BN / 2);

  floatx4 acc[4][NR];
#pragma unroll
  for (int m = 0; m < 4; ++m)
#pragma unroll
    for (int n = 0; n < NR; ++n) acc[m][n] = (floatx4){0.f, 0.f, 0.f, 0.f};

  const int sRow = lane >> 2;
  const int sK = (lane & 3) * 8;

  for (int k0 = 0; k0 < K; k0 += 32) {
#pragma unroll
    for (int c = 0; c < 2; ++c) {
      const int g = c * 4 + wave;
      gload_lds16(A + (size_t)(row0 + g * 16 + sRow) * K + k0 + sK,
                  (char*)As + g * 1024);
    }
    if constexpr (BN == 128) {
#pragma unroll
      for (int c = 0; c < 2; ++c) {
        const int g = c * 4 + wave;
        gload_lds16(Bt + (size_t)(col0 + g * 16 + sRow) * K + k0 + sK,
                    (char*)Bs + g * 1024);
      }
    } else {
      gload_lds16(Bt + (size_t)(col0 + wave * 16 + sRow) * K + k0 + sK,
                  (char*)Bs + wave * 1024);
    }
    __syncthreads();

    short8 af[4], bf[NR];
#pragma unroll
    for (int m = 0; m < 4; ++m)
      af[m] = *(const short8*)(As + (wr + m * 16 + (lane & 15)) * 32 + (lane >> 4) * 8);
#pragma unroll
    for (int n = 0; n < NR; ++n)
      bf[n] = *(const short8*)(Bs + (wc + n * 16 + (lane & 15)) * 32 + (lane >> 4) * 8);
#pragma unroll
    for (int m = 0; m < 4; ++m)
#pragma unroll
      for (int n = 0; n < NR; ++n)
        acc[m][n] = __builtin_amdgcn_mfma_f32_16x16x32_bf16(af[m], bf[n], acc[m][n], 0, 0, 0);
    __syncthreads();
  }

  const int cl = lane & 15;
  const int rg = (lane >> 4) * 4;
#pragma unroll
  for (int m = 0; m < 4; ++m) {
#pragma unroll
    for (int n = 0; n < NR; ++n) {
      const int col = col0 + wc + n * 16 + cl;
      const float bv = bias[col];
#pragma unroll
      for (int r = 0; r < 4; ++r) {
        const int row = row0 + wr + m * 16 + rg + r;
        const float v = acc[m][n][r] + bv;
        if (BF16_OUT)
          ((unsigned short*)Cout)[(size_t)row * N + col] = f32_to_bf16_rne(v);
        else
          ((float*)Cout)[(size_t)row * N + col] = v;
      }
    }
  }
}

// ---------------------------------------------------------------------------
// MFMA flash attention, swapped-operand, 8 waves x 16 q-rows, 2-phase pipe.
// Q pre-scaled by 1/8*log2e (folded into W_attn/b_attn) -> S is log2-domain.
// In-register softmax with defer-max (THR=8); cvt_pk bf16 pack.
// Complementary-qt 1-D grid for causal load balance.
// ---------------------------------------------------------------------------
__global__ __launch_bounds__(512) void flash_mfma_kernel(
    const unsigned short* __restrict__ qkv,
    const unsigned short* __restrict__ vT,
    unsigned short* __restrict__ y) {
  __shared__ unsigned short Ks[2][64 * 64];   // [token][d-chunk swz]
  __shared__ unsigned short Vs[2][64 * 64];   // [d][k-chunk swz]
  __shared__ unsigned short Ps[8][16 * 64];   // per-wave P / O^T staging

  // complementary-qt mapping (bijective over 512)
  const int id = blockIdx.x;
  const int half = id >> 8;
  const int id2 = id & 255;
  const int bh = half * 16 + (id2 >> 4);
  const int qtx = id2 & 15;
  const int qt = half ? qtx : 15 - qtx;

  const int h = bh & (NHEAD - 1);
  const int b = bh >> 4;
  const int tid = threadIdx.x;
  const int wq = tid >> 6;      // 0..7
  const int lane = tid & 63;
  const int l15 = lane & 15;
  const int l4 = lane >> 4;
  const int srow = lane >> 3;
  const int schunk = lane & 7;

  const int qminw = qt * 128 + wq * 16;

  const size_t baseQ = (size_t)(b * TT) * (3 * CC) + h * DHEAD;
  const size_t baseK = baseQ + CC;
  const size_t vbase = (size_t)((b * NHEAD + h) * DHEAD) * TT;

  // Q B-frags (pre-scaled): lane l15 = q-row, d = kc*32 + l4*8
  short8 aq[2];
  {
    const unsigned short* qp =
        qkv + baseQ + (size_t)(qminw + l15) * (3 * CC) + l4 * 8;
    aq[0] = *(const short8*)(qp);
    aq[1] = *(const short8*)(qp + 32);
  }

  floatx4 accT[4];  // [nd]: O^T[d=nd*16+l4*4+r][q=l15]
  float m_i = -1e30f, l_i = 0.f;
#pragma unroll
  for (int n = 0; n < 4; ++n) accT[n] = (floatx4){0.f, 0.f, 0.f, 0.f};

  const int nt = 2 * qt + 2;

  auto stage = [&](int KT, int BUF) {
    const int grow = wq * 8 + srow;
    gload_lds16(qkv + baseK + (size_t)(KT * 64 + grow) * (3 * CC) +
                    (schunk ^ srow) * 8,
                (char*)Ks[BUF] + wq * 1024);
    gload_lds16(vT + vbase + (size_t)grow * TT + KT * 64 + (schunk ^ srow) * 8,
                (char*)Vs[BUF] + wq * 1024);
  };

  stage(0, 0);
  asm volatile("s_waitcnt vmcnt(0)" ::: "memory");
  __builtin_amdgcn_s_barrier();

  for (int kt = 0; kt < nt; ++kt) {
    const int cur = kt & 1;
    if (kt + 1 < nt) stage(kt + 1, cur ^ 1);  // overlaps with compute below

    if (kt * 64 <= qminw + 15) {  // wave has unmasked rows in this tile
      // ---- S^T = K Q^T : sa[f] rows k=f*16+l4*4+r, col q=l15 ----
      floatx4 sa[4];
#pragma unroll
      for (int f = 0; f < 4; ++f) sa[f] = (floatx4){0.f, 0.f, 0.f, 0.f};

      __builtin_amdgcn_s_setprio(1);
#pragma unroll
      for (int kc = 0; kc < 2; ++kc) {
#pragma unroll
        for (int f = 0; f < 4; ++f) {
          const int row = 16 * f + l15;
          short8 bk = *(const short8*)(Ks[cur] + row * 64 +
                                       ((kc * 4 + l4) ^ (row & 7)) * 8);
          sa[f] = __builtin_amdgcn_mfma_f32_16x16x32_bf16(bk, aq[kc], sa[f], 0, 0, 0);
        }
      }
      __builtin_amdgcn_s_setprio(0);

      // ---- in-register online softmax (log2 domain, Q pre-scaled) ----
      const int qg = qminw + l15;
      if (kt * 64 + 63 > qminw) {  // only the diagonal tile needs masking
#pragma unroll
        for (int f = 0; f < 4; ++f)
#pragma unroll
          for (int r = 0; r < 4; ++r) {
            const int kg = kt * 64 + f * 16 + l4 * 4 + r;
            if (kg > qg) sa[f][r] = -1e30f;
          }
      }
      float rm = -1e30f;
#pragma unroll
      for (int f = 0; f < 4; ++f)
        rm = fmaxf(rm, fmaxf(fmaxf(sa[f][0], sa[f][1]), fmaxf(sa[f][2], sa[f][3])));
      rm = fmaxf(rm, __shfl_xor(rm, 16, 64));
      rm = fmaxf(rm, __shfl_xor(rm, 32, 64));

      float rs = 0.f;
      if (__all(rm <= m_i + 8.0f)) {
        // deferred: keep old max, skip O/l rescale; P bounded by 2^8
#pragma unroll
        for (int f = 0; f < 4; ++f)
#pragma unroll
          for (int r = 0; r < 4; ++r) {
            const float p = exp2f(sa[f][r] - m_i);
            sa[f][r] = p;
            rs += p;
          }
        rs += __shfl_xor(rs, 16, 64);
        rs += __shfl_xor(rs, 32, 64);
        l_i += rs;
      } else {
        const float mn = fmaxf(m_i, rm);
        const float scale = exp2f(m_i - mn);
#pragma unroll
        for (int f = 0; f < 4; ++f)
#pragma unroll
          for (int r = 0; r < 4; ++r) {
            const float p = exp2f(sa[f][r] - mn);
            sa[f][r] = p;
            rs += p;
          }
        rs += __shfl_xor(rs, 16, 64);
        rs += __shfl_xor(rs, 32, 64);
        l_i = l_i * scale + rs;
        m_i = mn;
#pragma unroll
        for (int nd = 0; nd < 4; ++nd) accT[nd] *= scale;
      }

      // P^T pack via v_cvt_pk_bf16_f32: lane (q=l15) holds k=f*16+l4*4+0..3
      char* Pg = (char*)Ps[wq];
#pragma unroll
      for (int f = 0; f < 4; ++f) {
        uintx2 dw;
        dw[0] = cvt_pk_bf16(sa[f][0], sa[f][1]);
        dw[1] = cvt_pk_bf16(sa[f][2], sa[f][3]);
        const int c = f * 2 + (l4 >> 1);
        *(uintx2*)(Pg + l15 * 128 + ((c ^ (l15 & 7)) * 16) + (l4 & 1) * 8) = dw;
      }
      asm volatile("s_waitcnt lgkmcnt(0)" ::: "memory");  // same-wave RAW

      // ---- B-frags of P: lane l15 = q, k = kc*32 + l4*8 ----
      short8 pb[2];
#pragma unroll
      for (int kc = 0; kc < 2; ++kc) {
        const int c = kc * 4 + l4;
        pb[kc] = *(const short8*)(Pg + l15 * 128 + ((c ^ (l15 & 7)) * 16));
      }

      // ---- O^T += V^T P ----
      __builtin_amdgcn_s_setprio(1);
#pragma unroll
      for (int kc = 0; kc < 2; ++kc) {
#pragma unroll
        for (int nd = 0; nd < 4; ++nd) {
          const int row = 16 * nd + l15;
          short8 vb = *(const short8*)(Vs[cur] + row * 64 +
                                       ((kc * 4 + l4) ^ (row & 7)) * 8);
          accT[nd] = __builtin_amdgcn_mfma_f32_16x16x32_bf16(vb, pb[kc], accT[nd], 0, 0, 0);
        }
      }
      __builtin_amdgcn_s_setprio(0);
    }

    asm volatile("s_waitcnt vmcnt(0)" ::: "memory");
    __builtin_amdgcn_s_barrier();
  }

  // ---- epilogue: O = (O^T)^T via per-wave LDS, then coalesced store ----
  char* Pw = (char*)Ps[wq];
  {
    const float inv = 1.0f / l_i;
#pragma unroll
    for (int nd = 0; nd < 4; ++nd) {
      uintx2 dw;
      dw[0] = cvt_pk_bf16(accT[nd][0] * inv, accT[nd][1] * inv);
      dw[1] = cvt_pk_bf16(accT[nd][2] * inv, accT[nd][3] * inv);
      const int c = nd * 2 + (l4 >> 1);
      *(uintx2*)(Pw + l15 * 128 + ((c ^ (l15 & 7)) * 16) + (l4 & 1) * 8) = dw;
    }
  }
  asm volatile("s_waitcnt lgkmcnt(0)" ::: "memory");
#pragma unroll
  for (int ch = 0; ch < 2; ++ch) {
    const int q16 = lane >> 2;
    const int c = ch * 4 + (lane & 3);
    ushort8 o = *(const ushort8*)(Pw + q16 * 128 + ((c ^ (q16 & 7)) * 16));
    const int qg = qminw + q16;
    *(ushort8*)(y + (size_t)(b * TT + qg) * CC + h * DHEAD + c * 8) = o;
  }
}

extern "C" void kernel_launch(void* const* d_in, const int* in_sizes, int n_in,
                              void* d_out, int out_size, void* d_ws, size_t ws_size,
                              hipStream_t stream) {
  const float* x      = (const float*)d_in[0];
  const float* W_attn = (const float*)d_in[1];
  const float* b_attn = (const float*)d_in[2];
  const float* W_proj = (const float*)d_in[3];
  const float* b_proj = (const float*)d_in[4];
  float* out = (float*)d_out;

  const int M = BB * TT;  // 4096
  const float SCL = 0.125f * 1.44269504089f;  // 1/sqrt(64) * log2(e)

  // workspace layout (ushort units)
  unsigned short* qkvb = (unsigned short*)d_ws;          // M * 3C
  unsigned short* xb   = qkvb + (size_t)M * 3 * CC;      // M * C
  unsigned short* Wat  = xb + (size_t)M * CC;            // 3C * C
  unsigned short* Wpt  = Wat + (size_t)3 * CC * CC;      // C * C
  unsigned short* yb   = Wpt + (size_t)CC * CC;          // M * C
  unsigned short* vTb  = yb + (size_t)M * CC;            // B*H*D*T
  float* bscl = (float*)(vTb + (size_t)BB * NHEAD * DHEAD * TT);  // 3C floats

  cvt_bf16_kernel<<<(M * CC) / 1024, 256, 0, stream>>>(x, xb, M * CC);
  {
    dim3 g((3 * CC) / 32, CC / 32);
    transpose_cvt_kernel<<<g, 256, 0, stream>>>(W_attn, Wat, CC, 3 * CC, CC, SCL);
  }
  {
    dim3 g(CC / 32, CC / 32);
    transpose_cvt_kernel<<<g, 256, 0, stream>>>(W_proj, Wpt, CC, CC, 0, 1.0f);
  }
  bias_scale_kernel<<<(3 * CC) / 256, 256, 0, stream>>>(b_attn, bscl, CC, SCL, 3 * CC);

  // GEMM1: qkv = x @ W_attn + b_attn (Q third pre-scaled via Wat/bscl)
  {
    dim3 grid((3 * CC) / 128, M / 128);
    gemm_mfma_kernel<true, 128><<<grid, 256, 0, stream>>>(xb, Wat, bscl, qkvb, M, 3 * CC, CC);
  }

  // V -> vT[b][h][d][T]
  {
    dim3 grid(TT / 64, BB * NHEAD);
    transpose_v_kernel<<<grid, 256, 0, stream>>>(qkvb, vTb);
  }

  // MFMA flash attention (128-row q tiles, 8 waves, balanced 1-D grid)
  flash_mfma_kernel<<<512, 512, 0, stream>>>(qkvb, vTb, yb);

  // GEMM2: out = y @ W_proj + b_proj (fp32 out, BN=64 -> 512 blocks)
  {
    dim3 grid(CC / 64, M / 128);
    gemm_mfma_kernel<false, 64><<<grid, 256, 0, stream>>>(yb, Wpt, b_proj, out, M, CC, CC);
  }
}

// Round 10
// 134.654 us; speedup vs baseline: 29.9707x; 1.0074x over previous
//
#include <hip/hip_runtime.h>

#define BB 2
#define TT 2048
#define CC 1024
#define NHEAD 16
#define DHEAD 64

typedef __attribute__((ext_vector_type(8))) short short8;     // bf16x8 MFMA frag
typedef __attribute__((ext_vector_type(8))) unsigned short ushort8;
typedef __attribute__((ext_vector_type(4))) float floatx4;
typedef __attribute__((ext_vector_type(2))) unsigned int uintx2;

__device__ inline unsigned short f32_to_bf16_rne(float f) {
  unsigned u = __builtin_bit_cast(unsigned, f);
  unsigned r = (u + 0x7FFFu + ((u >> 16) & 1u)) >> 16;
  return (unsigned short)r;
}
__device__ inline unsigned cvt_pk_bf16(float lo, float hi) {
  unsigned r;
  asm("v_cvt_pk_bf16_f32 %0, %1, %2" : "=v"(r) : "v"(lo), "v"(hi));
  return r;
}
__device__ inline void gload_lds16(const void* g, void* l) {
  __builtin_amdgcn_global_load_lds(
      (const __attribute__((address_space(1))) void*)g,
      (__attribute__((address_space(3))) void*)l, 16, 0, 0);
}

// ---------------------------------------------------------------------------
// fp32 -> bf16 straight convert
// ---------------------------------------------------------------------------
__global__ __launch_bounds__(256) void cvt_bf16_kernel(
    const float* __restrict__ in, unsigned short* __restrict__ outp, int n) {
  int i = (blockIdx.x * 256 + threadIdx.x) * 4;
  if (i < n) {
    float4 v = *(const float4*)(in + i);
    ushort4 o;
    o.x = f32_to_bf16_rne(v.x);
    o.y = f32_to_bf16_rne(v.y);
    o.z = f32_to_bf16_rne(v.z);
    o.w = f32_to_bf16_rne(v.w);
    *(ushort4*)(outp + i) = o;
  }
}

// ---------------------------------------------------------------------------
// scaled bias copy: out[i] = b[i] * (i < cut ? scl : 1)
// ---------------------------------------------------------------------------
__global__ __launch_bounds__(256) void bias_scale_kernel(
    const float* __restrict__ b, float* __restrict__ outp, int cut, float scl, int n) {
  int i = blockIdx.x * 256 + threadIdx.x;
  if (i < n) outp[i] = b[i] * (i < cut ? scl : 1.0f);
}

// ---------------------------------------------------------------------------
// W[K][N] fp32 -> Wt[N][K] bf16 (32x32 LDS tile transpose).
// Output rows (= W cols) < scale_cut are multiplied by scl (Q pre-scaling).
// ---------------------------------------------------------------------------
__global__ __launch_bounds__(256) void transpose_cvt_kernel(
    const float* __restrict__ W, unsigned short* __restrict__ Wt, int K, int N,
    int scale_cut, float scl) {
  __shared__ float T[32][33];
  const int tx = threadIdx.x & 31;
  const int ty = threadIdx.x >> 5;
  const int r0 = blockIdx.y * 32;
  const int c0 = blockIdx.x * 32;
#pragma unroll
  for (int i = 0; i < 4; ++i)
    T[ty + i * 8][tx] = W[(size_t)(r0 + ty + i * 8) * N + c0 + tx];
  __syncthreads();
#pragma unroll
  for (int i = 0; i < 4; ++i) {
    const int nrow = c0 + ty + i * 8;
    const float s = (nrow < scale_cut) ? scl : 1.0f;
    Wt[(size_t)nrow * K + r0 + tx] = f32_to_bf16_rne(T[tx][ty + i * 8] * s);
  }
}

// ---------------------------------------------------------------------------
// V part of qkv (bf16, [B,T,3C] at col 2C+h*64) -> vT[b][h][d][T]
// ---------------------------------------------------------------------------
__global__ __launch_bounds__(256) void transpose_v_kernel(
    const unsigned short* __restrict__ qkv, unsigned short* __restrict__ vT) {
  __shared__ unsigned short Ts[64][72];
  const int tt0 = blockIdx.x * 64;
  const int bh = blockIdx.y;
  const int h = bh & (NHEAD - 1);
  const int b = bh >> 4;
  const int tid = threadIdx.x;
  const unsigned short* src = qkv + (size_t)(b * TT) * (3 * CC) + 2 * CC + h * DHEAD;
#pragma unroll
  for (int it = 0; it < 2; ++it) {
    const int t = it * 32 + (tid >> 3);
    const int d8 = (tid & 7) * 8;
    ushort8 v = *(const ushort8*)(src + (size_t)(tt0 + t) * (3 * CC) + d8);
#pragma unroll
    for (int j = 0; j < 8; ++j) Ts[t][d8 + j] = v[j];
  }
  __syncthreads();
  unsigned short* dst = vT + ((size_t)((b * NHEAD + h) * DHEAD)) * TT;
#pragma unroll
  for (int it = 0; it < 2; ++it) {
    const int d = it * 32 + (tid >> 3);
    const int t8 = (tid & 7) * 8;
    ushort8 o;
#pragma unroll
    for (int j = 0; j < 8; ++j) o[j] = Ts[t8 + j][d];
    *(ushort8*)(dst + (size_t)d * TT + tt0 + t8) = o;
  }
}

// ---------------------------------------------------------------------------
// bf16 MFMA GEMM: C[M][N] = A[M][K] @ Bt[N][K]^T + bias[N]
// 128xBN tile (BN=128 or 64), BK=32, 256 threads (4 waves, 2x2).
// ---------------------------------------------------------------------------
template <bool BF16_OUT, int BN>
__global__ __launch_bounds__(256) void gemm_mfma_kernel(
    const unsigned short* __restrict__ A, const unsigned short* __restrict__ Bt,
    const float* __restrict__ bias, void* __restrict__ Cout,
    int M, int N, int K) {
  constexpr int NR = BN / 32;  // col frags per wave
  __shared__ unsigned short As[128 * 32];
  __shared__ unsigned short Bs[BN * 32];

  const int tid = threadIdx.x;
  const int wave = tid >> 6;
  const int lane = tid & 63;
  const int row0 = blockIdx.y * 128;
  const int col0 = blockIdx.x * BN;
  const int wr = (wave >> 1) * 64;
  const int wc = (wave & 1) * (BN / 2);

  floatx4 acc[4][NR];
#pragma unroll
  for (int m = 0; m < 4; ++m)
#pragma unroll
    for (int n = 0; n < NR; ++n) acc[m][n] = (floatx4){0.f, 0.f, 0.f, 0.f};

  const int sRow = lane >> 2;
  const int sK = (lane & 3) * 8;

  for (int k0 = 0; k0 < K; k0 += 32) {
#pragma unroll
    for (int c = 0; c < 2; ++c) {
      const int g = c * 4 + wave;
      gload_lds16(A + (size_t)(row0 + g * 16 + sRow) * K + k0 + sK,
                  (char*)As + g * 1024);
    }
    if constexpr (BN == 128) {
#pragma unroll
      for (int c = 0; c < 2; ++c) {
        const int g = c * 4 + wave;
        gload_lds16(Bt + (size_t)(col0 + g * 16 + sRow) * K + k0 + sK,
                    (char*)Bs + g * 1024);
      }
    } else {
      gload_lds16(Bt + (size_t)(col0 + wave * 16 + sRow) * K + k0 + sK,
                  (char*)Bs + wave * 1024);
    }
    __syncthreads();

    short8 af[4], bf[NR];
#pragma unroll
    for (int m = 0; m < 4; ++m)
      af[m] = *(const short8*)(As + (wr + m * 16 + (lane & 15)) * 32 + (lane >> 4) * 8);
#pragma unroll
    for (int n = 0; n < NR; ++n)
      bf[n] = *(const short8*)(Bs + (wc + n * 16 + (lane & 15)) * 32 + (lane >> 4) * 8);
#pragma unroll
    for (int m = 0; m < 4; ++m)
#pragma unroll
      for (int n = 0; n < NR; ++n)
        acc[m][n] = __builtin_amdgcn_mfma_f32_16x16x32_bf16(af[m], bf[n], acc[m][n], 0, 0, 0);
    __syncthreads();
  }

  const int cl = lane & 15;
  const int rg = (lane >> 4) * 4;
#pragma unroll
  for (int m = 0; m < 4; ++m) {
#pragma unroll
    for (int n = 0; n < NR; ++n) {
      const int col = col0 + wc + n * 16 + cl;
      const float bv = bias[col];
#pragma unroll
      for (int r = 0; r < 4; ++r) {
        const int row = row0 + wr + m * 16 + rg + r;
        const float v = acc[m][n][r] + bv;
        if (BF16_OUT)
          ((unsigned short*)Cout)[(size_t)row * N + col] = f32_to_bf16_rne(v);
        else
          ((float*)Cout)[(size_t)row * N + col] = v;
      }
    }
  }
}

// ---------------------------------------------------------------------------
// MFMA flash attention, swapped-operand, 4 waves x 16 q-rows (64-row q tiles),
// 2-phase pipe, 40KB LDS -> 4 blocks/CU resident (16 waves/CU).
// Q pre-scaled by 1/8*log2e -> S is log2-domain; defer-max (THR=8);
// cvt_pk bf16 pack; complementary-qt 1-D grid (1024 blocks) for balance.
// ---------------------------------------------------------------------------
__global__ __launch_bounds__(256) void flash_mfma_kernel(
    const unsigned short* __restrict__ qkv,
    const unsigned short* __restrict__ vT,
    unsigned short* __restrict__ y) {
  __shared__ unsigned short Ks[2][64 * 64];   // [token][d-chunk swz]  16KB
  __shared__ unsigned short Vs[2][64 * 64];   // [d][k-chunk swz]      16KB
  __shared__ unsigned short Ps[4][16 * 64];   // per-wave P / O^T       8KB

  // complementary-qt mapping (bijective over 1024 = 32 bh x 32 qt)
  const int id = blockIdx.x;
  const int half = id >> 9;          // 0 | 1
  const int r9 = id & 511;
  const int bh = r9 >> 4;            // 0..31
  const int j = r9 & 15;
  const int qt = half ? j : 31 - j;  // half0: 31..16, half1: 0..15

  const int h = bh & (NHEAD - 1);
  const int b = bh >> 4;
  const int tid = threadIdx.x;
  const int wq = tid >> 6;      // 0..3
  const int lane = tid & 63;
  const int l15 = lane & 15;
  const int l4 = lane >> 4;
  const int srow = lane >> 3;
  const int schunk = lane & 7;

  const int qminw = qt * 64 + wq * 16;

  const size_t baseQ = (size_t)(b * TT) * (3 * CC) + h * DHEAD;
  const size_t baseK = baseQ + CC;
  const size_t vbase = (size_t)((b * NHEAD + h) * DHEAD) * TT;

  // Q B-frags (pre-scaled): lane l15 = q-row, d = kc*32 + l4*8
  short8 aq[2];
  {
    const unsigned short* qp =
        qkv + baseQ + (size_t)(qminw + l15) * (3 * CC) + l4 * 8;
    aq[0] = *(const short8*)(qp);
    aq[1] = *(const short8*)(qp + 32);
  }

  floatx4 accT[4];  // [nd]: O^T[d=nd*16+l4*4+r][q=l15]
  float m_i = -1e30f, l_i = 0.f;
#pragma unroll
  for (int n = 0; n < 4; ++n) accT[n] = (floatx4){0.f, 0.f, 0.f, 0.f};

  const int nt = qt + 1;

  auto stage = [&](int KT, int BUF) {
#pragma unroll
    for (int it = 0; it < 2; ++it) {
      const int blk = it * 4 + wq;      // 8-row block, wave-uniform
      const int grow = blk * 8 + srow;
      gload_lds16(qkv + baseK + (size_t)(KT * 64 + grow) * (3 * CC) +
                      (schunk ^ srow) * 8,
                  (char*)Ks[BUF] + blk * 1024);
      gload_lds16(vT + vbase + (size_t)grow * TT + KT * 64 + (schunk ^ srow) * 8,
                  (char*)Vs[BUF] + blk * 1024);
    }
  };

  stage(0, 0);
  asm volatile("s_waitcnt vmcnt(0)" ::: "memory");
  __builtin_amdgcn_s_barrier();

  for (int kt = 0; kt < nt; ++kt) {
    const int cur = kt & 1;
    if (kt + 1 < nt) stage(kt + 1, cur ^ 1);  // overlaps with compute below

    if (kt * 64 <= qminw + 15) {  // wave has unmasked rows in this tile
      // ---- S^T = K Q^T : sa[f] rows k=f*16+l4*4+r, col q=l15 ----
      floatx4 sa[4];
#pragma unroll
      for (int f = 0; f < 4; ++f) sa[f] = (floatx4){0.f, 0.f, 0.f, 0.f};

      __builtin_amdgcn_s_setprio(1);
#pragma unroll
      for (int kc = 0; kc < 2; ++kc) {
#pragma unroll
        for (int f = 0; f < 4; ++f) {
          const int row = 16 * f + l15;
          short8 bk = *(const short8*)(Ks[cur] + row * 64 +
                                       ((kc * 4 + l4) ^ (row & 7)) * 8);
          sa[f] = __builtin_amdgcn_mfma_f32_16x16x32_bf16(bk, aq[kc], sa[f], 0, 0, 0);
        }
      }
      __builtin_amdgcn_s_setprio(0);

      // ---- in-register online softmax (log2 domain, Q pre-scaled) ----
      const int qg = qminw + l15;
      if (kt * 64 + 63 > qminw) {  // only the diagonal tile needs masking
#pragma unroll
        for (int f = 0; f < 4; ++f)
#pragma unroll
          for (int r = 0; r < 4; ++r) {
            const int kg = kt * 64 + f * 16 + l4 * 4 + r;
            if (kg > qg) sa[f][r] = -1e30f;
          }
      }
      float rm = -1e30f;
#pragma unroll
      for (int f = 0; f < 4; ++f)
        rm = fmaxf(rm, fmaxf(fmaxf(sa[f][0], sa[f][1]), fmaxf(sa[f][2], sa[f][3])));
      rm = fmaxf(rm, __shfl_xor(rm, 16, 64));
      rm = fmaxf(rm, __shfl_xor(rm, 32, 64));

      float rs = 0.f;
      if (__all(rm <= m_i + 8.0f)) {
        // deferred: keep old max, skip O/l rescale; P bounded by 2^8
#pragma unroll
        for (int f = 0; f < 4; ++f)
#pragma unroll
          for (int r = 0; r < 4; ++r) {
            const float p = __builtin_amdgcn_exp2f(sa[f][r] - m_i);
            sa[f][r] = p;
            rs += p;
          }
        rs += __shfl_xor(rs, 16, 64);
        rs += __shfl_xor(rs, 32, 64);
        l_i += rs;
      } else {
        const float mn = fmaxf(m_i, rm);
        const float scale = __builtin_amdgcn_exp2f(m_i - mn);
#pragma unroll
        for (int f = 0; f < 4; ++f)
#pragma unroll
          for (int r = 0; r < 4; ++r) {
            const float p = __builtin_amdgcn_exp2f(sa[f][r] - mn);
            sa[f][r] = p;
            rs += p;
          }
        rs += __shfl_xor(rs, 16, 64);
        rs += __shfl_xor(rs, 32, 64);
        l_i = l_i * scale + rs;
        m_i = mn;
#pragma unroll
        for (int nd = 0; nd < 4; ++nd) accT[nd] *= scale;
      }

      // P^T pack via v_cvt_pk_bf16_f32: lane (q=l15) holds k=f*16+l4*4+0..3
      char* Pg = (char*)Ps[wq];
#pragma unroll
      for (int f = 0; f < 4; ++f) {
        uintx2 dw;
        dw[0] = cvt_pk_bf16(sa[f][0], sa[f][1]);
        dw[1] = cvt_pk_bf16(sa[f][2], sa[f][3]);
        const int c = f * 2 + (l4 >> 1);
        *(uintx2*)(Pg + l15 * 128 + ((c ^ (l15 & 7)) * 16) + (l4 & 1) * 8) = dw;
      }
      asm volatile("s_waitcnt lgkmcnt(0)" ::: "memory");  // same-wave RAW

      // ---- B-frags of P: lane l15 = q, k = kc*32 + l4*8 ----
      short8 pb[2];
#pragma unroll
      for (int kc = 0; kc < 2; ++kc) {
        const int c = kc * 4 + l4;
        pb[kc] = *(const short8*)(Pg + l15 * 128 + ((c ^ (l15 & 7)) * 16));
      }

      // ---- O^T += V^T P ----
      __builtin_amdgcn_s_setprio(1);
#pragma unroll
      for (int kc = 0; kc < 2; ++kc) {
#pragma unroll
        for (int nd = 0; nd < 4; ++nd) {
          const int row = 16 * nd + l15;
          short8 vb = *(const short8*)(Vs[cur] + row * 64 +
                                       ((kc * 4 + l4) ^ (row & 7)) * 8);
          accT[nd] = __builtin_amdgcn_mfma_f32_16x16x32_bf16(vb, pb[kc], accT[nd], 0, 0, 0);
        }
      }
      __builtin_amdgcn_s_setprio(0);
    }

    asm volatile("s_waitcnt vmcnt(0)" ::: "memory");
    __builtin_amdgcn_s_barrier();
  }

  // ---- epilogue: O = (O^T)^T via per-wave LDS, then coalesced store ----
  char* Pw = (char*)Ps[wq];
  {
    const float inv = 1.0f / l_i;
#pragma unroll
    for (int nd = 0; nd < 4; ++nd) {
      uintx2 dw;
      dw[0] = cvt_pk_bf16(accT[nd][0] * inv, accT[nd][1] * inv);
      dw[1] = cvt_pk_bf16(accT[nd][2] * inv, accT[nd][3] * inv);
      const int c = nd * 2 + (l4 >> 1);
      *(uintx2*)(Pw + l15 * 128 + ((c ^ (l15 & 7)) * 16) + (l4 & 1) * 8) = dw;
    }
  }
  asm volatile("s_waitcnt lgkmcnt(0)" ::: "memory");
#pragma unroll
  for (int ch = 0; ch < 2; ++ch) {
    const int q16 = lane >> 2;
    const int c = ch * 4 + (lane & 3);
    ushort8 o = *(const ushort8*)(Pw + q16 * 128 + ((c ^ (q16 & 7)) * 16));
    const int qg = qminw + q16;
    *(ushort8*)(y + (size_t)(b * TT + qg) * CC + h * DHEAD + c * 8) = o;
  }
}

extern "C" void kernel_launch(void* const* d_in, const int* in_sizes, int n_in,
                              void* d_out, int out_size, void* d_ws, size_t ws_size,
                              hipStream_t stream) {
  const float* x      = (const float*)d_in[0];
  const float* W_attn = (const float*)d_in[1];
  const float* b_attn = (const float*)d_in[2];
  const float* W_proj = (const float*)d_in[3];
  const float* b_proj = (const float*)d_in[4];
  float* out = (float*)d_out;

  const int M = BB * TT;  // 4096
  const float SCL = 0.125f * 1.44269504089f;  // 1/sqrt(64) * log2(e)

  // workspace layout (ushort units)
  unsigned short* qkvb = (unsigned short*)d_ws;          // M * 3C
  unsigned short* xb   = qkvb + (size_t)M * 3 * CC;      // M * C
  unsigned short* Wat  = xb + (size_t)M * CC;            // 3C * C
  unsigned short* Wpt  = Wat + (size_t)3 * CC * CC;      // C * C
  unsigned short* yb   = Wpt + (size_t)CC * CC;          // M * C
  unsigned short* vTb  = yb + (size_t)M * CC;            // B*H*D*T
  float* bscl = (float*)(vTb + (size_t)BB * NHEAD * DHEAD * TT);  // 3C floats

  cvt_bf16_kernel<<<(M * CC) / 1024, 256, 0, stream>>>(x, xb, M * CC);
  {
    dim3 g((3 * CC) / 32, CC / 32);
    transpose_cvt_kernel<<<g, 256, 0, stream>>>(W_attn, Wat, CC, 3 * CC, CC, SCL);
  }
  {
    dim3 g(CC / 32, CC / 32);
    transpose_cvt_kernel<<<g, 256, 0, stream>>>(W_proj, Wpt, CC, CC, 0, 1.0f);
  }
  bias_scale_kernel<<<(3 * CC) / 256, 256, 0, stream>>>(b_attn, bscl, CC, SCL, 3 * CC);

  // GEMM1: qkv = x @ W_attn + b_attn (Q third pre-scaled via Wat/bscl)
  {
    dim3 grid((3 * CC) / 128, M / 128);
    gemm_mfma_kernel<true, 128><<<grid, 256, 0, stream>>>(xb, Wat, bscl, qkvb, M, 3 * CC, CC);
  }

  // V -> vT[b][h][d][T]
  {
    dim3 grid(TT / 64, BB * NHEAD);
    transpose_v_kernel<<<grid, 256, 0, stream>>>(qkvb, vTb);
  }

  // MFMA flash attention (64-row q tiles, 4 waves, 4 blocks/CU, balanced grid)
  flash_mfma_kernel<<<1024, 256, 0, stream>>>(qkvb, vTb, yb);

  // GEMM2: out = y @ W_proj + b_proj (fp32 out, BN=64 -> 512 blocks)
  {
    dim3 grid(CC / 64, M / 128);
    gemm_mfma_kernel<false, 64><<<grid, 256, 0, stream>>>(yb, Wpt, b_proj, out, M, CC, CC);
  }
}

// Round 11
// 129.272 us; speedup vs baseline: 31.2184x; 1.0416x over previous
//
#include <hip/hip_runtime.h>

#define BB 2
#define TT 2048
#define CC 1024
#define NHEAD 16
#define DHEAD 64

typedef __attribute__((ext_vector_type(8))) short short8;     // bf16x8 MFMA frag
typedef __attribute__((ext_vector_type(8))) unsigned short ushort8;
typedef __attribute__((ext_vector_type(4))) float floatx4;
typedef __attribute__((ext_vector_type(2))) unsigned int uintx2;

__device__ inline unsigned short f32_to_bf16_rne(float f) {
  unsigned u = __builtin_bit_cast(unsigned, f);
  unsigned r = (u + 0x7FFFu + ((u >> 16) & 1u)) >> 16;
  return (unsigned short)r;
}
__device__ inline unsigned cvt_pk_bf16(float lo, float hi) {
  unsigned r;
  asm("v_cvt_pk_bf16_f32 %0, %1, %2" : "=v"(r) : "v"(lo), "v"(hi));
  return r;
}
__device__ inline void gload_lds16(const void* g, void* l) {
  __builtin_amdgcn_global_load_lds(
      (const __attribute__((address_space(1))) void*)g,
      (__attribute__((address_space(3))) void*)l, 16, 0, 0);
}

// ---------------------------------------------------------------------------
// Fused prep kernel: x->bf16 cvt | W_attn transpose(+Q scale) | W_proj
// transpose | scaled bias. One launch instead of four.
// Grid: [0,4096) x-cvt, [4096,7168) W_attn tiles, [7168,8192) W_proj tiles,
// [8192,8204) bias.
// ---------------------------------------------------------------------------
__device__ inline void transpose_tile(const float* __restrict__ W,
                                      unsigned short* __restrict__ Wt,
                                      int K, int N, int scale_cut, float scl,
                                      int bx, int by, float (*T)[33]) {
  const int tx = threadIdx.x & 31;
  const int ty = threadIdx.x >> 5;
  const int r0 = by * 32, c0 = bx * 32;
#pragma unroll
  for (int i = 0; i < 4; ++i)
    T[ty + i * 8][tx] = W[(size_t)(r0 + ty + i * 8) * N + c0 + tx];
  __syncthreads();
#pragma unroll
  for (int i = 0; i < 4; ++i) {
    const int nrow = c0 + ty + i * 8;
    const float s = (nrow < scale_cut) ? scl : 1.0f;
    Wt[(size_t)nrow * K + r0 + tx] = f32_to_bf16_rne(T[tx][ty + i * 8] * s);
  }
}

__global__ __launch_bounds__(256) void prep_kernel(
    const float* __restrict__ x, const float* __restrict__ W_attn,
    const float* __restrict__ b_attn, const float* __restrict__ W_proj,
    unsigned short* __restrict__ xb, unsigned short* __restrict__ Wat,
    unsigned short* __restrict__ Wpt, float* __restrict__ bscl, float scl) {
  __shared__ float T[32][33];
  const int id = blockIdx.x;
  if (id < 4096) {
    // x -> bf16 (4096 blocks x 1024 elems)
    const int i = (id * 256 + threadIdx.x) * 4;
    float4 v = *(const float4*)(x + i);
    ushort4 o;
    o.x = f32_to_bf16_rne(v.x);
    o.y = f32_to_bf16_rne(v.y);
    o.z = f32_to_bf16_rne(v.z);
    o.w = f32_to_bf16_rne(v.w);
    *(ushort4*)(xb + i) = o;
  } else if (id < 4096 + 3072) {
    const int t = id - 4096;         // W_attn: N=3C, 96 x 32 tiles
    transpose_tile(W_attn, Wat, CC, 3 * CC, CC, scl, t % 96, t / 96, T);
  } else if (id < 4096 + 3072 + 1024) {
    const int t = id - (4096 + 3072);  // W_proj: 32 x 32 tiles
    transpose_tile(W_proj, Wpt, CC, CC, 0, 1.0f, t % 32, t / 32, T);
  } else {
    const int i = (id - 8192) * 256 + threadIdx.x;
    if (i < 3 * CC) bscl[i] = b_attn[i] * (i < CC ? scl : 1.0f);
  }
}

// ---------------------------------------------------------------------------
// V part of qkv (bf16, [B,T,3C] at col 2C+h*64) -> vT[b][h][d][T]
// ---------------------------------------------------------------------------
__global__ __launch_bounds__(256) void transpose_v_kernel(
    const unsigned short* __restrict__ qkv, unsigned short* __restrict__ vT) {
  __shared__ unsigned short Ts[64][72];
  const int tt0 = blockIdx.x * 64;
  const int bh = blockIdx.y;
  const int h = bh & (NHEAD - 1);
  const int b = bh >> 4;
  const int tid = threadIdx.x;
  const unsigned short* src = qkv + (size_t)(b * TT) * (3 * CC) + 2 * CC + h * DHEAD;
#pragma unroll
  for (int it = 0; it < 2; ++it) {
    const int t = it * 32 + (tid >> 3);
    const int d8 = (tid & 7) * 8;
    ushort8 v = *(const ushort8*)(src + (size_t)(tt0 + t) * (3 * CC) + d8);
#pragma unroll
    for (int j = 0; j < 8; ++j) Ts[t][d8 + j] = v[j];
  }
  __syncthreads();
  unsigned short* dst = vT + ((size_t)((b * NHEAD + h) * DHEAD)) * TT;
#pragma unroll
  for (int it = 0; it < 2; ++it) {
    const int d = it * 32 + (tid >> 3);
    const int t8 = (tid & 7) * 8;
    ushort8 o;
#pragma unroll
    for (int j = 0; j < 8; ++j) o[j] = Ts[t8 + j][d];
    *(ushort8*)(dst + (size_t)d * TT + tt0 + t8) = o;
  }
}

// ---------------------------------------------------------------------------
// bf16 MFMA GEMM: C[M][N] = A[M][K] @ Bt[N][K]^T + bias[N]
// 128xBN tile (BN=128 or 64), BK=32, 256 threads (4 waves, 2x2).
// ---------------------------------------------------------------------------
template <bool BF16_OUT, int BN>
__global__ __launch_bounds__(256) void gemm_mfma_kernel(
    const unsigned short* __restrict__ A, const unsigned short* __restrict__ Bt,
    const float* __restrict__ bias, void* __restrict__ Cout,
    int M, int N, int K) {
  constexpr int NR = BN / 32;  // col frags per wave
  __shared__ unsigned short As[128 * 32];
  __shared__ unsigned short Bs[BN * 32];

  const int tid = threadIdx.x;
  const int wave = tid >> 6;
  const int lane = tid & 63;
  const int row0 = blockIdx.y * 128;
  const int col0 = blockIdx.x * BN;
  const int wr = (wave >> 1) * 64;
  const int wc = (wave & 1) * (BN / 2);

  floatx4 acc[4][NR];
#pragma unroll
  for (int m = 0; m < 4; ++m)
#pragma unroll
    for (int n = 0; n < NR; ++n) acc[m][n] = (floatx4){0.f, 0.f, 0.f, 0.f};

  const int sRow = lane >> 2;
  const int sK = (lane & 3) * 8;

  for (int k0 = 0; k0 < K; k0 += 32) {
#pragma unroll
    for (int c = 0; c < 2; ++c) {
      const int g = c * 4 + wave;
      gload_lds16(A + (size_t)(row0 + g * 16 + sRow) * K + k0 + sK,
                  (char*)As + g * 1024);
    }
    if constexpr (BN == 128) {
#pragma unroll
      for (int c = 0; c < 2; ++c) {
        const int g = c * 4 + wave;
        gload_lds16(Bt + (size_t)(col0 + g * 16 + sRow) * K + k0 + sK,
                    (char*)Bs + g * 1024);
      }
    } else {
      gload_lds16(Bt + (size_t)(col0 + wave * 16 + sRow) * K + k0 + sK,
                  (char*)Bs + wave * 1024);
    }
    __syncthreads();

    short8 af[4], bf[NR];
#pragma unroll
    for (int m = 0; m < 4; ++m)
      af[m] = *(const short8*)(As + (wr + m * 16 + (lane & 15)) * 32 + (lane >> 4) * 8);
#pragma unroll
    for (int n = 0; n < NR; ++n)
      bf[n] = *(const short8*)(Bs + (wc + n * 16 + (lane & 15)) * 32 + (lane >> 4) * 8);
#pragma unroll
    for (int m = 0; m < 4; ++m)
#pragma unroll
      for (int n = 0; n < NR; ++n)
        acc[m][n] = __builtin_amdgcn_mfma_f32_16x16x32_bf16(af[m], bf[n], acc[m][n], 0, 0, 0);
    __syncthreads();
  }

  const int cl = lane & 15;
  const int rg = (lane >> 4) * 4;
#pragma unroll
  for (int m = 0; m < 4; ++m) {
#pragma unroll
    for (int n = 0; n < NR; ++n) {
      const int col = col0 + wc + n * 16 + cl;
      const float bv = bias[col];
#pragma unroll
      for (int r = 0; r < 4; ++r) {
        const int row = row0 + wr + m * 16 + rg + r;
        const float v = acc[m][n][r] + bv;
        if (BF16_OUT)
          ((unsigned short*)Cout)[(size_t)row * N + col] = f32_to_bf16_rne(v);
        else
          ((float*)Cout)[(size_t)row * N + col] = v;
      }
    }
  }
}

// ---------------------------------------------------------------------------
// MFMA flash attention v5: swapped-operand, 4 waves x 16 q-rows, SINGLE-
// buffered K/V (24KB LDS -> 6 blocks/CU capacity; latency hidden by TLP).
// XCD-locality mapping: id&7 = XCD, each XCD owns 4 bh (K/V 2MB fits its L2).
// qt = (grp&1) ? 31-base : base, base = (j&1) ? j>>1 : 31-(j>>1):
//   per-CU duration sum = exactly 66 tiles under BOTH strided and contiguous
//   intra-XCD block->CU assignment.
// Q pre-scaled by 1/8*log2e -> log2-domain softmax; defer-max THR=8; cvt_pk.
// ---------------------------------------------------------------------------
__global__ __launch_bounds__(256) void flash_mfma_kernel(
    const unsigned short* __restrict__ qkv,
    const unsigned short* __restrict__ vT,
    unsigned short* __restrict__ y) {
  __shared__ unsigned short Ks[64 * 64];     // [token][d-chunk swz]  8KB
  __shared__ unsigned short Vs[64 * 64];     // [d][k-chunk swz]      8KB
  __shared__ unsigned short Ps[4][16 * 64];  // per-wave P / O^T      8KB

  // XCD-local, per-CU-balanced mapping (bijective over 1024)
  const int id = blockIdx.x;
  const int xcd = id & 7;
  const int k = id >> 3;        // 0..127
  const int grp = k >> 5;       // 0..3
  const int j = k & 31;
  const int base = (j & 1) ? (j >> 1) : (31 - (j >> 1));
  const int qt = (grp & 1) ? (31 - base) : base;
  const int bh = xcd * 4 + grp;

  const int h = bh & (NHEAD - 1);
  const int b = bh >> 4;
  const int tid = threadIdx.x;
  const int wq = tid >> 6;      // 0..3
  const int lane = tid & 63;
  const int l15 = lane & 15;
  const int l4 = lane >> 4;
  const int srow = lane >> 3;
  const int schunk = lane & 7;

  const int qminw = qt * 64 + wq * 16;

  const size_t baseQ = (size_t)(b * TT) * (3 * CC) + h * DHEAD;
  const size_t baseK = baseQ + CC;
  const size_t vbase = (size_t)((b * NHEAD + h) * DHEAD) * TT;

  // Q B-frags (pre-scaled): lane l15 = q-row, d = kc*32 + l4*8
  short8 aq[2];
  {
    const unsigned short* qp =
        qkv + baseQ + (size_t)(qminw + l15) * (3 * CC) + l4 * 8;
    aq[0] = *(const short8*)(qp);
    aq[1] = *(const short8*)(qp + 32);
  }

  floatx4 accT[4];  // [nd]: O^T[d=nd*16+l4*4+r][q=l15]
  float m_i = -1e30f, l_i = 0.f;
#pragma unroll
  for (int n = 0; n < 4; ++n) accT[n] = (floatx4){0.f, 0.f, 0.f, 0.f};

  const int nt = qt + 1;

  for (int kt = 0; kt < nt; ++kt) {
    if (kt) __builtin_amdgcn_s_barrier();  // all waves done reading prev tile

    // ---- stage K and V^T tiles (single buffer) ----
#pragma unroll
    for (int it = 0; it < 2; ++it) {
      const int blk = it * 4 + wq;      // 8-row block, wave-uniform
      const int grow = blk * 8 + srow;
      gload_lds16(qkv + baseK + (size_t)(kt * 64 + grow) * (3 * CC) +
                      (schunk ^ srow) * 8,
                  (char*)Ks + blk * 1024);
      gload_lds16(vT + vbase + (size_t)grow * TT + kt * 64 + (schunk ^ srow) * 8,
                  (char*)Vs + blk * 1024);
    }
    asm volatile("s_waitcnt vmcnt(0)" ::: "memory");
    __builtin_amdgcn_s_barrier();

    // ---- S^T = K Q^T : sa[f] rows k=f*16+l4*4+r, col q=l15 ----
    floatx4 sa[4];
#pragma unroll
    for (int f = 0; f < 4; ++f) sa[f] = (floatx4){0.f, 0.f, 0.f, 0.f};

    __builtin_amdgcn_s_setprio(1);
#pragma unroll
    for (int kc = 0; kc < 2; ++kc) {
#pragma unroll
      for (int f = 0; f < 4; ++f) {
        const int row = 16 * f + l15;
        short8 bk = *(const short8*)(Ks + row * 64 +
                                     ((kc * 4 + l4) ^ (row & 7)) * 8);
        sa[f] = __builtin_amdgcn_mfma_f32_16x16x32_bf16(bk, aq[kc], sa[f], 0, 0, 0);
      }
    }
    __builtin_amdgcn_s_setprio(0);

    // ---- in-register online softmax (log2 domain, Q pre-scaled) ----
    const int qg = qminw + l15;
    if (kt * 64 + 63 > qminw) {  // only the diagonal tile needs masking
#pragma unroll
      for (int f = 0; f < 4; ++f)
#pragma unroll
        for (int r = 0; r < 4; ++r) {
          const int kg = kt * 64 + f * 16 + l4 * 4 + r;
          if (kg > qg) sa[f][r] = -1e30f;
        }
    }
    float rm = -1e30f;
#pragma unroll
    for (int f = 0; f < 4; ++f)
      rm = fmaxf(rm, fmaxf(fmaxf(sa[f][0], sa[f][1]), fmaxf(sa[f][2], sa[f][3])));
    rm = fmaxf(rm, __shfl_xor(rm, 16, 64));
    rm = fmaxf(rm, __shfl_xor(rm, 32, 64));

    float rs = 0.f;
    if (__all(rm <= m_i + 8.0f)) {
      // deferred: keep old max, skip O/l rescale; P bounded by 2^8
#pragma unroll
      for (int f = 0; f < 4; ++f)
#pragma unroll
        for (int r = 0; r < 4; ++r) {
          const float p = __builtin_amdgcn_exp2f(sa[f][r] - m_i);
          sa[f][r] = p;
          rs += p;
        }
      rs += __shfl_xor(rs, 16, 64);
      rs += __shfl_xor(rs, 32, 64);
      l_i += rs;
    } else {
      const float mn = fmaxf(m_i, rm);
      const float scale = __builtin_amdgcn_exp2f(m_i - mn);
#pragma unroll
      for (int f = 0; f < 4; ++f)
#pragma unroll
        for (int r = 0; r < 4; ++r) {
          const float p = __builtin_amdgcn_exp2f(sa[f][r] - mn);
          sa[f][r] = p;
          rs += p;
        }
      rs += __shfl_xor(rs, 16, 64);
      rs += __shfl_xor(rs, 32, 64);
      l_i = l_i * scale + rs;
      m_i = mn;
#pragma unroll
      for (int nd = 0; nd < 4; ++nd) accT[nd] *= scale;
    }

    // P^T pack via v_cvt_pk_bf16_f32: lane (q=l15) holds k=f*16+l4*4+0..3
    char* Pg = (char*)Ps[wq];
#pragma unroll
    for (int f = 0; f < 4; ++f) {
      uintx2 dw;
      dw[0] = cvt_pk_bf16(sa[f][0], sa[f][1]);
      dw[1] = cvt_pk_bf16(sa[f][2], sa[f][3]);
      const int c = f * 2 + (l4 >> 1);
      *(uintx2*)(Pg + l15 * 128 + ((c ^ (l15 & 7)) * 16) + (l4 & 1) * 8) = dw;
    }
    asm volatile("s_waitcnt lgkmcnt(0)" ::: "memory");  // same-wave RAW

    // ---- B-frags of P: lane l15 = q, k = kc*32 + l4*8 ----
    short8 pb[2];
#pragma unroll
    for (int kc = 0; kc < 2; ++kc) {
      const int c = kc * 4 + l4;
      pb[kc] = *(const short8*)(Pg + l15 * 128 + ((c ^ (l15 & 7)) * 16));
    }

    // ---- O^T += V^T P ----
    __builtin_amdgcn_s_setprio(1);
#pragma unroll
    for (int kc = 0; kc < 2; ++kc) {
#pragma unroll
      for (int nd = 0; nd < 4; ++nd) {
        const int row = 16 * nd + l15;
        short8 vb = *(const short8*)(Vs + row * 64 +
                                     ((kc * 4 + l4) ^ (row & 7)) * 8);
        accT[nd] = __builtin_amdgcn_mfma_f32_16x16x32_bf16(vb, pb[kc], accT[nd], 0, 0, 0);
      }
    }
    __builtin_amdgcn_s_setprio(0);
  }

  // ---- epilogue: O = (O^T)^T via per-wave LDS, then coalesced store ----
  char* Pw = (char*)Ps[wq];
  {
    const float inv = 1.0f / l_i;
#pragma unroll
    for (int nd = 0; nd < 4; ++nd) {
      uintx2 dw;
      dw[0] = cvt_pk_bf16(accT[nd][0] * inv, accT[nd][1] * inv);
      dw[1] = cvt_pk_bf16(accT[nd][2] * inv, accT[nd][3] * inv);
      const int c = nd * 2 + (l4 >> 1);
      *(uintx2*)(Pw + l15 * 128 + ((c ^ (l15 & 7)) * 16) + (l4 & 1) * 8) = dw;
    }
  }
  asm volatile("s_waitcnt lgkmcnt(0)" ::: "memory");
#pragma unroll
  for (int ch = 0; ch < 2; ++ch) {
    const int q16 = lane >> 2;
    const int c = ch * 4 + (lane & 3);
    ushort8 o = *(const ushort8*)(Pw + q16 * 128 + ((c ^ (q16 & 7)) * 16));
    const int qg = qt * 64 + wq * 16 + q16;
    *(ushort8*)(y + (size_t)(b * TT + qg) * CC + h * DHEAD + c * 8) = o;
  }
}

extern "C" void kernel_launch(void* const* d_in, const int* in_sizes, int n_in,
                              void* d_out, int out_size, void* d_ws, size_t ws_size,
                              hipStream_t stream) {
  const float* x      = (const float*)d_in[0];
  const float* W_attn = (const float*)d_in[1];
  const float* b_attn = (const float*)d_in[2];
  const float* W_proj = (const float*)d_in[3];
  const float* b_proj = (const float*)d_in[4];
  float* out = (float*)d_out;

  const int M = BB * TT;  // 4096
  const float SCL = 0.125f * 1.44269504089f;  // 1/sqrt(64) * log2(e)

  // workspace layout (ushort units)
  unsigned short* qkvb = (unsigned short*)d_ws;          // M * 3C
  unsigned short* xb   = qkvb + (size_t)M * 3 * CC;      // M * C
  unsigned short* Wat  = xb + (size_t)M * CC;            // 3C * C
  unsigned short* Wpt  = Wat + (size_t)3 * CC * CC;      // C * C
  unsigned short* yb   = Wpt + (size_t)CC * CC;          // M * C
  unsigned short* vTb  = yb + (size_t)M * CC;            // B*H*D*T
  float* bscl = (float*)(vTb + (size_t)BB * NHEAD * DHEAD * TT);  // 3C floats

  // fused prep: x cvt + both weight transposes + scaled bias (one launch)
  prep_kernel<<<8204, 256, 0, stream>>>(x, W_attn, b_attn, W_proj,
                                        xb, Wat, Wpt, bscl, SCL);

  // GEMM1: qkv = x @ W_attn + b_attn (Q third pre-scaled via Wat/bscl)
  {
    dim3 grid((3 * CC) / 128, M / 128);
    gemm_mfma_kernel<true, 128><<<grid, 256, 0, stream>>>(xb, Wat, bscl, qkvb, M, 3 * CC, CC);
  }

  // V -> vT[b][h][d][T]
  {
    dim3 grid(TT / 64, BB * NHEAD);
    transpose_v_kernel<<<grid, 256, 0, stream>>>(qkvb, vTb);
  }

  // MFMA flash attention (64-row q tiles, 4 waves, 24KB LDS, XCD-local grid)
  flash_mfma_kernel<<<1024, 256, 0, stream>>>(qkvb, vTb, yb);

  // GEMM2: out = y @ W_proj + b_proj (fp32 out, BN=64 -> 512 blocks)
  {
    dim3 grid(CC / 64, M / 128);
    gemm_mfma_kernel<false, 64><<<grid, 256, 0, stream>>>(yb, Wpt, b_proj, out, M, CC, CC);
  }
}

// Round 12
// 123.355 us; speedup vs baseline: 32.7159x; 1.0480x over previous
//
#include <hip/hip_runtime.h>

#define BB 2
#define TT 2048
#define CC 1024
#define NHEAD 16
#define DHEAD 64

typedef __attribute__((ext_vector_type(8))) short short8;     // bf16x8 MFMA frag
typedef __attribute__((ext_vector_type(8))) unsigned short ushort8;
typedef __attribute__((ext_vector_type(4))) float floatx4;
typedef __attribute__((ext_vector_type(2))) unsigned int uintx2;

__device__ inline unsigned short f32_to_bf16_rne(float f) {
  unsigned u = __builtin_bit_cast(unsigned, f);
  unsigned r = (u + 0x7FFFu + ((u >> 16) & 1u)) >> 16;
  return (unsigned short)r;
}
__device__ inline unsigned cvt_pk_bf16(float lo, float hi) {
  unsigned r;
  asm("v_cvt_pk_bf16_f32 %0, %1, %2" : "=v"(r) : "v"(lo), "v"(hi));
  return r;
}
__device__ inline void gload_lds16(const void* g, void* l) {
  __builtin_amdgcn_global_load_lds(
      (const __attribute__((address_space(1))) void*)g,
      (__attribute__((address_space(3))) void*)l, 16, 0, 0);
}

// ---------------------------------------------------------------------------
// Fused prep kernel: x->bf16 cvt | W_attn transpose(+Q scale) | W_proj
// transpose | scaled bias.
// ---------------------------------------------------------------------------
__device__ inline void transpose_tile(const float* __restrict__ W,
                                      unsigned short* __restrict__ Wt,
                                      int K, int N, int scale_cut, float scl,
                                      int bx, int by, float (*T)[33]) {
  const int tx = threadIdx.x & 31;
  const int ty = threadIdx.x >> 5;
  const int r0 = by * 32, c0 = bx * 32;
#pragma unroll
  for (int i = 0; i < 4; ++i)
    T[ty + i * 8][tx] = W[(size_t)(r0 + ty + i * 8) * N + c0 + tx];
  __syncthreads();
#pragma unroll
  for (int i = 0; i < 4; ++i) {
    const int nrow = c0 + ty + i * 8;
    const float s = (nrow < scale_cut) ? scl : 1.0f;
    Wt[(size_t)nrow * K + r0 + tx] = f32_to_bf16_rne(T[tx][ty + i * 8] * s);
  }
}

__global__ __launch_bounds__(256) void prep_kernel(
    const float* __restrict__ x, const float* __restrict__ W_attn,
    const float* __restrict__ b_attn, const float* __restrict__ W_proj,
    unsigned short* __restrict__ xb, unsigned short* __restrict__ Wat,
    unsigned short* __restrict__ Wpt, float* __restrict__ bscl, float scl) {
  __shared__ float T[32][33];
  const int id = blockIdx.x;
  if (id < 4096) {
    const int i = (id * 256 + threadIdx.x) * 4;
    float4 v = *(const float4*)(x + i);
    ushort4 o;
    o.x = f32_to_bf16_rne(v.x);
    o.y = f32_to_bf16_rne(v.y);
    o.z = f32_to_bf16_rne(v.z);
    o.w = f32_to_bf16_rne(v.w);
    *(ushort4*)(xb + i) = o;
  } else if (id < 4096 + 3072) {
    const int t = id - 4096;
    transpose_tile(W_attn, Wat, CC, 3 * CC, CC, scl, t % 96, t / 96, T);
  } else if (id < 4096 + 3072 + 1024) {
    const int t = id - (4096 + 3072);
    transpose_tile(W_proj, Wpt, CC, CC, 0, 1.0f, t % 32, t / 32, T);
  } else {
    const int i = (id - 8192) * 256 + threadIdx.x;
    if (i < 3 * CC) bscl[i] = b_attn[i] * (i < CC ? scl : 1.0f);
  }
}

// ---------------------------------------------------------------------------
// V part of qkv -> vT[b][h][d][T]
// ---------------------------------------------------------------------------
__global__ __launch_bounds__(256) void transpose_v_kernel(
    const unsigned short* __restrict__ qkv, unsigned short* __restrict__ vT) {
  __shared__ unsigned short Ts[64][72];
  const int tt0 = blockIdx.x * 64;
  const int bh = blockIdx.y;
  const int h = bh & (NHEAD - 1);
  const int b = bh >> 4;
  const int tid = threadIdx.x;
  const unsigned short* src = qkv + (size_t)(b * TT) * (3 * CC) + 2 * CC + h * DHEAD;
#pragma unroll
  for (int it = 0; it < 2; ++it) {
    const int t = it * 32 + (tid >> 3);
    const int d8 = (tid & 7) * 8;
    ushort8 v = *(const ushort8*)(src + (size_t)(tt0 + t) * (3 * CC) + d8);
#pragma unroll
    for (int j = 0; j < 8; ++j) Ts[t][d8 + j] = v[j];
  }
  __syncthreads();
  unsigned short* dst = vT + ((size_t)((b * NHEAD + h) * DHEAD)) * TT;
#pragma unroll
  for (int it = 0; it < 2; ++it) {
    const int d = it * 32 + (tid >> 3);
    const int t8 = (tid & 7) * 8;
    ushort8 o;
#pragma unroll
    for (int j = 0; j < 8; ++j) o[j] = Ts[t8 + j][d];
    *(ushort8*)(dst + (size_t)d * TT + tt0 + t8) = o;
  }
}

// ---------------------------------------------------------------------------
// bf16 MFMA GEMM: C[M][N] = A[M][K] @ Bt[N][K]^T + bias[N]
// ---------------------------------------------------------------------------
template <bool BF16_OUT, int BN>
__global__ __launch_bounds__(256) void gemm_mfma_kernel(
    const unsigned short* __restrict__ A, const unsigned short* __restrict__ Bt,
    const float* __restrict__ bias, void* __restrict__ Cout,
    int M, int N, int K) {
  constexpr int NR = BN / 32;
  __shared__ unsigned short As[128 * 32];
  __shared__ unsigned short Bs[BN * 32];

  const int tid = threadIdx.x;
  const int wave = tid >> 6;
  const int lane = tid & 63;
  const int row0 = blockIdx.y * 128;
  const int col0 = blockIdx.x * BN;
  const int wr = (wave >> 1) * 64;
  const int wc = (wave & 1) * (BN / 2);

  floatx4 acc[4][NR];
#pragma unroll
  for (int m = 0; m < 4; ++m)
#pragma unroll
    for (int n = 0; n < NR; ++n) acc[m][n] = (floatx4){0.f, 0.f, 0.f, 0.f};

  const int sRow = lane >> 2;
  const int sK = (lane & 3) * 8;

  for (int k0 = 0; k0 < K; k0 += 32) {
#pragma unroll
    for (int c = 0; c < 2; ++c) {
      const int g = c * 4 + wave;
      gload_lds16(A + (size_t)(row0 + g * 16 + sRow) * K + k0 + sK,
                  (char*)As + g * 1024);
    }
    if constexpr (BN == 128) {
#pragma unroll
      for (int c = 0; c < 2; ++c) {
        const int g = c * 4 + wave;
        gload_lds16(Bt + (size_t)(col0 + g * 16 + sRow) * K + k0 + sK,
                    (char*)Bs + g * 1024);
      }
    } else {
      gload_lds16(Bt + (size_t)(col0 + wave * 16 + sRow) * K + k0 + sK,
                  (char*)Bs + wave * 1024);
    }
    __syncthreads();

    short8 af[4], bf[NR];
#pragma unroll
    for (int m = 0; m < 4; ++m)
      af[m] = *(const short8*)(As + (wr + m * 16 + (lane & 15)) * 32 + (lane >> 4) * 8);
#pragma unroll
    for (int n = 0; n < NR; ++n)
      bf[n] = *(const short8*)(Bs + (wc + n * 16 + (lane & 15)) * 32 + (lane >> 4) * 8);
#pragma unroll
    for (int m = 0; m < 4; ++m)
#pragma unroll
      for (int n = 0; n < NR; ++n)
        acc[m][n] = __builtin_amdgcn_mfma_f32_16x16x32_bf16(af[m], bf[n], acc[m][n], 0, 0, 0);
    __syncthreads();
  }

  const int cl = lane & 15;
  const int rg = (lane >> 4) * 4;
#pragma unroll
  for (int m = 0; m < 4; ++m) {
#pragma unroll
    for (int n = 0; n < NR; ++n) {
      const int col = col0 + wc + n * 16 + cl;
      const float bv = bias[col];
#pragma unroll
      for (int r = 0; r < 4; ++r) {
        const int row = row0 + wr + m * 16 + rg + r;
        const float v = acc[m][n][r] + bv;
        if (BF16_OUT)
          ((unsigned short*)Cout)[(size_t)row * N + col] = f32_to_bf16_rne(v);
        else
          ((float*)Cout)[(size_t)row * N + col] = v;
      }
    }
  }
}

// ---------------------------------------------------------------------------
// MFMA flash attention v6: paired-qt uniform blocks.
// Each block processes qtA = 31-p then qtB = p (33 KV-tiles total, identical
// for every block -> zero tail; 2 blocks/CU resident for the whole kernel).
// 4 waves x 16 q-rows; double-buffered K/V (40KB LDS); XCD-local bh mapping;
// swapped-operand log2-softmax with defer-max; cvt_pk bf16 pack.
// ---------------------------------------------------------------------------
__global__ __launch_bounds__(256) void flash_mfma_kernel(
    const unsigned short* __restrict__ qkv,
    const unsigned short* __restrict__ vT,
    unsigned short* __restrict__ y) {
  __shared__ unsigned short Ks[2][64 * 64];   // 16KB
  __shared__ unsigned short Vs[2][64 * 64];   // 16KB
  __shared__ unsigned short Ps[4][16 * 64];   // 8KB

  // id: [xcd:3][grp:2][pair:4]  (512 blocks)
  const int id = blockIdx.x;
  const int xcd = id & 7;
  const int grp = (id >> 3) & 3;
  const int p = id >> 5;               // 0..15
  const int bh = xcd * 4 + grp;        // XCD-local heads (K/V 2MB in 4MB L2)
  const int qtA = 31 - p, qtB = p;
  const int ntA = qtA + 1, ntB = qtB + 1;  // total 33 for every block

  const int h = bh & (NHEAD - 1);
  const int b = bh >> 4;
  const int tid = threadIdx.x;
  const int wq = tid >> 6;      // 0..3
  const int lane = tid & 63;
  const int l15 = lane & 15;
  const int l4 = lane >> 4;
  const int srow = lane >> 3;
  const int schunk = lane & 7;

  const size_t baseQ = (size_t)(b * TT) * (3 * CC) + h * DHEAD;
  const size_t baseK = baseQ + CC;
  const size_t vbase = (size_t)((b * NHEAD + h) * DHEAD) * TT;

  // Q B-frags for both phases (pre-scaled): lane l15 = q-row
  short8 aqA[2], aqB[2];
  {
    const unsigned short* qp =
        qkv + baseQ + (size_t)(qtA * 64 + wq * 16 + l15) * (3 * CC) + l4 * 8;
    aqA[0] = *(const short8*)(qp);
    aqA[1] = *(const short8*)(qp + 32);
    const unsigned short* qp2 =
        qkv + baseQ + (size_t)(qtB * 64 + wq * 16 + l15) * (3 * CC) + l4 * 8;
    aqB[0] = *(const short8*)(qp2);
    aqB[1] = *(const short8*)(qp2 + 32);
  }

  floatx4 accT[4];
  float m_i = -1e30f, l_i = 0.f;
#pragma unroll
  for (int n = 0; n < 4; ++n) accT[n] = (floatx4){0.f, 0.f, 0.f, 0.f};

  auto stage = [&](int KT, int BUF) {
#pragma unroll
    for (int it = 0; it < 2; ++it) {
      const int blk = it * 4 + wq;
      const int grow = blk * 8 + srow;
      gload_lds16(qkv + baseK + (size_t)(KT * 64 + grow) * (3 * CC) +
                      (schunk ^ srow) * 8,
                  (char*)Ks[BUF] + blk * 1024);
      gload_lds16(vT + vbase + (size_t)grow * TT + KT * 64 + (schunk ^ srow) * 8,
                  (char*)Vs[BUF] + blk * 1024);
    }
  };

  auto epilogue = [&](int qt) {
    char* Pw = (char*)Ps[wq];
    const float inv = 1.0f / l_i;
#pragma unroll
    for (int nd = 0; nd < 4; ++nd) {
      uintx2 dw;
      dw[0] = cvt_pk_bf16(accT[nd][0] * inv, accT[nd][1] * inv);
      dw[1] = cvt_pk_bf16(accT[nd][2] * inv, accT[nd][3] * inv);
      const int c = nd * 2 + (l4 >> 1);
      *(uintx2*)(Pw + l15 * 128 + ((c ^ (l15 & 7)) * 16) + (l4 & 1) * 8) = dw;
    }
    asm volatile("s_waitcnt lgkmcnt(0)" ::: "memory");
#pragma unroll
    for (int ch = 0; ch < 2; ++ch) {
      const int q16 = lane >> 2;
      const int c = ch * 4 + (lane & 3);
      ushort8 o = *(const ushort8*)(Pw + q16 * 128 + ((c ^ (q16 & 7)) * 16));
      const int qg = qt * 64 + wq * 16 + q16;
      *(ushort8*)(y + (size_t)(b * TT + qg) * CC + h * DHEAD + c * 8) = o;
    }
  };

  const int nt_total = ntA + ntB;  // 33

  stage(0, 0);
  asm volatile("s_waitcnt vmcnt(0)" ::: "memory");
  __builtin_amdgcn_s_barrier();

  for (int t = 0; t < nt_total; ++t) {
    const bool phB = (t >= ntA);
    const int kt = phB ? t - ntA : t;
    const int qminw = (phB ? qtB : qtA) * 64 + wq * 16;
    const int cur = t & 1;
    if (t + 1 < nt_total)
      stage((t + 1 >= ntA) ? t + 1 - ntA : t + 1, cur ^ 1);  // overlapped

    // ---- S^T = K Q^T ----
    floatx4 sa[4];
#pragma unroll
    for (int f = 0; f < 4; ++f) sa[f] = (floatx4){0.f, 0.f, 0.f, 0.f};

    __builtin_amdgcn_s_setprio(1);
#pragma unroll
    for (int kc = 0; kc < 2; ++kc) {
      const short8 aq = phB ? aqB[kc] : aqA[kc];
#pragma unroll
      for (int f = 0; f < 4; ++f) {
        const int row = 16 * f + l15;
        short8 bk = *(const short8*)(Ks[cur] + row * 64 +
                                     ((kc * 4 + l4) ^ (row & 7)) * 8);
        sa[f] = __builtin_amdgcn_mfma_f32_16x16x32_bf16(bk, aq, sa[f], 0, 0, 0);
      }
    }
    __builtin_amdgcn_s_setprio(0);

    // ---- in-register online softmax (log2 domain) ----
    const int qg = qminw + l15;
    if (kt * 64 + 63 > qminw) {  // diagonal tile only
#pragma unroll
      for (int f = 0; f < 4; ++f)
#pragma unroll
        for (int r = 0; r < 4; ++r) {
          const int kg = kt * 64 + f * 16 + l4 * 4 + r;
          if (kg > qg) sa[f][r] = -1e30f;
        }
    }
    float rm = -1e30f;
#pragma unroll
    for (int f = 0; f < 4; ++f)
      rm = fmaxf(rm, fmaxf(fmaxf(sa[f][0], sa[f][1]), fmaxf(sa[f][2], sa[f][3])));
    rm = fmaxf(rm, __shfl_xor(rm, 16, 64));
    rm = fmaxf(rm, __shfl_xor(rm, 32, 64));

    float rs = 0.f;
    if (__all(rm <= m_i + 8.0f)) {
#pragma unroll
      for (int f = 0; f < 4; ++f)
#pragma unroll
        for (int r = 0; r < 4; ++r) {
          const float pv = __builtin_amdgcn_exp2f(sa[f][r] - m_i);
          sa[f][r] = pv;
          rs += pv;
        }
      rs += __shfl_xor(rs, 16, 64);
      rs += __shfl_xor(rs, 32, 64);
      l_i += rs;
    } else {
      const float mn = fmaxf(m_i, rm);
      const float scale = __builtin_amdgcn_exp2f(m_i - mn);
#pragma unroll
      for (int f = 0; f < 4; ++f)
#pragma unroll
        for (int r = 0; r < 4; ++r) {
          const float pv = __builtin_amdgcn_exp2f(sa[f][r] - mn);
          sa[f][r] = pv;
          rs += pv;
        }
      rs += __shfl_xor(rs, 16, 64);
      rs += __shfl_xor(rs, 32, 64);
      l_i = l_i * scale + rs;
      m_i = mn;
#pragma unroll
      for (int nd = 0; nd < 4; ++nd) accT[nd] *= scale;
    }

    // ---- P^T pack to LDS (cvt_pk) ----
    char* Pg = (char*)Ps[wq];
#pragma unroll
    for (int f = 0; f < 4; ++f) {
      uintx2 dw;
      dw[0] = cvt_pk_bf16(sa[f][0], sa[f][1]);
      dw[1] = cvt_pk_bf16(sa[f][2], sa[f][3]);
      const int c = f * 2 + (l4 >> 1);
      *(uintx2*)(Pg + l15 * 128 + ((c ^ (l15 & 7)) * 16) + (l4 & 1) * 8) = dw;
    }
    asm volatile("s_waitcnt lgkmcnt(0)" ::: "memory");

    short8 pb[2];
#pragma unroll
    for (int kc = 0; kc < 2; ++kc) {
      const int c = kc * 4 + l4;
      pb[kc] = *(const short8*)(Pg + l15 * 128 + ((c ^ (l15 & 7)) * 16));
    }

    // ---- O^T += V^T P ----
    __builtin_amdgcn_s_setprio(1);
#pragma unroll
    for (int kc = 0; kc < 2; ++kc) {
#pragma unroll
      for (int nd = 0; nd < 4; ++nd) {
        const int row = 16 * nd + l15;
        short8 vb = *(const short8*)(Vs[cur] + row * 64 +
                                     ((kc * 4 + l4) ^ (row & 7)) * 8);
        accT[nd] = __builtin_amdgcn_mfma_f32_16x16x32_bf16(vb, pb[kc], accT[nd], 0, 0, 0);
      }
    }
    __builtin_amdgcn_s_setprio(0);

    // staged tile t+1 landed; all waves done with buf[cur]
    asm volatile("s_waitcnt vmcnt(0)" ::: "memory");
    __builtin_amdgcn_s_barrier();

    if (t == ntA - 1) {  // phase A done: write its output, reset state
      epilogue(qtA);
      m_i = -1e30f;
      l_i = 0.f;
#pragma unroll
      for (int n = 0; n < 4; ++n) accT[n] = (floatx4){0.f, 0.f, 0.f, 0.f};
    }
  }

  epilogue(qtB);
}

extern "C" void kernel_launch(void* const* d_in, const int* in_sizes, int n_in,
                              void* d_out, int out_size, void* d_ws, size_t ws_size,
                              hipStream_t stream) {
  const float* x      = (const float*)d_in[0];
  const float* W_attn = (const float*)d_in[1];
  const float* b_attn = (const float*)d_in[2];
  const float* W_proj = (const float*)d_in[3];
  const float* b_proj = (const float*)d_in[4];
  float* out = (float*)d_out;

  const int M = BB * TT;  // 4096
  const float SCL = 0.125f * 1.44269504089f;  // 1/sqrt(64) * log2(e)

  // workspace layout (ushort units)
  unsigned short* qkvb = (unsigned short*)d_ws;          // M * 3C
  unsigned short* xb   = qkvb + (size_t)M * 3 * CC;      // M * C
  unsigned short* Wat  = xb + (size_t)M * CC;            // 3C * C
  unsigned short* Wpt  = Wat + (size_t)3 * CC * CC;      // C * C
  unsigned short* yb   = Wpt + (size_t)CC * CC;          // M * C
  unsigned short* vTb  = yb + (size_t)M * CC;            // B*H*D*T
  float* bscl = (float*)(vTb + (size_t)BB * NHEAD * DHEAD * TT);  // 3C floats

  prep_kernel<<<8204, 256, 0, stream>>>(x, W_attn, b_attn, W_proj,
                                        xb, Wat, Wpt, bscl, SCL);

  // GEMM1: qkv = x @ W_attn + b_attn (Q third pre-scaled via Wat/bscl)
  {
    dim3 grid((3 * CC) / 128, M / 128);
    gemm_mfma_kernel<true, 128><<<grid, 256, 0, stream>>>(xb, Wat, bscl, qkvb, M, 3 * CC, CC);
  }

  // V -> vT[b][h][d][T]
  {
    dim3 grid(TT / 64, BB * NHEAD);
    transpose_v_kernel<<<grid, 256, 0, stream>>>(qkvb, vTb);
  }

  // MFMA flash attention (paired-qt uniform blocks, dbuf, XCD-local)
  flash_mfma_kernel<<<512, 256, 0, stream>>>(qkvb, vTb, yb);

  // GEMM2: out = y @ W_proj + b_proj (fp32 out, BN=64 -> 512 blocks)
  {
    dim3 grid(CC / 64, M / 128);
    gemm_mfma_kernel<false, 64><<<grid, 256, 0, stream>>>(yb, Wpt, b_proj, out, M, CC, CC);
  }
}

// Round 13
// 121.635 us; speedup vs baseline: 33.1785x; 1.0141x over previous
//
#include <hip/hip_runtime.h>

#define BB 2
#define TT 2048
#define CC 1024
#define NHEAD 16
#define DHEAD 64

typedef __attribute__((ext_vector_type(8))) short short8;     // bf16x8 MFMA frag
typedef __attribute__((ext_vector_type(8))) unsigned short ushort8;
typedef __attribute__((ext_vector_type(4))) float floatx4;
typedef __attribute__((ext_vector_type(2))) unsigned int uintx2;

__device__ inline unsigned short f32_to_bf16_rne(float f) {
  unsigned u = __builtin_bit_cast(unsigned, f);
  unsigned r = (u + 0x7FFFu + ((u >> 16) & 1u)) >> 16;
  return (unsigned short)r;
}
__device__ inline unsigned cvt_pk_bf16(float lo, float hi) {
  unsigned r;
  asm("v_cvt_pk_bf16_f32 %0, %1, %2" : "=v"(r) : "v"(lo), "v"(hi));
  return r;
}
__device__ inline void gload_lds16(const void* g, void* l) {
  __builtin_amdgcn_global_load_lds(
      (const __attribute__((address_space(1))) void*)g,
      (__attribute__((address_space(3))) void*)l, 16, 0, 0);
}

// ---------------------------------------------------------------------------
// Fused prep kernel: x->bf16 cvt | W_attn transpose(+Q scale) | W_proj
// transpose | scaled bias.
// ---------------------------------------------------------------------------
__device__ inline void transpose_tile(const float* __restrict__ W,
                                      unsigned short* __restrict__ Wt,
                                      int K, int N, int scale_cut, float scl,
                                      int bx, int by, float (*T)[33]) {
  const int tx = threadIdx.x & 31;
  const int ty = threadIdx.x >> 5;
  const int r0 = by * 32, c0 = bx * 32;
#pragma unroll
  for (int i = 0; i < 4; ++i)
    T[ty + i * 8][tx] = W[(size_t)(r0 + ty + i * 8) * N + c0 + tx];
  __syncthreads();
#pragma unroll
  for (int i = 0; i < 4; ++i) {
    const int nrow = c0 + ty + i * 8;
    const float s = (nrow < scale_cut) ? scl : 1.0f;
    Wt[(size_t)nrow * K + r0 + tx] = f32_to_bf16_rne(T[tx][ty + i * 8] * s);
  }
}

__global__ __launch_bounds__(256) void prep_kernel(
    const float* __restrict__ x, const float* __restrict__ W_attn,
    const float* __restrict__ b_attn, const float* __restrict__ W_proj,
    unsigned short* __restrict__ xb, unsigned short* __restrict__ Wat,
    unsigned short* __restrict__ Wpt, float* __restrict__ bscl, float scl) {
  __shared__ float T[32][33];
  const int id = blockIdx.x;
  if (id < 4096) {
    const int i = (id * 256 + threadIdx.x) * 4;
    float4 v = *(const float4*)(x + i);
    ushort4 o;
    o.x = f32_to_bf16_rne(v.x);
    o.y = f32_to_bf16_rne(v.y);
    o.z = f32_to_bf16_rne(v.z);
    o.w = f32_to_bf16_rne(v.w);
    *(ushort4*)(xb + i) = o;
  } else if (id < 4096 + 3072) {
    const int t = id - 4096;
    transpose_tile(W_attn, Wat, CC, 3 * CC, CC, scl, t % 96, t / 96, T);
  } else if (id < 4096 + 3072 + 1024) {
    const int t = id - (4096 + 3072);
    transpose_tile(W_proj, Wpt, CC, CC, 0, 1.0f, t % 32, t / 32, T);
  } else {
    const int i = (id - 8192) * 256 + threadIdx.x;
    if (i < 3 * CC) bscl[i] = b_attn[i] * (i < CC ? scl : 1.0f);
  }
}

// ---------------------------------------------------------------------------
// bf16 MFMA GEMM: C[M][N] = A[M][K] @ Bt[N][K]^T + bias[N]
// 128xBN tile, BK=64 (kc-major LDS sub-tiles, half the barriers of BK=32),
// 256 threads (4 waves, 2x2). VFOLD (GEMM1 only): blocks with col0 >= 2C
// write the V third transposed into vTp[b][h][d][T] via an LDS transpose
// (token-swizzled for bank-conflict-free access) instead of Cout.
// ---------------------------------------------------------------------------
template <bool BF16_OUT, int BN, bool VFOLD>
__global__ __launch_bounds__(256) void gemm_mfma_kernel(
    const unsigned short* __restrict__ A, const unsigned short* __restrict__ Bt,
    const float* __restrict__ bias, void* __restrict__ Cout,
    unsigned short* __restrict__ vTp, int M, int N, int K) {
  constexpr int NR = BN / 32;
  // contiguous so the VFOLD epilogue can reuse As+Bs as one 128x128 tile
  __shared__ unsigned short SM[128 * 64 + BN * 64];
  unsigned short* As = SM;               // 2 sub-tiles of 128x32 (kc-major)
  unsigned short* Bs = SM + 128 * 64;    // 2 sub-tiles of BNx32

  const int tid = threadIdx.x;
  const int wave = tid >> 6;
  const int lane = tid & 63;
  const int row0 = blockIdx.y * 128;
  const int col0 = blockIdx.x * BN;
  const int wr = (wave >> 1) * 64;
  const int wc = (wave & 1) * (BN / 2);

  floatx4 acc[4][NR];
#pragma unroll
  for (int m = 0; m < 4; ++m)
#pragma unroll
    for (int n = 0; n < NR; ++n) acc[m][n] = (floatx4){0.f, 0.f, 0.f, 0.f};

  const int sRow = lane >> 2;
  const int sK = (lane & 3) * 8;

  for (int k0 = 0; k0 < K; k0 += 64) {
#pragma unroll
    for (int kc = 0; kc < 2; ++kc) {
#pragma unroll
      for (int c = 0; c < 2; ++c) {
        const int g = c * 4 + wave;
        gload_lds16(A + (size_t)(row0 + g * 16 + sRow) * K + k0 + kc * 32 + sK,
                    (char*)As + kc * 8192 + g * 1024);
      }
      if constexpr (BN == 128) {
#pragma unroll
        for (int c = 0; c < 2; ++c) {
          const int g = c * 4 + wave;
          gload_lds16(Bt + (size_t)(col0 + g * 16 + sRow) * K + k0 + kc * 32 + sK,
                      (char*)Bs + kc * 8192 + g * 1024);
        }
      } else {
        gload_lds16(Bt + (size_t)(col0 + wave * 16 + sRow) * K + k0 + kc * 32 + sK,
                    (char*)Bs + kc * 4096 + wave * 1024);
      }
    }
    __syncthreads();

#pragma unroll
    for (int kc = 0; kc < 2; ++kc) {
      short8 af[4], bf[NR];
#pragma unroll
      for (int m = 0; m < 4; ++m)
        af[m] = *(const short8*)(As + kc * 4096 +
                                 (wr + m * 16 + (lane & 15)) * 32 + (lane >> 4) * 8);
#pragma unroll
      for (int n = 0; n < NR; ++n)
        bf[n] = *(const short8*)(Bs + kc * (BN * 32) +
                                 (wc + n * 16 + (lane & 15)) * 32 + (lane >> 4) * 8);
#pragma unroll
      for (int m = 0; m < 4; ++m)
#pragma unroll
        for (int n = 0; n < NR; ++n)
          acc[m][n] = __builtin_amdgcn_mfma_f32_16x16x32_bf16(af[m], bf[n], acc[m][n], 0, 0, 0);
    }
    __syncthreads();
  }

  const int cl = lane & 15;
  const int rg = (lane >> 4) * 4;

  if (VFOLD && col0 >= 2 * CC) {
    // ---- V columns: transpose via LDS, store vT[b][h][d][T] coalesced ----
    unsigned short* T = SM;  // 128 cols x 128 toks (tok bits 3..6 ^= c&15)
#pragma unroll
    for (int m = 0; m < 4; ++m) {
#pragma unroll
      for (int n = 0; n < 4; ++n) {
        const int c = wc + n * 16 + cl;
        const float bsv = bias[col0 + c];
        const int tok0 = wr + m * 16 + rg;  // even; tok0&7 in {0,4}
        const int swz = (cl) << 3;          // (c&15)==cl
        const unsigned w0 = cvt_pk_bf16(acc[m][n][0] + bsv, acc[m][n][1] + bsv);
        const unsigned w1 = cvt_pk_bf16(acc[m][n][2] + bsv, acc[m][n][3] + bsv);
        *(unsigned*)(T + c * 128 + (((tok0 & 0x78) ^ swz) | (tok0 & 7))) = w0;
        *(unsigned*)(T + c * 128 + ((((tok0 + 2) & 0x78) ^ swz) | ((tok0 + 2) & 7))) = w1;
      }
    }
    __syncthreads();
    const int bb = row0 >> 11;
    const int rloc = row0 & (TT - 1);
#pragma unroll
    for (int i = 0; i < 8; ++i) {
      const int idx = i * 256 + tid;
      const int c = idx >> 4;   // local col 0..127
      const int g = idx & 15;   // 8-token segment
      const int gcol = col0 + c;
      const int hh = (gcol >> 6) & (NHEAD - 1);
      const int dd = gcol & (DHEAD - 1);
      ushort8 o = *(const ushort8*)(T + c * 128 + ((g ^ (c & 15)) << 3));
      *(ushort8*)(vTp + ((size_t)((bb * NHEAD + hh) * DHEAD + dd)) * TT + rloc + g * 8) = o;
    }
  } else {
#pragma unroll
    for (int m = 0; m < 4; ++m) {
#pragma unroll
      for (int n = 0; n < NR; ++n) {
        const int col = col0 + wc + n * 16 + cl;
        const float bv = bias[col];
#pragma unroll
        for (int r = 0; r < 4; ++r) {
          const int row = row0 + wr + m * 16 + rg + r;
          const float v = acc[m][n][r] + bv;
          if (BF16_OUT)
            ((unsigned short*)Cout)[(size_t)row * N + col] = f32_to_bf16_rne(v);
          else
            ((float*)Cout)[(size_t)row * N + col] = v;
        }
      }
    }
  }
}

// ---------------------------------------------------------------------------
// MFMA flash attention v6 (unchanged from round 12): paired-qt uniform blocks,
// 4 waves x 16 q-rows, double-buffered K/V, XCD-local bh mapping, swapped-
// operand log2-softmax with defer-max, cvt_pk bf16 pack.
// ---------------------------------------------------------------------------
__global__ __launch_bounds__(256) void flash_mfma_kernel(
    const unsigned short* __restrict__ qkv,
    const unsigned short* __restrict__ vT,
    unsigned short* __restrict__ y) {
  __shared__ unsigned short Ks[2][64 * 64];   // 16KB
  __shared__ unsigned short Vs[2][64 * 64];   // 16KB
  __shared__ unsigned short Ps[4][16 * 64];   // 8KB

  const int id = blockIdx.x;
  const int xcd = id & 7;
  const int grp = (id >> 3) & 3;
  const int p = id >> 5;               // 0..15
  const int bh = xcd * 4 + grp;
  const int qtA = 31 - p, qtB = p;
  const int ntA = qtA + 1, ntB = qtB + 1;  // total 33 for every block

  const int h = bh & (NHEAD - 1);
  const int b = bh >> 4;
  const int tid = threadIdx.x;
  const int wq = tid >> 6;
  const int lane = tid & 63;
  const int l15 = lane & 15;
  const int l4 = lane >> 4;
  const int srow = lane >> 3;
  const int schunk = lane & 7;

  const size_t baseQ = (size_t)(b * TT) * (3 * CC) + h * DHEAD;
  const size_t baseK = baseQ + CC;
  const size_t vbase = (size_t)((b * NHEAD + h) * DHEAD) * TT;

  short8 aqA[2], aqB[2];
  {
    const unsigned short* qp =
        qkv + baseQ + (size_t)(qtA * 64 + wq * 16 + l15) * (3 * CC) + l4 * 8;
    aqA[0] = *(const short8*)(qp);
    aqA[1] = *(const short8*)(qp + 32);
    const unsigned short* qp2 =
        qkv + baseQ + (size_t)(qtB * 64 + wq * 16 + l15) * (3 * CC) + l4 * 8;
    aqB[0] = *(const short8*)(qp2);
    aqB[1] = *(const short8*)(qp2 + 32);
  }

  floatx4 accT[4];
  float m_i = -1e30f, l_i = 0.f;
#pragma unroll
  for (int n = 0; n < 4; ++n) accT[n] = (floatx4){0.f, 0.f, 0.f, 0.f};

  auto stage = [&](int KT, int BUF) {
#pragma unroll
    for (int it = 0; it < 2; ++it) {
      const int blk = it * 4 + wq;
      const int grow = blk * 8 + srow;
      gload_lds16(qkv + baseK + (size_t)(KT * 64 + grow) * (3 * CC) +
                      (schunk ^ srow) * 8,
                  (char*)Ks[BUF] + blk * 1024);
      gload_lds16(vT + vbase + (size_t)grow * TT + KT * 64 + (schunk ^ srow) * 8,
                  (char*)Vs[BUF] + blk * 1024);
    }
  };

  auto epilogue = [&](int qt) {
    char* Pw = (char*)Ps[wq];
    const float inv = 1.0f / l_i;
#pragma unroll
    for (int nd = 0; nd < 4; ++nd) {
      uintx2 dw;
      dw[0] = cvt_pk_bf16(accT[nd][0] * inv, accT[nd][1] * inv);
      dw[1] = cvt_pk_bf16(accT[nd][2] * inv, accT[nd][3] * inv);
      const int c = nd * 2 + (l4 >> 1);
      *(uintx2*)(Pw + l15 * 128 + ((c ^ (l15 & 7)) * 16) + (l4 & 1) * 8) = dw;
    }
    asm volatile("s_waitcnt lgkmcnt(0)" ::: "memory");
#pragma unroll
    for (int ch = 0; ch < 2; ++ch) {
      const int q16 = lane >> 2;
      const int c = ch * 4 + (lane & 3);
      ushort8 o = *(const ushort8*)(Pw + q16 * 128 + ((c ^ (q16 & 7)) * 16));
      const int qg = qt * 64 + wq * 16 + q16;
      *(ushort8*)(y + (size_t)(b * TT + qg) * CC + h * DHEAD + c * 8) = o;
    }
  };

  const int nt_total = ntA + ntB;  // 33

  stage(0, 0);
  asm volatile("s_waitcnt vmcnt(0)" ::: "memory");
  __builtin_amdgcn_s_barrier();

  for (int t = 0; t < nt_total; ++t) {
    const bool phB = (t >= ntA);
    const int kt = phB ? t - ntA : t;
    const int qminw = (phB ? qtB : qtA) * 64 + wq * 16;
    const int cur = t & 1;
    if (t + 1 < nt_total)
      stage((t + 1 >= ntA) ? t + 1 - ntA : t + 1, cur ^ 1);

    floatx4 sa[4];
#pragma unroll
    for (int f = 0; f < 4; ++f) sa[f] = (floatx4){0.f, 0.f, 0.f, 0.f};

    __builtin_amdgcn_s_setprio(1);
#pragma unroll
    for (int kc = 0; kc < 2; ++kc) {
      const short8 aq = phB ? aqB[kc] : aqA[kc];
#pragma unroll
      for (int f = 0; f < 4; ++f) {
        const int row = 16 * f + l15;
        short8 bk = *(const short8*)(Ks[cur] + row * 64 +
                                     ((kc * 4 + l4) ^ (row & 7)) * 8);
        sa[f] = __builtin_amdgcn_mfma_f32_16x16x32_bf16(bk, aq, sa[f], 0, 0, 0);
      }
    }
    __builtin_amdgcn_s_setprio(0);

    const int qg = qminw + l15;
    if (kt * 64 + 63 > qminw) {
#pragma unroll
      for (int f = 0; f < 4; ++f)
#pragma unroll
        for (int r = 0; r < 4; ++r) {
          const int kg = kt * 64 + f * 16 + l4 * 4 + r;
          if (kg > qg) sa[f][r] = -1e30f;
        }
    }
    float rm = -1e30f;
#pragma unroll
    for (int f = 0; f < 4; ++f)
      rm = fmaxf(rm, fmaxf(fmaxf(sa[f][0], sa[f][1]), fmaxf(sa[f][2], sa[f][3])));
    rm = fmaxf(rm, __shfl_xor(rm, 16, 64));
    rm = fmaxf(rm, __shfl_xor(rm, 32, 64));

    float rs = 0.f;
    if (__all(rm <= m_i + 8.0f)) {
#pragma unroll
      for (int f = 0; f < 4; ++f)
#pragma unroll
        for (int r = 0; r < 4; ++r) {
          const float pv = __builtin_amdgcn_exp2f(sa[f][r] - m_i);
          sa[f][r] = pv;
          rs += pv;
        }
      rs += __shfl_xor(rs, 16, 64);
      rs += __shfl_xor(rs, 32, 64);
      l_i += rs;
    } else {
      const float mn = fmaxf(m_i, rm);
      const float scale = __builtin_amdgcn_exp2f(m_i - mn);
#pragma unroll
      for (int f = 0; f < 4; ++f)
#pragma unroll
        for (int r = 0; r < 4; ++r) {
          const float pv = __builtin_amdgcn_exp2f(sa[f][r] - mn);
          sa[f][r] = pv;
          rs += pv;
        }
      rs += __shfl_xor(rs, 16, 64);
      rs += __shfl_xor(rs, 32, 64);
      l_i = l_i * scale + rs;
      m_i = mn;
#pragma unroll
      for (int nd = 0; nd < 4; ++nd) accT[nd] *= scale;
    }

    char* Pg = (char*)Ps[wq];
#pragma unroll
    for (int f = 0; f < 4; ++f) {
      uintx2 dw;
      dw[0] = cvt_pk_bf16(sa[f][0], sa[f][1]);
      dw[1] = cvt_pk_bf16(sa[f][2], sa[f][3]);
      const int c = f * 2 + (l4 >> 1);
      *(uintx2*)(Pg + l15 * 128 + ((c ^ (l15 & 7)) * 16) + (l4 & 1) * 8) = dw;
    }
    asm volatile("s_waitcnt lgkmcnt(0)" ::: "memory");

    short8 pb[2];
#pragma unroll
    for (int kc = 0; kc < 2; ++kc) {
      const int c = kc * 4 + l4;
      pb[kc] = *(const short8*)(Pg + l15 * 128 + ((c ^ (l15 & 7)) * 16));
    }

    __builtin_amdgcn_s_setprio(1);
#pragma unroll
    for (int kc = 0; kc < 2; ++kc) {
#pragma unroll
      for (int nd = 0; nd < 4; ++nd) {
        const int row = 16 * nd + l15;
        short8 vb = *(const short8*)(Vs[cur] + row * 64 +
                                     ((kc * 4 + l4) ^ (row & 7)) * 8);
        accT[nd] = __builtin_amdgcn_mfma_f32_16x16x32_bf16(vb, pb[kc], accT[nd], 0, 0, 0);
      }
    }
    __builtin_amdgcn_s_setprio(0);

    asm volatile("s_waitcnt vmcnt(0)" ::: "memory");
    __builtin_amdgcn_s_barrier();

    if (t == ntA - 1) {
      epilogue(qtA);
      m_i = -1e30f;
      l_i = 0.f;
#pragma unroll
      for (int n = 0; n < 4; ++n) accT[n] = (floatx4){0.f, 0.f, 0.f, 0.f};
    }
  }

  epilogue(qtB);
}

extern "C" void kernel_launch(void* const* d_in, const int* in_sizes, int n_in,
                              void* d_out, int out_size, void* d_ws, size_t ws_size,
                              hipStream_t stream) {
  const float* x      = (const float*)d_in[0];
  const float* W_attn = (const float*)d_in[1];
  const float* b_attn = (const float*)d_in[2];
  const float* W_proj = (const float*)d_in[3];
  const float* b_proj = (const float*)d_in[4];
  float* out = (float*)d_out;

  const int M = BB * TT;  // 4096
  const float SCL = 0.125f * 1.44269504089f;  // 1/sqrt(64) * log2(e)

  // workspace layout (ushort units)
  unsigned short* qkvb = (unsigned short*)d_ws;          // M * 3C (V third unused)
  unsigned short* xb   = qkvb + (size_t)M * 3 * CC;      // M * C
  unsigned short* Wat  = xb + (size_t)M * CC;            // 3C * C
  unsigned short* Wpt  = Wat + (size_t)3 * CC * CC;      // C * C
  unsigned short* yb   = Wpt + (size_t)CC * CC;          // M * C
  unsigned short* vTb  = yb + (size_t)M * CC;            // B*H*D*T
  float* bscl = (float*)(vTb + (size_t)BB * NHEAD * DHEAD * TT);  // 3C floats

  prep_kernel<<<8204, 256, 0, stream>>>(x, W_attn, b_attn, W_proj,
                                        xb, Wat, Wpt, bscl, SCL);

  // GEMM1: qkv = x @ W_attn + b_attn; V third transposed straight to vTb
  {
    dim3 grid((3 * CC) / 128, M / 128);
    gemm_mfma_kernel<true, 128, true><<<grid, 256, 0, stream>>>(
        xb, Wat, bscl, qkvb, vTb, M, 3 * CC, CC);
  }

  // MFMA flash attention (paired-qt uniform blocks, dbuf, XCD-local)
  flash_mfma_kernel<<<512, 256, 0, stream>>>(qkvb, vTb, yb);

  // GEMM2: out = y @ W_proj + b_proj (fp32 out, BN=64)
  {
    dim3 grid(CC / 64, M / 128);
    gemm_mfma_kernel<false, 64, false><<<grid, 256, 0, stream>>>(
        yb, Wpt, b_proj, out, nullptr, M, CC, CC);
  }
}

// Round 14
// 120.407 us; speedup vs baseline: 33.5170x; 1.0102x over previous
//
#include <hip/hip_runtime.h>

#define BB 2
#define TT 2048
#define CC 1024
#define NHEAD 16
#define DHEAD 64

typedef __attribute__((ext_vector_type(8))) short short8;     // bf16x8 MFMA frag
typedef __attribute__((ext_vector_type(8))) unsigned short ushort8;
typedef __attribute__((ext_vector_type(4))) float floatx4;
typedef __attribute__((ext_vector_type(2))) unsigned int uintx2;

__device__ inline unsigned short f32_to_bf16_rne(float f) {
  unsigned u = __builtin_bit_cast(unsigned, f);
  unsigned r = (u + 0x7FFFu + ((u >> 16) & 1u)) >> 16;
  return (unsigned short)r;
}
__device__ inline unsigned cvt_pk_bf16(float lo, float hi) {
  unsigned r;
  asm("v_cvt_pk_bf16_f32 %0, %1, %2" : "=v"(r) : "v"(lo), "v"(hi));
  return r;
}
__device__ inline void gload_lds16(const void* g, void* l) {
  __builtin_amdgcn_global_load_lds(
      (const __attribute__((address_space(1))) void*)g,
      (__attribute__((address_space(3))) void*)l, 16, 0, 0);
}

// ---------------------------------------------------------------------------
// Fused prep kernel: x->bf16 cvt | W_attn transpose(+Q scale) | W_proj
// transpose | scaled bias.
// ---------------------------------------------------------------------------
__device__ inline void transpose_tile(const float* __restrict__ W,
                                      unsigned short* __restrict__ Wt,
                                      int K, int N, int scale_cut, float scl,
                                      int bx, int by, float (*T)[33]) {
  const int tx = threadIdx.x & 31;
  const int ty = threadIdx.x >> 5;
  const int r0 = by * 32, c0 = bx * 32;
#pragma unroll
  for (int i = 0; i < 4; ++i)
    T[ty + i * 8][tx] = W[(size_t)(r0 + ty + i * 8) * N + c0 + tx];
  __syncthreads();
#pragma unroll
  for (int i = 0; i < 4; ++i) {
    const int nrow = c0 + ty + i * 8;
    const float s = (nrow < scale_cut) ? scl : 1.0f;
    Wt[(size_t)nrow * K + r0 + tx] = f32_to_bf16_rne(T[tx][ty + i * 8] * s);
  }
}

__global__ __launch_bounds__(256) void prep_kernel(
    const float* __restrict__ x, const float* __restrict__ W_attn,
    const float* __restrict__ b_attn, const float* __restrict__ W_proj,
    unsigned short* __restrict__ xb, unsigned short* __restrict__ Wat,
    unsigned short* __restrict__ Wpt, float* __restrict__ bscl, float scl) {
  __shared__ float T[32][33];
  const int id = blockIdx.x;
  if (id < 4096) {
    const int i = (id * 256 + threadIdx.x) * 4;
    float4 v = *(const float4*)(x + i);
    ushort4 o;
    o.x = f32_to_bf16_rne(v.x);
    o.y = f32_to_bf16_rne(v.y);
    o.z = f32_to_bf16_rne(v.z);
    o.w = f32_to_bf16_rne(v.w);
    *(ushort4*)(xb + i) = o;
  } else if (id < 4096 + 3072) {
    const int t = id - 4096;
    transpose_tile(W_attn, Wat, CC, 3 * CC, CC, scl, t % 96, t / 96, T);
  } else if (id < 4096 + 3072 + 1024) {
    const int t = id - (4096 + 3072);
    transpose_tile(W_proj, Wpt, CC, CC, 0, 1.0f, t % 32, t / 32, T);
  } else {
    const int i = (id - 8192) * 256 + threadIdx.x;
    if (i < 3 * CC) bscl[i] = b_attn[i] * (i < CC ? scl : 1.0f);
  }
}

// ---------------------------------------------------------------------------
// V part of qkv (bf16, [B,T,3C] at col 2C+h*64) -> vT[b][h][d][T]
// ---------------------------------------------------------------------------
__global__ __launch_bounds__(256) void transpose_v_kernel(
    const unsigned short* __restrict__ qkv, unsigned short* __restrict__ vT) {
  __shared__ unsigned short Ts[64][72];
  const int tt0 = blockIdx.x * 64;
  const int bh = blockIdx.y;
  const int h = bh & (NHEAD - 1);
  const int b = bh >> 4;
  const int tid = threadIdx.x;
  const unsigned short* src = qkv + (size_t)(b * TT) * (3 * CC) + 2 * CC + h * DHEAD;
#pragma unroll
  for (int it = 0; it < 2; ++it) {
    const int t = it * 32 + (tid >> 3);
    const int d8 = (tid & 7) * 8;
    ushort8 v = *(const ushort8*)(src + (size_t)(tt0 + t) * (3 * CC) + d8);
#pragma unroll
    for (int j = 0; j < 8; ++j) Ts[t][d8 + j] = v[j];
  }
  __syncthreads();
  unsigned short* dst = vT + ((size_t)((b * NHEAD + h) * DHEAD)) * TT;
#pragma unroll
  for (int it = 0; it < 2; ++it) {
    const int d = it * 32 + (tid >> 3);
    const int t8 = (tid & 7) * 8;
    ushort8 o;
#pragma unroll
    for (int j = 0; j < 8; ++j) o[j] = Ts[t8 + j][d];
    *(ushort8*)(dst + (size_t)d * TT + tt0 + t8) = o;
  }
}

// ---------------------------------------------------------------------------
// GEMM1: 256x256 tile, BK=32, 8 waves (2M x 4N, per-wave 128x64 output).
// THREE LDS buffers (96KB) + depth-2 prefetch: while computing tile t we
// stage tile t+2 into buf (t+2)%3 which nobody reads -> race-free counted
// pipeline; boundary wait is vmcnt(4) (t+2's 4 own-loads), never drain-0.
// Chunk-XOR swizzle c ^= (row>>1)&3 (pre-swizzled global src + swizzled
// ds_read; 2-way banks = free). Two phases per K-tile with setprio'd MFMA.
// ---------------------------------------------------------------------------
__global__ __launch_bounds__(512, 2) void gemm256_kernel(
    const unsigned short* __restrict__ A,   // [M][K] bf16
    const unsigned short* __restrict__ Bt,  // [N][K] bf16
    const float* __restrict__ bias,
    unsigned short* __restrict__ C,         // [M][N] bf16
    int M, int N, int K) {
  __shared__ unsigned short SA[3][256 * 32];  // 48KB
  __shared__ unsigned short SB[3][256 * 32];  // 48KB

  // XCD-grouped grid: xcd owns 2 M-strips x 12 N-strips (B-cols L2-shared)
  const int id = blockIdx.x;
  const int xcd = id & 7;
  const int j = id >> 3;                    // 0..23
  const int row0 = (xcd * 2 + (j >= 12 ? 1 : 0)) * 256;
  const int col0 = (j % 12) * 256;

  const int tid = threadIdx.x;
  const int w = tid >> 6;                   // 0..7
  const int lane = tid & 63;
  const int l15 = lane & 15;
  const int l4 = lane >> 4;
  const int wr = (w >> 2) * 128;            // wave M offset
  const int wc = (w & 3) * 64;              // wave N offset
  const int sr = lane >> 2;                 // staging row-in-16
  const int sc = lane & 3;                  // staging chunk

  floatx4 acc[8][4];
#pragma unroll
  for (int m = 0; m < 8; ++m)
#pragma unroll
    for (int n = 0; n < 4; ++n) acc[m][n] = (floatx4){0.f, 0.f, 0.f, 0.f};

  auto stageA = [&](int t) {
    const int buf = t % 3;
    const int k0 = t * 32;
#pragma unroll
    for (int l = 0; l < 2; ++l) {
      const int r = w * 16 + sr + l * 128;
      gload_lds16(A + (size_t)(row0 + r) * K + k0 + ((sc ^ ((r >> 1) & 3)) * 8),
                  (char*)SA[buf] + (w * 16 + l * 128) * 64);
    }
  };
  auto stageB = [&](int t) {
    const int buf = t % 3;
    const int k0 = t * 32;
#pragma unroll
    for (int l = 0; l < 2; ++l) {
      const int r = w * 16 + sr + l * 128;
      gload_lds16(Bt + (size_t)(col0 + r) * K + k0 + ((sc ^ ((r >> 1) & 3)) * 8),
                  (char*)SB[buf] + (w * 16 + l * 128) * 64);
    }
  };

  // prologue: tiles 0 and 1 in flight; wait tile 0 (allow tile 1's 4)
  stageA(0); stageB(0);
  stageA(1); stageB(1);
  asm volatile("s_waitcnt vmcnt(4)" ::: "memory");
  __builtin_amdgcn_s_barrier();

  const int NT = K / 32;  // 32
  for (int t = 0; t < NT; ++t) {
    const unsigned short* sa = SA[t % 3];
    const unsigned short* sb = SB[t % 3];

    short8 af[4], bf[4];
#pragma unroll
    for (int n = 0; n < 4; ++n) {
      const int rb = wc + n * 16 + l15;
      bf[n] = *(const short8*)(sb + rb * 32 + ((l4 ^ ((rb >> 1) & 3)) * 8));
    }
#pragma unroll
    for (int m = 0; m < 4; ++m) {
      const int ra = wr + m * 16 + l15;
      af[m] = *(const short8*)(sa + ra * 32 + ((l4 ^ ((ra >> 1) & 3)) * 8));
    }
    if (t + 2 < NT) stageA(t + 2);
    __builtin_amdgcn_s_barrier();
    __builtin_amdgcn_s_setprio(1);
#pragma unroll
    for (int m = 0; m < 4; ++m)
#pragma unroll
      for (int n = 0; n < 4; ++n)
        acc[m][n] = __builtin_amdgcn_mfma_f32_16x16x32_bf16(af[m], bf[n], acc[m][n], 0, 0, 0);
    __builtin_amdgcn_s_setprio(0);
    __builtin_amdgcn_s_barrier();

    // phase 1: second M-half (B-frags reused from registers)
#pragma unroll
    for (int m = 0; m < 4; ++m) {
      const int ra = wr + 64 + m * 16 + l15;
      af[m] = *(const short8*)(sa + ra * 32 + ((l4 ^ ((ra >> 1) & 3)) * 8));
    }
    if (t + 2 < NT) stageB(t + 2);
    __builtin_amdgcn_s_barrier();
    __builtin_amdgcn_s_setprio(1);
#pragma unroll
    for (int m = 0; m < 4; ++m)
#pragma unroll
      for (int n = 0; n < 4; ++n)
        acc[4 + m][n] = __builtin_amdgcn_mfma_f32_16x16x32_bf16(af[m], bf[n], acc[4 + m][n], 0, 0, 0);
    __builtin_amdgcn_s_setprio(0);
    __builtin_amdgcn_s_barrier();

    if (t + 1 < NT) {  // tile t+1 confirmed landed; only t+2's loads may fly
      if (t + 2 < NT)
        asm volatile("s_waitcnt vmcnt(4)" ::: "memory");
      else
        asm volatile("s_waitcnt vmcnt(0)" ::: "memory");
      __builtin_amdgcn_s_barrier();
    }
  }

  // epilogue: bias + bf16 store
  const int rg = l4 * 4;
#pragma unroll
  for (int m = 0; m < 8; ++m) {
#pragma unroll
    for (int n = 0; n < 4; ++n) {
      const int col = col0 + wc + n * 16 + l15;
      const float bv = bias[col];
#pragma unroll
      for (int r = 0; r < 4; ++r) {
        const int row = row0 + wr + m * 16 + rg + r;
        C[(size_t)row * N + col] = f32_to_bf16_rne(acc[m][n][r] + bv);
      }
    }
  }
}

// ---------------------------------------------------------------------------
// bf16 MFMA GEMM (GEMM2): C[M][N] = A[M][K] @ Bt[N][K]^T + bias[N]
// 128xBN tile, BK=64, 256 threads (4 waves, 2x2).
// ---------------------------------------------------------------------------
template <bool BF16_OUT, int BN>
__global__ __launch_bounds__(256) void gemm_mfma_kernel(
    const unsigned short* __restrict__ A, const unsigned short* __restrict__ Bt,
    const float* __restrict__ bias, void* __restrict__ Cout,
    int M, int N, int K) {
  constexpr int NR = BN / 32;
  __shared__ unsigned short As[128 * 64];
  __shared__ unsigned short Bs[BN * 64];

  const int tid = threadIdx.x;
  const int wave = tid >> 6;
  const int lane = tid & 63;
  const int row0 = blockIdx.y * 128;
  const int col0 = blockIdx.x * BN;
  const int wr = (wave >> 1) * 64;
  const int wc = (wave & 1) * (BN / 2);

  floatx4 acc[4][NR];
#pragma unroll
  for (int m = 0; m < 4; ++m)
#pragma unroll
    for (int n = 0; n < NR; ++n) acc[m][n] = (floatx4){0.f, 0.f, 0.f, 0.f};

  const int sRow = lane >> 2;
  const int sK = (lane & 3) * 8;

  for (int k0 = 0; k0 < K; k0 += 64) {
#pragma unroll
    for (int kc = 0; kc < 2; ++kc) {
#pragma unroll
      for (int c = 0; c < 2; ++c) {
        const int g = c * 4 + wave;
        gload_lds16(A + (size_t)(row0 + g * 16 + sRow) * K + k0 + kc * 32 + sK,
                    (char*)As + kc * 8192 + g * 1024);
      }
      if constexpr (BN == 128) {
#pragma unroll
        for (int c = 0; c < 2; ++c) {
          const int g = c * 4 + wave;
          gload_lds16(Bt + (size_t)(col0 + g * 16 + sRow) * K + k0 + kc * 32 + sK,
                      (char*)Bs + kc * 8192 + g * 1024);
        }
      } else {
        gload_lds16(Bt + (size_t)(col0 + wave * 16 + sRow) * K + k0 + kc * 32 + sK,
                    (char*)Bs + kc * 4096 + wave * 1024);
      }
    }
    __syncthreads();

#pragma unroll
    for (int kc = 0; kc < 2; ++kc) {
      short8 af[4], bf[NR];
#pragma unroll
      for (int m = 0; m < 4; ++m)
        af[m] = *(const short8*)(As + kc * 4096 +
                                 (wr + m * 16 + (lane & 15)) * 32 + (lane >> 4) * 8);
#pragma unroll
      for (int n = 0; n < NR; ++n)
        bf[n] = *(const short8*)(Bs + kc * (BN * 32) +
                                 (wc + n * 16 + (lane & 15)) * 32 + (lane >> 4) * 8);
#pragma unroll
      for (int m = 0; m < 4; ++m)
#pragma unroll
        for (int n = 0; n < NR; ++n)
          acc[m][n] = __builtin_amdgcn_mfma_f32_16x16x32_bf16(af[m], bf[n], acc[m][n], 0, 0, 0);
    }
    __syncthreads();
  }

  const int cl = lane & 15;
  const int rg = (lane >> 4) * 4;
#pragma unroll
  for (int m = 0; m < 4; ++m) {
#pragma unroll
    for (int n = 0; n < NR; ++n) {
      const int col = col0 + wc + n * 16 + cl;
      const float bv = bias[col];
#pragma unroll
      for (int r = 0; r < 4; ++r) {
        const int row = row0 + wr + m * 16 + rg + r;
        const float v = acc[m][n][r] + bv;
        if (BF16_OUT)
          ((unsigned short*)Cout)[(size_t)row * N + col] = f32_to_bf16_rne(v);
        else
          ((float*)Cout)[(size_t)row * N + col] = v;
      }
    }
  }
}

// ---------------------------------------------------------------------------
// MFMA flash attention v6 (unchanged): paired-qt uniform blocks,
// 4 waves x 16 q-rows, double-buffered K/V, XCD-local bh mapping, swapped-
// operand log2-softmax with defer-max, cvt_pk bf16 pack.
// ---------------------------------------------------------------------------
__global__ __launch_bounds__(256) void flash_mfma_kernel(
    const unsigned short* __restrict__ qkv,
    const unsigned short* __restrict__ vT,
    unsigned short* __restrict__ y) {
  __shared__ unsigned short Ks[2][64 * 64];   // 16KB
  __shared__ unsigned short Vs[2][64 * 64];   // 16KB
  __shared__ unsigned short Ps[4][16 * 64];   // 8KB

  const int id = blockIdx.x;
  const int xcd = id & 7;
  const int grp = (id >> 3) & 3;
  const int p = id >> 5;               // 0..15
  const int bh = xcd * 4 + grp;
  const int qtA = 31 - p, qtB = p;
  const int ntA = qtA + 1, ntB = qtB + 1;  // total 33 for every block

  const int h = bh & (NHEAD - 1);
  const int b = bh >> 4;
  const int tid = threadIdx.x;
  const int wq = tid >> 6;
  const int lane = tid & 63;
  const int l15 = lane & 15;
  const int l4 = lane >> 4;
  const int srow = lane >> 3;
  const int schunk = lane & 7;

  const size_t baseQ = (size_t)(b * TT) * (3 * CC) + h * DHEAD;
  const size_t baseK = baseQ + CC;
  const size_t vbase = (size_t)((b * NHEAD + h) * DHEAD) * TT;

  short8 aqA[2], aqB[2];
  {
    const unsigned short* qp =
        qkv + baseQ + (size_t)(qtA * 64 + wq * 16 + l15) * (3 * CC) + l4 * 8;
    aqA[0] = *(const short8*)(qp);
    aqA[1] = *(const short8*)(qp + 32);
    const unsigned short* qp2 =
        qkv + baseQ + (size_t)(qtB * 64 + wq * 16 + l15) * (3 * CC) + l4 * 8;
    aqB[0] = *(const short8*)(qp2);
    aqB[1] = *(const short8*)(qp2 + 32);
  }

  floatx4 accT[4];
  float m_i = -1e30f, l_i = 0.f;
#pragma unroll
  for (int n = 0; n < 4; ++n) accT[n] = (floatx4){0.f, 0.f, 0.f, 0.f};

  auto stage = [&](int KT, int BUF) {
#pragma unroll
    for (int it = 0; it < 2; ++it) {
      const int blk = it * 4 + wq;
      const int grow = blk * 8 + srow;
      gload_lds16(qkv + baseK + (size_t)(KT * 64 + grow) * (3 * CC) +
                      (schunk ^ srow) * 8,
                  (char*)Ks[BUF] + blk * 1024);
      gload_lds16(vT + vbase + (size_t)grow * TT + KT * 64 + (schunk ^ srow) * 8,
                  (char*)Vs[BUF] + blk * 1024);
    }
  };

  auto epilogue = [&](int qt) {
    char* Pw = (char*)Ps[wq];
    const float inv = 1.0f / l_i;
#pragma unroll
    for (int nd = 0; nd < 4; ++nd) {
      uintx2 dw;
      dw[0] = cvt_pk_bf16(accT[nd][0] * inv, accT[nd][1] * inv);
      dw[1] = cvt_pk_bf16(accT[nd][2] * inv, accT[nd][3] * inv);
      const int c = nd * 2 + (l4 >> 1);
      *(uintx2*)(Pw + l15 * 128 + ((c ^ (l15 & 7)) * 16) + (l4 & 1) * 8) = dw;
    }
    asm volatile("s_waitcnt lgkmcnt(0)" ::: "memory");
#pragma unroll
    for (int ch = 0; ch < 2; ++ch) {
      const int q16 = lane >> 2;
      const int c = ch * 4 + (lane & 3);
      ushort8 o = *(const ushort8*)(Pw + q16 * 128 + ((c ^ (q16 & 7)) * 16));
      const int qg = qt * 64 + wq * 16 + q16;
      *(ushort8*)(y + (size_t)(b * TT + qg) * CC + h * DHEAD + c * 8) = o;
    }
  };

  const int nt_total = ntA + ntB;  // 33

  stage(0, 0);
  asm volatile("s_waitcnt vmcnt(0)" ::: "memory");
  __builtin_amdgcn_s_barrier();

  for (int t = 0; t < nt_total; ++t) {
    const bool phB = (t >= ntA);
    const int kt = phB ? t - ntA : t;
    const int qminw = (phB ? qtB : qtA) * 64 + wq * 16;
    const int cur = t & 1;
    if (t + 1 < nt_total)
      stage((t + 1 >= ntA) ? t + 1 - ntA : t + 1, cur ^ 1);

    floatx4 sa[4];
#pragma unroll
    for (int f = 0; f < 4; ++f) sa[f] = (floatx4){0.f, 0.f, 0.f, 0.f};

    __builtin_amdgcn_s_setprio(1);
#pragma unroll
    for (int kc = 0; kc < 2; ++kc) {
      const short8 aq = phB ? aqB[kc] : aqA[kc];
#pragma unroll
      for (int f = 0; f < 4; ++f) {
        const int row = 16 * f + l15;
        short8 bk = *(const short8*)(Ks[cur] + row * 64 +
                                     ((kc * 4 + l4) ^ (row & 7)) * 8);
        sa[f] = __builtin_amdgcn_mfma_f32_16x16x32_bf16(bk, aq, sa[f], 0, 0, 0);
      }
    }
    __builtin_amdgcn_s_setprio(0);

    const int qg = qminw + l15;
    if (kt * 64 + 63 > qminw) {
#pragma unroll
      for (int f = 0; f < 4; ++f)
#pragma unroll
        for (int r = 0; r < 4; ++r) {
          const int kg = kt * 64 + f * 16 + l4 * 4 + r;
          if (kg > qg) sa[f][r] = -1e30f;
        }
    }
    float rm = -1e30f;
#pragma unroll
    for (int f = 0; f < 4; ++f)
      rm = fmaxf(rm, fmaxf(fmaxf(sa[f][0], sa[f][1]), fmaxf(sa[f][2], sa[f][3])));
    rm = fmaxf(rm, __shfl_xor(rm, 16, 64));
    rm = fmaxf(rm, __shfl_xor(rm, 32, 64));

    float rs = 0.f;
    if (__all(rm <= m_i + 8.0f)) {
#pragma unroll
      for (int f = 0; f < 4; ++f)
#pragma unroll
        for (int r = 0; r < 4; ++r) {
          const float pv = __builtin_amdgcn_exp2f(sa[f][r] - m_i);
          sa[f][r] = pv;
          rs += pv;
        }
      rs += __shfl_xor(rs, 16, 64);
      rs += __shfl_xor(rs, 32, 64);
      l_i += rs;
    } else {
      const float mn = fmaxf(m_i, rm);
      const float scale = __builtin_amdgcn_exp2f(m_i - mn);
#pragma unroll
      for (int f = 0; f < 4; ++f)
#pragma unroll
        for (int r = 0; r < 4; ++r) {
          const float pv = __builtin_amdgcn_exp2f(sa[f][r] - mn);
          sa[f][r] = pv;
          rs += pv;
        }
      rs += __shfl_xor(rs, 16, 64);
      rs += __shfl_xor(rs, 32, 64);
      l_i = l_i * scale + rs;
      m_i = mn;
#pragma unroll
      for (int nd = 0; nd < 4; ++nd) accT[nd] *= scale;
    }

    char* Pg = (char*)Ps[wq];
#pragma unroll
    for (int f = 0; f < 4; ++f) {
      uintx2 dw;
      dw[0] = cvt_pk_bf16(sa[f][0], sa[f][1]);
      dw[1] = cvt_pk_bf16(sa[f][2], sa[f][3]);
      const int c = f * 2 + (l4 >> 1);
      *(uintx2*)(Pg + l15 * 128 + ((c ^ (l15 & 7)) * 16) + (l4 & 1) * 8) = dw;
    }
    asm volatile("s_waitcnt lgkmcnt(0)" ::: "memory");

    short8 pb[2];
#pragma unroll
    for (int kc = 0; kc < 2; ++kc) {
      const int c = kc * 4 + l4;
      pb[kc] = *(const short8*)(Pg + l15 * 128 + ((c ^ (l15 & 7)) * 16));
    }

    __builtin_amdgcn_s_setprio(1);
#pragma unroll
    for (int kc = 0; kc < 2; ++kc) {
#pragma unroll
      for (int nd = 0; nd < 4; ++nd) {
        const int row = 16 * nd + l15;
        short8 vb = *(const short8*)(Vs[cur] + row * 64 +
                                     ((kc * 4 + l4) ^ (row & 7)) * 8);
        accT[nd] = __builtin_amdgcn_mfma_f32_16x16x32_bf16(vb, pb[kc], accT[nd], 0, 0, 0);
      }
    }
    __builtin_amdgcn_s_setprio(0);

    asm volatile("s_waitcnt vmcnt(0)" ::: "memory");
    __builtin_amdgcn_s_barrier();

    if (t == ntA - 1) {
      epilogue(qtA);
      m_i = -1e30f;
      l_i = 0.f;
#pragma unroll
      for (int n = 0; n < 4; ++n) accT[n] = (floatx4){0.f, 0.f, 0.f, 0.f};
    }
  }

  epilogue(qtB);
}

extern "C" void kernel_launch(void* const* d_in, const int* in_sizes, int n_in,
                              void* d_out, int out_size, void* d_ws, size_t ws_size,
                              hipStream_t stream) {
  const float* x      = (const float*)d_in[0];
  const float* W_attn = (const float*)d_in[1];
  const float* b_attn = (const float*)d_in[2];
  const float* W_proj = (const float*)d_in[3];
  const float* b_proj = (const float*)d_in[4];
  float* out = (float*)d_out;

  const int M = BB * TT;  // 4096
  const float SCL = 0.125f * 1.44269504089f;  // 1/sqrt(64) * log2(e)

  // workspace layout (ushort units)
  unsigned short* qkvb = (unsigned short*)d_ws;          // M * 3C
  unsigned short* xb   = qkvb + (size_t)M * 3 * CC;      // M * C
  unsigned short* Wat  = xb + (size_t)M * CC;            // 3C * C
  unsigned short* Wpt  = Wat + (size_t)3 * CC * CC;      // C * C
  unsigned short* yb   = Wpt + (size_t)CC * CC;          // M * C
  unsigned short* vTb  = yb + (size_t)M * CC;            // B*H*D*T
  float* bscl = (float*)(vTb + (size_t)BB * NHEAD * DHEAD * TT);  // 3C floats

  prep_kernel<<<8204, 256, 0, stream>>>(x, W_attn, b_attn, W_proj,
                                        xb, Wat, Wpt, bscl, SCL);

  // GEMM1: qkv = x @ W_attn + b_attn (256x256 counted-vmcnt pipeline)
  gemm256_kernel<<<192, 512, 0, stream>>>(xb, Wat, bscl, qkvb, M, 3 * CC, CC);

  // V -> vT[b][h][d][T]
  {
    dim3 grid(TT / 64, BB * NHEAD);
    transpose_v_kernel<<<grid, 256, 0, stream>>>(qkvb, vTb);
  }

  // MFMA flash attention (paired-qt uniform blocks, dbuf, XCD-local)
  flash_mfma_kernel<<<512, 256, 0, stream>>>(qkvb, vTb, yb);

  // GEMM2: out = y @ W_proj + b_proj (fp32 out, BN=64)
  {
    dim3 grid(CC / 64, M / 128);
    gemm_mfma_kernel<false, 64><<<grid, 256, 0, stream>>>(
        yb, Wpt, b_proj, out, M, CC, CC);
  }
}